// Round 5
// baseline (1026.064 us; speedup 1.0000x reference)
//
#include <hip/hip_runtime.h>
#include <hip/hip_bf16.h>
#include <math.h>

#define B_ 4
#define L_ 1024
#define DM 512
#define NH 8
#define HD 64
#define DFF 2048
#define KS 35
#define QS 1536   // packed QKV row stride
#define CH 128    // attention key chunk
#define NCH (L_/CH)

typedef __attribute__((ext_vector_type(8))) short bf16x8;
typedef __attribute__((ext_vector_type(4))) float f32x4;

__device__ inline ushort f2b(float f){
  __hip_bfloat16 h = __float2bfloat16(f);
  return *reinterpret_cast<ushort*>(&h);
}
__device__ inline float gelu_exact(float x){
  return 0.5f*x*(1.0f+erff(x*0.7071067811865476f));
}

#define GLOAD16(g, l) __builtin_amdgcn_global_load_lds( \
    (const __attribute__((address_space(1))) void*)(g), \
    (__attribute__((address_space(3))) void*)(l), 16, 0, 0)

// ---------------- weight convert + transpose to bf16 [N][K] ----------------
__global__ __launch_bounds__(256) void wconv_kernel(const float* __restrict__ W,
    ushort* __restrict__ Wt, int K, int N)
{
  __shared__ float tile[32][33];
  int n0 = blockIdx.x*32, k0 = blockIdx.y*32;
  int tx = threadIdx.x & 31, ty = threadIdx.x >> 5;
  #pragma unroll
  for (int i = ty; i < 32; i += 8) tile[i][tx] = W[(size_t)(k0+i)*N + n0+tx];
  __syncthreads();
  #pragma unroll
  for (int i = ty; i < 32; i += 8) Wt[(size_t)(n0+i)*K + k0+tx] = f2b(tile[tx][i]);
}

__global__ __launch_bounds__(256) void bcat_kernel(const float* __restrict__ bq,
    const float* __restrict__ bk, const float* __restrict__ bv, float* __restrict__ bqkv)
{
  int i = blockIdx.x*256 + threadIdx.x;   // 0..3071
  if (i >= 2*QS) return;
  int l = i / QS, j = i - l*QS;
  const float* src = (j < 512) ? bq : (j < 1024 ? bk : bv);
  bqkv[i] = src[l*DM + (j & 511)];
}

// ---------------- bf16 MFMA GEMM (single-buffered, known-pass) ----------------
// A: [M][K] bf16 row-major; Bt: [N][K] bf16; MODE 0: f32 out, 1: gelu->bf16 out, 2: +R f32 out
template<int BN, int MODE>
__global__ __launch_bounds__(256) void mfma_gemm(
    const ushort* __restrict__ A, const ushort* __restrict__ Bt,
    const float* __restrict__ bias, const float* __restrict__ R,
    float* __restrict__ Cf, ushort* __restrict__ Cb,
    int M, int N, int K)
{
  constexpr int BM = 128, BK = 32;
  constexpr int NF = BN/32;          // B fragments per wave
  constexpr int ACH = BM*4;          // 16B chunks in A tile
  constexpr int BCH = BN*4;
  __shared__ __align__(16) ushort As[BM*BK];
  __shared__ __align__(16) ushort Bs[BN*BK];
  const int t = threadIdx.x, lane = t & 63, w = t >> 6, wr = w >> 1, wc = w & 1;
  const int row0 = blockIdx.y*BM, col0 = blockIdx.x*BN;

  // staging addresses: linear LDS dest, inverse-swizzled global source
  const ushort* aSrc[ACH/256]; int aDst[ACH/256];
  #pragma unroll
  for (int j = 0; j < ACH/256; j++) {
    int ch = j*256 + t, r = ch >> 2, c = ch & 3, cs = c ^ ((r >> 1) & 3);
    aSrc[j] = A + (size_t)(row0 + r)*K + cs*8;
    aDst[j] = ch*16;
  }
  const ushort* bSrc[BCH/256]; int bDst[BCH/256];
  #pragma unroll
  for (int j = 0; j < BCH/256; j++) {
    int ch = j*256 + t, r = ch >> 2, c = ch & 3, cs = c ^ ((r >> 1) & 3);
    bSrc[j] = Bt + (size_t)(col0 + r)*K + cs*8;
    bDst[j] = ch*16;
  }
  // fragment read offsets (swizzled)
  int aOff[4], bOff[NF];
  #pragma unroll
  for (int m = 0; m < 4; m++) {
    int r = wr*64 + m*16 + (lane & 15);
    aOff[m] = r*64 + (((lane >> 4)*16) ^ (((r >> 1) & 3) << 4));
  }
  #pragma unroll
  for (int n = 0; n < NF; n++) {
    int r = wc*(BN/2) + n*16 + (lane & 15);
    bOff[n] = r*64 + (((lane >> 4)*16) ^ (((r >> 1) & 3) << 4));
  }
  f32x4 zero = {0.f, 0.f, 0.f, 0.f};
  f32x4 acc[4][NF];
  #pragma unroll
  for (int m = 0; m < 4; m++)
    #pragma unroll
    for (int n = 0; n < NF; n++) acc[m][n] = zero;

  for (int kt = 0; kt < K; kt += BK) {
    __syncthreads();
    #pragma unroll
    for (int j = 0; j < ACH/256; j++) GLOAD16(aSrc[j] + kt, (char*)As + aDst[j]);
    #pragma unroll
    for (int j = 0; j < BCH/256; j++) GLOAD16(bSrc[j] + kt, (char*)Bs + bDst[j]);
    __syncthreads();
    bf16x8 af[4], bfr[NF];
    #pragma unroll
    for (int m = 0; m < 4; m++) af[m] = *(const bf16x8*)((const char*)As + aOff[m]);
    #pragma unroll
    for (int n = 0; n < NF; n++) bfr[n] = *(const bf16x8*)((const char*)Bs + bOff[n]);
    #pragma unroll
    for (int m = 0; m < 4; m++)
      #pragma unroll
      for (int n = 0; n < NF; n++)
        acc[m][n] = __builtin_amdgcn_mfma_f32_16x16x32_bf16(af[m], bfr[n], acc[m][n], 0, 0, 0);
  }
  #pragma unroll
  for (int m = 0; m < 4; m++) {
    int rb = row0 + wr*64 + m*16 + ((lane >> 4) << 2);
    #pragma unroll
    for (int n = 0; n < NF; n++) {
      int c = col0 + wc*(BN/2) + n*16 + (lane & 15);
      float bv = bias[c];
      #pragma unroll
      for (int j = 0; j < 4; j++) {
        size_t idx = (size_t)(rb + j)*N + c;
        float v = acc[m][n][j] + bv;
        if (MODE == 1)      Cb[idx] = f2b(gelu_exact(v));
        else if (MODE == 2) Cf[idx] = v + R[idx];
        else                Cf[idx] = v;
      }
    }
  }
}

// ---------------- embed + positional encoding ----------------
__global__ __launch_bounds__(512) void embed_kernel(const float* __restrict__ src,
    const float* __restrict__ Wemb, const float* __restrict__ bemb,
    float* __restrict__ X, ushort* __restrict__ Xb)
{
  int row = blockIdx.x, l = row & (L_-1), t = threadIdx.x;
  __shared__ float s_src[32];
  if (t < 32) s_src[t] = src[row*32 + t];
  __syncthreads();
  float acc = bemb[t];
  #pragma unroll
  for (int k = 0; k < 32; k++) acc += s_src[k]*Wemb[k*DM + t];
  int i2 = t & ~1;
  float freq = expf((float)i2 * (-9.210340371976184f/512.0f));
  float ang = (float)l * freq;
  acc += (t & 1) ? cosf(ang) : sinf(ang);
  size_t idx = (size_t)row*DM + t;
  X[idx] = acc;
  Xb[idx] = f2b(acc);
}

// ---------------- QK_sample -> M score ----------------
__global__ __launch_bounds__(64) void qksample_kernel(const float* __restrict__ QKV,
    const int* __restrict__ idx_s, float* __restrict__ Msc)
{
  int gid = blockIdx.x;
  int i = gid & (L_-1), h = (gid >> 10) & 7, b = gid >> 13;
  int e = threadIdx.x;
  float q = QKV[((size_t)(b*L_ + i))*QS + h*HD + e];
  float mx = -3.4e38f, sm = 0.f;
  for (int j = 0; j < KS; j++) {
    int s = idx_s[i*KS + j];
    float p = q * QKV[((size_t)(b*L_ + s))*QS + 512 + h*HD + e];
    #pragma unroll
    for (int off = 32; off; off >>= 1) p += __shfl_xor(p, off);
    mx = fmaxf(mx, p); sm += p;
  }
  if (e == 0) Msc[gid] = mx - sm*(1.0f/KS);
}

// ---------------- single-wave top-35 (tie-break lower index) ----------------
__global__ __launch_bounds__(64) void topk_kernel(const float* __restrict__ Msc, int* __restrict__ idx_top)
{
  int bh = blockIdx.x, t = threadIdx.x;
  __shared__ float vals[L_];
  for (int i = t; i < L_; i += 64) vals[i] = Msc[(size_t)bh*L_ + i];
  __syncthreads();
  for (int sel = 0; sel < KS; sel++) {
    float bv = -3.4e38f; int bi = 0x7fffffff;
    for (int i = t; i < L_; i += 64) {
      float v = vals[i];
      if (v > bv || (v == bv && i < bi)) { bv = v; bi = i; }
    }
    #pragma unroll
    for (int off = 32; off; off >>= 1) {
      float ov = __shfl_xor(bv, off); int oi = __shfl_xor(bi, off);
      if (ov > bv || (ov == bv && oi < bi)) { bv = ov; bi = oi; }
    }
    if (t == 0) idx_top[bh*KS + sel] = bi;
    if (t == (bi & 63)) vals[bi] = -3.4e38f;
    __syncthreads();
  }
}

// ---------------- V mean over L ----------------
__global__ __launch_bounds__(256) void vmean_kernel(const float* __restrict__ QKV, float* __restrict__ Vmean)
{
  int bh = blockIdx.x, h = bh & 7, b = bh >> 3;
  int g = threadIdx.x >> 6, e = threadIdx.x & 63;
  __shared__ float p[4][64];
  const float* Vb = QKV + 1024 + h*HD + (size_t)b*L_*QS;
  float s = 0.f;
  for (int l = g; l < L_; l += 4) s += Vb[(size_t)l*QS + e];
  p[g][e] = s;
  __syncthreads();
  if (threadIdx.x < 64)
    Vmean[bh*HD + threadIdx.x] =
      (p[0][threadIdx.x]+p[1][threadIdx.x]+p[2][threadIdx.x]+p[3][threadIdx.x]) * (1.f/L_);
}

// ---------------- fill context with broadcast V-mean (bf16) ----------------
__global__ __launch_bounds__(512) void ctxfill_kernel(const float* __restrict__ Vmean, ushort* __restrict__ CTXb)
{
  int row = blockIdx.x, b = row >> 10, t = threadIdx.x;
  CTXb[(size_t)row*DM + t] = f2b(Vmean[b*DM + t]);
}

// ---------------- chunked flash attention, phase A: per-chunk partials ----------------
// grid: (b*8+h)*8 + chunk  (256 blocks), block 256
__global__ __launch_bounds__(256) void attn_part_kernel(const float* __restrict__ QKV,
    const int* __restrict__ idx_top,
    float* __restrict__ Pacc, float* __restrict__ Pm, float* __restrict__ Pl)
{
  int gid = blockIdx.x;
  int bh = gid >> 3, c = gid & 7;
  int h = bh & 7, b = bh >> 3;
  int t = threadIdx.x;
  __shared__ float qs[36][64];          // scaled Q (row 35 = zeroed pad)
  __shared__ float sc[35*132];          // scores (pitch 132 words)
  __shared__ float sm[35], sl[35];

  // load + scale Q rows; zero the pad row
  for (int idx = t; idx < 35*64; idx += 256) {
    int u = idx >> 6, e = idx & 63;
    int qi = idx_top[bh*KS + u];
    qs[u][e] = QKV[((size_t)(b*L_ + qi))*QS + h*HD + e] * 0.125f;
  }
  if (t < 64) qs[35][t] = 0.f;
  __syncthreads();

  // scores: thread = (half, local key k); K row in registers
  int k = t & 127, half = t >> 7;
  int s0 = c*CH + k;
  const float4* Kr = (const float4*)(QKV + ((size_t)(b*L_ + s0))*QS + 512 + h*HD);
  float4 kreg[16];
  #pragma unroll
  for (int e4 = 0; e4 < 16; e4++) kreg[e4] = Kr[e4];
  int u0 = half*18;
  float accd[18];
  #pragma unroll
  for (int iu = 0; iu < 18; iu++) accd[iu] = 0.f;
  #pragma unroll
  for (int e4 = 0; e4 < 16; e4++) {
    float4 k4 = kreg[e4];
    #pragma unroll
    for (int iu = 0; iu < 18; iu++) {
      float4 q4 = *(const float4*)&qs[u0 + iu][e4*4];   // broadcast
      accd[iu] += q4.x*k4.x + q4.y*k4.y + q4.z*k4.z + q4.w*k4.w;
    }
  }
  #pragma unroll
  for (int iu = 0; iu < 18; iu++) {
    int u = u0 + iu;
    if (u < 35) sc[u*132 + k] = accd[iu];
  }
  __syncthreads();

  // per-u local max, exp, sum (thread u)
  if (t < 35) {
    float4* row = (float4*)&sc[t*132];
    float m = -3.4e38f;
    #pragma unroll 8
    for (int kb = 0; kb < 32; kb++) {
      float4 v = row[kb];
      m = fmaxf(fmaxf(fmaxf(m, v.x), v.y), fmaxf(v.z, v.w));
    }
    float l = 0.f;
    #pragma unroll 8
    for (int kb = 0; kb < 32; kb++) {
      float4 v = row[kb];
      v.x = expf(v.x - m); v.y = expf(v.y - m); v.z = expf(v.z - m); v.w = expf(v.w - m);
      l += v.x + v.y + v.z + v.w;
      row[kb] = v;
    }
    sm[t] = m; sl[t] = l;
  }
  __syncthreads();

  // partial PV: thread = (ug, e); u in {ug, ug+4, ...}
  int e = t & 63, ug = t >> 6;
  const float* Vb = QKV + 1024 + h*HD + ((size_t)b*L_ + c*CH)*QS;
  float acc[9];
  #pragma unroll
  for (int iu = 0; iu < 9; iu++) acc[iu] = 0.f;
  for (int kb = 0; kb < 32; kb++) {
    float v0 = Vb[(size_t)(4*kb + 0)*QS + e];
    float v1 = Vb[(size_t)(4*kb + 1)*QS + e];
    float v2 = Vb[(size_t)(4*kb + 2)*QS + e];
    float v3 = Vb[(size_t)(4*kb + 3)*QS + e];
    #pragma unroll
    for (int iu = 0; iu < 9; iu++) {
      int u = ug + iu*4;
      if (u < 35) {
        float4 w4 = *(const float4*)&sc[u*132 + 4*kb];  // broadcast within wave
        acc[iu] += w4.x*v0 + w4.y*v1 + w4.z*v2 + w4.w*v3;
      }
    }
  }
  #pragma unroll
  for (int iu = 0; iu < 9; iu++) {
    int u = ug + iu*4;
    if (u < 35) Pacc[((size_t)gid*35 + u)*64 + e] = acc[iu];
  }
  if (t < 35) { Pm[gid*35 + t] = sm[t]; Pl[gid*35 + t] = sl[t]; }
}

// ---------------- phase B: merge partials, scatter bf16 ctx ----------------
__global__ __launch_bounds__(256) void attn_merge_kernel(const float* __restrict__ Pacc,
    const float* __restrict__ Pm, const float* __restrict__ Pl,
    const int* __restrict__ idx_top, ushort* __restrict__ CTXb)
{
  int bh = blockIdx.x;
  int h = bh & 7, b = bh >> 3;
  int t = threadIdx.x;
  __shared__ float m8[NCH*35], l8[NCH*35];
  for (int i = t; i < NCH*35; i += 256) {
    int c = i / 35, u = i - c*35;
    m8[c*35 + u] = Pm[((size_t)bh*NCH + c)*35 + u];
    l8[c*35 + u] = Pl[((size_t)bh*NCH + c)*35 + u];
  }
  __syncthreads();
  int e = t & 63, ug = t >> 6;
  #pragma unroll
  for (int iu = 0; iu < 9; iu++) {
    int u = ug + iu*4;
    if (u >= 35) break;
    float M = -3.4e38f;
    #pragma unroll
    for (int c = 0; c < NCH; c++) M = fmaxf(M, m8[c*35 + u]);
    float Ltot = 0.f, o = 0.f;
    #pragma unroll
    for (int c = 0; c < NCH; c++) {
      float w = expf(m8[c*35 + u] - M);
      Ltot += w * l8[c*35 + u];
      o += w * Pacc[(((size_t)bh*NCH + c)*35 + u)*64 + e];
    }
    int qi = idx_top[bh*KS + u];
    CTXb[((size_t)(b*L_ + qi))*DM + h*HD + e] = f2b(o / Ltot);
  }
}

// ---------------- LayerNorm (optional add), f32 + bf16 out ----------------
__global__ __launch_bounds__(512) void ln_kernel(const float* __restrict__ Xa,
    const float* __restrict__ Xadd, const float* __restrict__ g, const float* __restrict__ beta,
    float* __restrict__ outf, ushort* __restrict__ outb)
{
  int row = blockIdx.x, t = threadIdx.x;
  __shared__ float red[16];
  size_t idx = (size_t)row*DM + t;
  float v = Xa[idx];
  if (Xadd) v += Xadd[idx];
  float s = v;
  #pragma unroll
  for (int off = 32; off; off >>= 1) s += __shfl_xor(s, off);
  if ((t & 63) == 0) red[t >> 6] = s;
  __syncthreads();
  float mean = 0.f;
  #pragma unroll
  for (int k = 0; k < 8; k++) mean += red[k];
  mean *= (1.f/DM);
  float d = v - mean, q = d*d;
  #pragma unroll
  for (int off = 32; off; off >>= 1) q += __shfl_xor(q, off);
  if ((t & 63) == 0) red[8 + (t >> 6)] = q;
  __syncthreads();
  float var = 0.f;
  #pragma unroll
  for (int k = 0; k < 8; k++) var += red[8 + k];
  var *= (1.f/DM);
  float r = d / sqrtf(var + 1e-5f) * g[t] + beta[t];
  outf[idx] = r;
  if (outb) outb[idx] = f2b(r);
}

// ---------------- partial mean pool + classifier ----------------
__global__ __launch_bounds__(512) void poolp_kernel(const float* __restrict__ X, float* __restrict__ pooledP)
{
  int p = blockIdx.x;
  int t = threadIdx.x;
  int b = p >> 3, seg = p & 7;
  float s = 0.f;
  const float* base = X + ((size_t)b*L_ + seg*128)*DM + t;
  for (int l = 0; l < 128; l++) s += base[(size_t)l*DM];
  pooledP[p*DM + t] = s;
}

__global__ __launch_bounds__(64) void cls_kernel(const float* __restrict__ pooledP,
    const float* __restrict__ Wc, const float* __restrict__ bc, float* __restrict__ out)
{
  int o = blockIdx.x;
  int b = o/10, c = o%10, t = threadIdx.x;
  float s = 0.f;
  for (int d = t; d < DM; d += 64) {
    float p = 0.f;
    #pragma unroll
    for (int seg = 0; seg < 8; seg++) p += pooledP[(b*8 + seg)*DM + d];
    s += p * (1.f/L_) * Wc[d*10 + c];
  }
  #pragma unroll
  for (int off = 32; off; off >>= 1) s += __shfl_xor(s, off);
  if (t == 0) out[o] = bc[c] + s;
}

extern "C" void kernel_launch(void* const* d_in, const int* in_sizes, int n_in,
                              void* d_out, int out_size, void* d_ws, size_t ws_size,
                              hipStream_t stream)
{
  const float* src   = (const float*)d_in[0];
  const int*   idxs  = (const int*)d_in[1];
  const float* Wemb  = (const float*)d_in[2];
  const float* bemb  = (const float*)d_in[3];
  const float* Wq    = (const float*)d_in[4];
  const float* bq    = (const float*)d_in[5];
  const float* Wk    = (const float*)d_in[6];
  const float* bk    = (const float*)d_in[7];
  const float* Wv    = (const float*)d_in[8];
  const float* bv    = (const float*)d_in[9];
  const float* Wo    = (const float*)d_in[10];
  const float* bo    = (const float*)d_in[11];
  const float* g1    = (const float*)d_in[12];
  const float* beta1 = (const float*)d_in[13];
  const float* W1    = (const float*)d_in[14];
  const float* bf1   = (const float*)d_in[15];
  const float* W2    = (const float*)d_in[16];
  const float* bf2   = (const float*)d_in[17];
  const float* g2    = (const float*)d_in[18];
  const float* beta2 = (const float*)d_in[19];
  const float* gf    = (const float*)d_in[20];
  const float* betaf = (const float*)d_in[21];
  const float* Wc    = (const float*)d_in[22];
  const float* bc    = (const float*)d_in[23];
  float* out = (float*)d_out;

  float* wsf = (float*)d_ws;
  float*  X     = wsf;                              // [0, 2097152)
  ushort* Xb    = (ushort*)(wsf + 2097152);         // [2097152, 3145728)
  ushort* CTXb  = (ushort*)(wsf + 3145728);         // [3145728, 4194304)
  float*  QKV   = wsf + 4194304;                    // [4194304, 10485760)  LIVE during attention
  ushort* H     = (ushort*)(wsf + 4194304);         // FFN hidden bf16 (QKV dead by FFN1)
  float*  Y     = wsf + 8388608;                    // [8388608, 10485760)  FFN2 out (QKV dead)
  // attention partials: alias Xb (dead between QKV-GEMM and ln1) — NOT inside QKV!
  float*  Pacc  = wsf + 2097152;                    // 573,440 fl <= Xb's 1,048,576
  ushort* Wqkvt = (ushort*)(wsf + 10485760);        // 786,432 fl
  ushort* Wot   = (ushort*)(wsf + 11272192);        // 262,144 fl
  ushort* W1t   = (ushort*)(wsf + 11534336);        // 1,048,576 fl
  ushort* W2t   = (ushort*)(wsf + 12582912);        // 1,048,576 fl
  float*  bqkv  = wsf + 13631488;                   // 3,072
  float*  Msc   = wsf + 13634560;                   // 32,768 (dead after topk)
  float*  Pm    = wsf + 13634560;                   // alias Msc: 8,960
  float*  Pl    = wsf + 13634560 + 8960;            // alias Msc: 8,960 (17,920 <= 32,768)
  float*  Vmean = wsf + 13667328;                   // 2,048
  float*  pooledP = wsf + 13669376;                 // 16,384
  int*    idx_top = (int*)(wsf + 13685760);         // 1,120

  for (int l = 0; l < 2; l++) {
    wconv_kernel<<<dim3(DM/32, DM/32), 256, 0, stream>>>(Wq + (size_t)l*DM*DM, Wqkvt + ((size_t)l*QS +    0)*DM, DM, DM);
    wconv_kernel<<<dim3(DM/32, DM/32), 256, 0, stream>>>(Wk + (size_t)l*DM*DM, Wqkvt + ((size_t)l*QS +  512)*DM, DM, DM);
    wconv_kernel<<<dim3(DM/32, DM/32), 256, 0, stream>>>(Wv + (size_t)l*DM*DM, Wqkvt + ((size_t)l*QS + 1024)*DM, DM, DM);
    wconv_kernel<<<dim3(DM/32, DM/32), 256, 0, stream>>>(Wo + (size_t)l*DM*DM, Wot + (size_t)l*DM*DM, DM, DM);
    wconv_kernel<<<dim3(DFF/32, DM/32), 256, 0, stream>>>(W1 + (size_t)l*DM*DFF, W1t + (size_t)l*DFF*DM, DM, DFF);
    wconv_kernel<<<dim3(DM/32, DFF/32), 256, 0, stream>>>(W2 + (size_t)l*DFF*DM, W2t + (size_t)l*DM*DFF, DFF, DM);
  }
  bcat_kernel<<<12, 256, 0, stream>>>(bq, bk, bv, bqkv);

  const int M = B_ * L_; // 4096
  embed_kernel<<<M, 512, 0, stream>>>(src, Wemb, bemb, X, Xb);

  for (int l = 0; l < 2; l++) {
    const size_t vo = (size_t)l*DM;
    mfma_gemm<128,0><<<dim3(QS/128, M/128), 256, 0, stream>>>(
        Xb, Wqkvt + (size_t)l*QS*DM, bqkv + (size_t)l*QS, nullptr, QKV, nullptr, M, QS, DM);
    qksample_kernel<<<B_*NH*L_, 64, 0, stream>>>(QKV, idxs + (size_t)l*L_*KS, Msc);
    topk_kernel<<<B_*NH, 64, 0, stream>>>(Msc, idx_top);
    vmean_kernel<<<B_*NH, 256, 0, stream>>>(QKV, Vmean);
    ctxfill_kernel<<<M, 512, 0, stream>>>(Vmean, CTXb);
    attn_part_kernel<<<B_*NH*NCH, 256, 0, stream>>>(QKV, idx_top, Pacc, Pm, Pl);
    attn_merge_kernel<<<B_*NH, 256, 0, stream>>>(Pacc, Pm, Pl, idx_top, CTXb);
    mfma_gemm<64,2><<<dim3(DM/64, M/128), 256, 0, stream>>>(
        CTXb, Wot + (size_t)l*DM*DM, bo + vo, X, X, nullptr, M, DM, DM);
    ln_kernel<<<M, 512, 0, stream>>>(X, nullptr, g1 + vo, beta1 + vo, X, Xb);
    mfma_gemm<128,1><<<dim3(DFF/128, M/128), 256, 0, stream>>>(
        Xb, W1t + (size_t)l*DFF*DM, bf1 + (size_t)l*DFF, nullptr, nullptr, H, M, DFF, DM);
    mfma_gemm<64,0><<<dim3(DM/64, M/128), 256, 0, stream>>>(
        H, W2t + (size_t)l*DM*DFF, bf2 + vo, nullptr, Y, nullptr, M, DM, DFF);
    ln_kernel<<<M, 512, 0, stream>>>(X, Y, g2 + vo, beta2 + vo, X, Xb);
  }
  ln_kernel<<<M, 512, 0, stream>>>(X, nullptr, gf, betaf, X, nullptr);
  poolp_kernel<<<B_*8, 512, 0, stream>>>(X, pooledP);
  cls_kernel<<<40, 64, 0, stream>>>(pooledP, Wc, bc, out);
}

// Round 6
// 877.725 us; speedup vs baseline: 1.1690x; 1.1690x over previous
//
#include <hip/hip_runtime.h>
#include <hip/hip_bf16.h>
#include <math.h>

#define B_ 4
#define L_ 1024
#define DM 512
#define NH 8
#define HD 64
#define DFF 2048
#define KS 35
#define QS 1536   // packed QKV row stride
#define CH 128    // attention key chunk
#define NCH (L_/CH)

typedef __attribute__((ext_vector_type(8))) short bf16x8;
typedef __attribute__((ext_vector_type(4))) float f32x4;

__device__ inline ushort f2b(float f){
  __hip_bfloat16 h = __float2bfloat16(f);
  return *reinterpret_cast<ushort*>(&h);
}
__device__ inline float gelu_exact(float x){
  return 0.5f*x*(1.0f+erff(x*0.7071067811865476f));
}

#define GLOAD16(g, l) __builtin_amdgcn_global_load_lds( \
    (const __attribute__((address_space(1))) void*)(g), \
    (__attribute__((address_space(3))) void*)(l), 16, 0, 0)

// ---------------- weight convert + transpose to bf16 [N][K] ----------------
__global__ __launch_bounds__(256) void wconv_kernel(const float* __restrict__ W,
    ushort* __restrict__ Wt, int K, int N)
{
  __shared__ float tile[32][33];
  int n0 = blockIdx.x*32, k0 = blockIdx.y*32;
  int tx = threadIdx.x & 31, ty = threadIdx.x >> 5;
  #pragma unroll
  for (int i = ty; i < 32; i += 8) tile[i][tx] = W[(size_t)(k0+i)*N + n0+tx];
  __syncthreads();
  #pragma unroll
  for (int i = ty; i < 32; i += 8) Wt[(size_t)(n0+i)*K + k0+tx] = f2b(tile[tx][i]);
}

__global__ __launch_bounds__(256) void bcat_kernel(const float* __restrict__ bq,
    const float* __restrict__ bk, const float* __restrict__ bv, float* __restrict__ bqkv)
{
  int i = blockIdx.x*256 + threadIdx.x;   // 0..3071
  if (i >= 2*QS) return;
  int l = i / QS, j = i - l*QS;
  const float* src = (j < 512) ? bq : (j < 1024 ? bk : bv);
  bqkv[i] = src[l*DM + (j & 511)];
}

// ---------------- bf16 MFMA GEMM (single-buffered, known-pass) ----------------
// A: [M][K] bf16 row-major; Bt: [N][K] bf16; MODE 0: f32 out, 1: gelu->bf16 out, 2: +R f32 out
template<int BN, int MODE>
__global__ __launch_bounds__(256) void mfma_gemm(
    const ushort* __restrict__ A, const ushort* __restrict__ Bt,
    const float* __restrict__ bias, const float* __restrict__ R,
    float* __restrict__ Cf, ushort* __restrict__ Cb,
    int M, int N, int K)
{
  constexpr int BM = 128, BK = 32;
  constexpr int NF = BN/32;          // B fragments per wave
  constexpr int ACH = BM*4;          // 16B chunks in A tile
  constexpr int BCH = BN*4;
  __shared__ __align__(16) ushort As[BM*BK];
  __shared__ __align__(16) ushort Bs[BN*BK];
  const int t = threadIdx.x, lane = t & 63, w = t >> 6, wr = w >> 1, wc = w & 1;
  const int row0 = blockIdx.y*BM, col0 = blockIdx.x*BN;

  // staging addresses: linear LDS dest, inverse-swizzled global source
  const ushort* aSrc[ACH/256]; int aDst[ACH/256];
  #pragma unroll
  for (int j = 0; j < ACH/256; j++) {
    int ch = j*256 + t, r = ch >> 2, c = ch & 3, cs = c ^ ((r >> 1) & 3);
    aSrc[j] = A + (size_t)(row0 + r)*K + cs*8;
    aDst[j] = ch*16;
  }
  const ushort* bSrc[BCH/256]; int bDst[BCH/256];
  #pragma unroll
  for (int j = 0; j < BCH/256; j++) {
    int ch = j*256 + t, r = ch >> 2, c = ch & 3, cs = c ^ ((r >> 1) & 3);
    bSrc[j] = Bt + (size_t)(col0 + r)*K + cs*8;
    bDst[j] = ch*16;
  }
  // fragment read offsets (swizzled)
  int aOff[4], bOff[NF];
  #pragma unroll
  for (int m = 0; m < 4; m++) {
    int r = wr*64 + m*16 + (lane & 15);
    aOff[m] = r*64 + (((lane >> 4)*16) ^ (((r >> 1) & 3) << 4));
  }
  #pragma unroll
  for (int n = 0; n < NF; n++) {
    int r = wc*(BN/2) + n*16 + (lane & 15);
    bOff[n] = r*64 + (((lane >> 4)*16) ^ (((r >> 1) & 3) << 4));
  }
  f32x4 zero = {0.f, 0.f, 0.f, 0.f};
  f32x4 acc[4][NF];
  #pragma unroll
  for (int m = 0; m < 4; m++)
    #pragma unroll
    for (int n = 0; n < NF; n++) acc[m][n] = zero;

  for (int kt = 0; kt < K; kt += BK) {
    __syncthreads();
    #pragma unroll
    for (int j = 0; j < ACH/256; j++) GLOAD16(aSrc[j] + kt, (char*)As + aDst[j]);
    #pragma unroll
    for (int j = 0; j < BCH/256; j++) GLOAD16(bSrc[j] + kt, (char*)Bs + bDst[j]);
    __syncthreads();
    bf16x8 af[4], bfr[NF];
    #pragma unroll
    for (int m = 0; m < 4; m++) af[m] = *(const bf16x8*)((const char*)As + aOff[m]);
    #pragma unroll
    for (int n = 0; n < NF; n++) bfr[n] = *(const bf16x8*)((const char*)Bs + bOff[n]);
    #pragma unroll
    for (int m = 0; m < 4; m++)
      #pragma unroll
      for (int n = 0; n < NF; n++)
        acc[m][n] = __builtin_amdgcn_mfma_f32_16x16x32_bf16(af[m], bfr[n], acc[m][n], 0, 0, 0);
  }
  #pragma unroll
  for (int m = 0; m < 4; m++) {
    int rb = row0 + wr*64 + m*16 + ((lane >> 4) << 2);
    #pragma unroll
    for (int n = 0; n < NF; n++) {
      int c = col0 + wc*(BN/2) + n*16 + (lane & 15);
      float bv = bias[c];
      #pragma unroll
      for (int j = 0; j < 4; j++) {
        size_t idx = (size_t)(rb + j)*N + c;
        float v = acc[m][n][j] + bv;
        if (MODE == 1)      Cb[idx] = f2b(gelu_exact(v));
        else if (MODE == 2) Cf[idx] = v + R[idx];
        else                Cf[idx] = v;
      }
    }
  }
}

// ---------------- embed + positional encoding ----------------
__global__ __launch_bounds__(512) void embed_kernel(const float* __restrict__ src,
    const float* __restrict__ Wemb, const float* __restrict__ bemb,
    float* __restrict__ X, ushort* __restrict__ Xb)
{
  int row = blockIdx.x, l = row & (L_-1), t = threadIdx.x;
  __shared__ float s_src[32];
  if (t < 32) s_src[t] = src[row*32 + t];
  __syncthreads();
  float acc = bemb[t];
  #pragma unroll
  for (int k = 0; k < 32; k++) acc += s_src[k]*Wemb[k*DM + t];
  int i2 = t & ~1;
  float freq = expf((float)i2 * (-9.210340371976184f/512.0f));
  float ang = (float)l * freq;
  acc += (t & 1) ? cosf(ang) : sinf(ang);
  size_t idx = (size_t)row*DM + t;
  X[idx] = acc;
  Xb[idx] = f2b(acc);
}

// ---------------- QK_sample -> M score ----------------
__global__ __launch_bounds__(64) void qksample_kernel(const float* __restrict__ QKV,
    const int* __restrict__ idx_s, float* __restrict__ Msc)
{
  int gid = blockIdx.x;
  int i = gid & (L_-1), h = (gid >> 10) & 7, b = gid >> 13;
  int e = threadIdx.x;
  float q = QKV[((size_t)(b*L_ + i))*QS + h*HD + e];
  float mx = -3.4e38f, sm = 0.f;
  for (int j = 0; j < KS; j++) {
    int s = idx_s[i*KS + j];
    float p = q * QKV[((size_t)(b*L_ + s))*QS + 512 + h*HD + e];
    #pragma unroll
    for (int off = 32; off; off >>= 1) p += __shfl_xor(p, off);
    mx = fmaxf(mx, p); sm += p;
  }
  if (e == 0) Msc[gid] = mx - sm*(1.0f/KS);
}

// ---------------- single-wave top-35 (tie-break lower index) ----------------
__global__ __launch_bounds__(64) void topk_kernel(const float* __restrict__ Msc, int* __restrict__ idx_top)
{
  int bh = blockIdx.x, t = threadIdx.x;
  __shared__ float vals[L_];
  for (int i = t; i < L_; i += 64) vals[i] = Msc[(size_t)bh*L_ + i];
  __syncthreads();
  for (int sel = 0; sel < KS; sel++) {
    float bv = -3.4e38f; int bi = 0x7fffffff;
    for (int i = t; i < L_; i += 64) {
      float v = vals[i];
      if (v > bv || (v == bv && i < bi)) { bv = v; bi = i; }
    }
    #pragma unroll
    for (int off = 32; off; off >>= 1) {
      float ov = __shfl_xor(bv, off); int oi = __shfl_xor(bi, off);
      if (ov > bv || (ov == bv && oi < bi)) { bv = ov; bi = oi; }
    }
    if (t == 0) idx_top[bh*KS + sel] = bi;
    if (t == (bi & 63)) vals[bi] = -3.4e38f;
    __syncthreads();
  }
}

// ---------------- V mean over L ----------------
__global__ __launch_bounds__(256) void vmean_kernel(const float* __restrict__ QKV, float* __restrict__ Vmean)
{
  int bh = blockIdx.x, h = bh & 7, b = bh >> 3;
  int g = threadIdx.x >> 6, e = threadIdx.x & 63;
  __shared__ float p[4][64];
  const float* Vb = QKV + 1024 + h*HD + (size_t)b*L_*QS;
  float s = 0.f;
  for (int l = g; l < L_; l += 4) s += Vb[(size_t)l*QS + e];
  p[g][e] = s;
  __syncthreads();
  if (threadIdx.x < 64)
    Vmean[bh*HD + threadIdx.x] =
      (p[0][threadIdx.x]+p[1][threadIdx.x]+p[2][threadIdx.x]+p[3][threadIdx.x]) * (1.f/L_);
}

// ---------------- fill context with broadcast V-mean (bf16) ----------------
__global__ __launch_bounds__(512) void ctxfill_kernel(const float* __restrict__ Vmean, ushort* __restrict__ CTXb)
{
  int row = blockIdx.x, b = row >> 10, t = threadIdx.x;
  CTXb[(size_t)row*DM + t] = f2b(Vmean[b*DM + t]);
}

// ---------------- chunked flash attention, phase A (register-lean rewrite) ----------------
// grid: (b*8+h)*8 + chunk  (256 blocks), block 256
__global__ __launch_bounds__(256) void attn_part_kernel(const float* __restrict__ QKV,
    const int* __restrict__ idx_top,
    float* __restrict__ Pacc, float* __restrict__ Pm, float* __restrict__ Pl)
{
  int gid = blockIdx.x;
  int bh = gid >> 3, c = gid & 7;
  int h = bh & 7, b = bh >> 3;
  int t = threadIdx.x;
  __shared__ float qs[35][68];          // scaled Q rows (padded pitch)
  __shared__ float sc[35][132];         // scores -> exp'd scores
  __shared__ float sm[35], sl[35];

  // load + scale Q rows
  for (int idx = t; idx < 35*64; idx += 256) {
    int u = idx >> 6, e = idx & 63;
    int qi = idx_top[bh*KS + u];
    qs[u][e] = QKV[((size_t)(b*L_ + qi))*QS + h*HD + e] * 0.125f;
  }
  __syncthreads();

  // scores: thread k = t&127 owns one key; K row in 16 float4 regs; single scalar acc per u
  {
    int k = t & 127, par = t >> 7;     // two halves split u by parity
    const float4* Kr = (const float4*)(QKV + ((size_t)(b*L_ + c*CH + k))*QS + 512 + h*HD);
    float4 kreg[16];
    #pragma unroll
    for (int e4 = 0; e4 < 16; e4++) kreg[e4] = Kr[e4];
    for (int u = par; u < 35; u += 2) {
      float d = 0.f;
      #pragma unroll
      for (int e4 = 0; e4 < 16; e4++) {
        float4 q4 = *(const float4*)&qs[u][e4*4];   // wave-uniform broadcast
        float4 k4 = kreg[e4];
        d += q4.x*k4.x + q4.y*k4.y + q4.z*k4.z + q4.w*k4.w;
      }
      sc[u][k] = d;
    }
  }
  __syncthreads();

  // softmax per u: 4 threads/u, strided keys (2-way bank alias = free)
  {
    int u = t >> 2, sub = t & 3;
    if (u < 35) {
      float m = -3.4e38f;
      for (int i = sub; i < 128; i += 4) m = fmaxf(m, sc[u][i]);
      m = fmaxf(m, __shfl_xor(m, 1));
      m = fmaxf(m, __shfl_xor(m, 2));
      float l = 0.f;
      for (int i = sub; i < 128; i += 4) {
        float ev = expf(sc[u][i] - m);
        sc[u][i] = ev;
        l += ev;
      }
      l += __shfl_xor(l, 1);
      l += __shfl_xor(l, 2);
      if (sub == 0) { sm[u] = m; sl[u] = l; }
    }
  }
  __syncthreads();

  // partial PV: thread = (ug, e); u in {ug, ug+4, ...}; scalar V loads (coalesced)
  {
    int e = t & 63, ug = t >> 6;
    const float* Vb = QKV + 1024 + h*HD + ((size_t)(b*L_ + c*CH))*QS;
    float acc[9];
    #pragma unroll
    for (int iu = 0; iu < 9; iu++) acc[iu] = 0.f;
    for (int kb = 0; kb < CH; kb++) {
      float v = Vb[(size_t)kb*QS + e];
      #pragma unroll
      for (int iu = 0; iu < 9; iu++) {
        int u = ug + iu*4;
        if (u < 35) acc[iu] += sc[u][kb] * v;     // sc read is wave-uniform broadcast
      }
    }
    #pragma unroll
    for (int iu = 0; iu < 9; iu++) {
      int u = ug + iu*4;
      if (u < 35) Pacc[((size_t)gid*35 + u)*64 + e] = acc[iu];
    }
  }
  if (t < 35) { Pm[gid*35 + t] = sm[t]; Pl[gid*35 + t] = sl[t]; }
}

// ---------------- phase B: merge partials, scatter bf16 ctx ----------------
__global__ __launch_bounds__(256) void attn_merge_kernel(const float* __restrict__ Pacc,
    const float* __restrict__ Pm, const float* __restrict__ Pl,
    const int* __restrict__ idx_top, ushort* __restrict__ CTXb)
{
  int bh = blockIdx.x;
  int h = bh & 7, b = bh >> 3;
  int t = threadIdx.x;
  __shared__ float m8[NCH*35], l8[NCH*35];
  for (int i = t; i < NCH*35; i += 256) {
    int c = i / 35, u = i - c*35;
    m8[c*35 + u] = Pm[((size_t)bh*NCH + c)*35 + u];
    l8[c*35 + u] = Pl[((size_t)bh*NCH + c)*35 + u];
  }
  __syncthreads();
  int e = t & 63, ug = t >> 6;
  #pragma unroll
  for (int iu = 0; iu < 9; iu++) {
    int u = ug + iu*4;
    if (u >= 35) break;
    float M = -3.4e38f;
    #pragma unroll
    for (int c = 0; c < NCH; c++) M = fmaxf(M, m8[c*35 + u]);
    float Ltot = 0.f, o = 0.f;
    #pragma unroll
    for (int c = 0; c < NCH; c++) {
      float w = expf(m8[c*35 + u] - M);
      Ltot += w * l8[c*35 + u];
      o += w * Pacc[(((size_t)bh*NCH + c)*35 + u)*64 + e];
    }
    int qi = idx_top[bh*KS + u];
    CTXb[((size_t)(b*L_ + qi))*DM + h*HD + e] = f2b(o / Ltot);
  }
}

// ---------------- LayerNorm (optional add), f32 + bf16 out ----------------
__global__ __launch_bounds__(512) void ln_kernel(const float* __restrict__ Xa,
    const float* __restrict__ Xadd, const float* __restrict__ g, const float* __restrict__ beta,
    float* __restrict__ outf, ushort* __restrict__ outb)
{
  int row = blockIdx.x, t = threadIdx.x;
  __shared__ float red[16];
  size_t idx = (size_t)row*DM + t;
  float v = Xa[idx];
  if (Xadd) v += Xadd[idx];
  float s = v;
  #pragma unroll
  for (int off = 32; off; off >>= 1) s += __shfl_xor(s, off);
  if ((t & 63) == 0) red[t >> 6] = s;
  __syncthreads();
  float mean = 0.f;
  #pragma unroll
  for (int k = 0; k < 8; k++) mean += red[k];
  mean *= (1.f/DM);
  float d = v - mean, q = d*d;
  #pragma unroll
  for (int off = 32; off; off >>= 1) q += __shfl_xor(q, off);
  if ((t & 63) == 0) red[8 + (t >> 6)] = q;
  __syncthreads();
  float var = 0.f;
  #pragma unroll
  for (int k = 0; k < 8; k++) var += red[8 + k];
  var *= (1.f/DM);
  float r = d / sqrtf(var + 1e-5f) * g[t] + beta[t];
  outf[idx] = r;
  if (outb) outb[idx] = f2b(r);
}

// ---------------- partial mean pool + classifier ----------------
__global__ __launch_bounds__(512) void poolp_kernel(const float* __restrict__ X, float* __restrict__ pooledP)
{
  int p = blockIdx.x;
  int t = threadIdx.x;
  int b = p >> 3, seg = p & 7;
  float s = 0.f;
  const float* base = X + ((size_t)b*L_ + seg*128)*DM + t;
  for (int l = 0; l < 128; l++) s += base[(size_t)l*DM];
  pooledP[p*DM + t] = s;
}

__global__ __launch_bounds__(64) void cls_kernel(const float* __restrict__ pooledP,
    const float* __restrict__ Wc, const float* __restrict__ bc, float* __restrict__ out)
{
  int o = blockIdx.x;
  int b = o/10, c = o%10, t = threadIdx.x;
  float s = 0.f;
  for (int d = t; d < DM; d += 64) {
    float p = 0.f;
    #pragma unroll
    for (int seg = 0; seg < 8; seg++) p += pooledP[(b*8 + seg)*DM + d];
    s += p * (1.f/L_) * Wc[d*10 + c];
  }
  #pragma unroll
  for (int off = 32; off; off >>= 1) s += __shfl_xor(s, off);
  if (t == 0) out[o] = bc[c] + s;
}

extern "C" void kernel_launch(void* const* d_in, const int* in_sizes, int n_in,
                              void* d_out, int out_size, void* d_ws, size_t ws_size,
                              hipStream_t stream)
{
  const float* src   = (const float*)d_in[0];
  const int*   idxs  = (const int*)d_in[1];
  const float* Wemb  = (const float*)d_in[2];
  const float* bemb  = (const float*)d_in[3];
  const float* Wq    = (const float*)d_in[4];
  const float* bq    = (const float*)d_in[5];
  const float* Wk    = (const float*)d_in[6];
  const float* bk    = (const float*)d_in[7];
  const float* Wv    = (const float*)d_in[8];
  const float* bv    = (const float*)d_in[9];
  const float* Wo    = (const float*)d_in[10];
  const float* bo    = (const float*)d_in[11];
  const float* g1    = (const float*)d_in[12];
  const float* beta1 = (const float*)d_in[13];
  const float* W1    = (const float*)d_in[14];
  const float* bf1   = (const float*)d_in[15];
  const float* W2    = (const float*)d_in[16];
  const float* bf2   = (const float*)d_in[17];
  const float* g2    = (const float*)d_in[18];
  const float* beta2 = (const float*)d_in[19];
  const float* gf    = (const float*)d_in[20];
  const float* betaf = (const float*)d_in[21];
  const float* Wc    = (const float*)d_in[22];
  const float* bc    = (const float*)d_in[23];
  float* out = (float*)d_out;

  float* wsf = (float*)d_ws;
  float*  X     = wsf;                              // [0, 2097152)
  ushort* Xb    = (ushort*)(wsf + 2097152);         // [2097152, 3145728)
  ushort* CTXb  = (ushort*)(wsf + 3145728);         // [3145728, 4194304)
  float*  QKV   = wsf + 4194304;                    // [4194304, 10485760)  LIVE during attention
  ushort* H     = (ushort*)(wsf + 4194304);         // FFN hidden bf16 (QKV dead by FFN1)
  float*  Y     = wsf + 8388608;                    // [8388608, 10485760)  FFN2 out (QKV dead)
  // attention partials: alias Xb (dead between QKV-GEMM and ln1)
  float*  Pacc  = wsf + 2097152;                    // 573,440 fl <= Xb's 1,048,576
  ushort* Wqkvt = (ushort*)(wsf + 10485760);        // 786,432 fl
  ushort* Wot   = (ushort*)(wsf + 11272192);        // 262,144 fl
  ushort* W1t   = (ushort*)(wsf + 11534336);        // 1,048,576 fl
  ushort* W2t   = (ushort*)(wsf + 12582912);        // 1,048,576 fl
  float*  bqkv  = wsf + 13631488;                   // 3,072
  float*  Msc   = wsf + 13634560;                   // 32,768 (dead after topk)
  float*  Pm    = wsf + 13634560;                   // alias Msc: 8,960
  float*  Pl    = wsf + 13634560 + 8960;            // alias Msc: 8,960
  float*  Vmean = wsf + 13667328;                   // 2,048
  float*  pooledP = wsf + 13669376;                 // 16,384
  int*    idx_top = (int*)(wsf + 13685760);         // 1,120

  for (int l = 0; l < 2; l++) {
    wconv_kernel<<<dim3(DM/32, DM/32), 256, 0, stream>>>(Wq + (size_t)l*DM*DM, Wqkvt + ((size_t)l*QS +    0)*DM, DM, DM);
    wconv_kernel<<<dim3(DM/32, DM/32), 256, 0, stream>>>(Wk + (size_t)l*DM*DM, Wqkvt + ((size_t)l*QS +  512)*DM, DM, DM);
    wconv_kernel<<<dim3(DM/32, DM/32), 256, 0, stream>>>(Wv + (size_t)l*DM*DM, Wqkvt + ((size_t)l*QS + 1024)*DM, DM, DM);
    wconv_kernel<<<dim3(DM/32, DM/32), 256, 0, stream>>>(Wo + (size_t)l*DM*DM, Wot + (size_t)l*DM*DM, DM, DM);
    wconv_kernel<<<dim3(DFF/32, DM/32), 256, 0, stream>>>(W1 + (size_t)l*DM*DFF, W1t + (size_t)l*DFF*DM, DM, DFF);
    wconv_kernel<<<dim3(DM/32, DFF/32), 256, 0, stream>>>(W2 + (size_t)l*DFF*DM, W2t + (size_t)l*DM*DFF, DFF, DM);
  }
  bcat_kernel<<<12, 256, 0, stream>>>(bq, bk, bv, bqkv);

  const int M = B_ * L_; // 4096
  embed_kernel<<<M, 512, 0, stream>>>(src, Wemb, bemb, X, Xb);

  for (int l = 0; l < 2; l++) {
    const size_t vo = (size_t)l*DM;
    mfma_gemm<128,0><<<dim3(QS/128, M/128), 256, 0, stream>>>(
        Xb, Wqkvt + (size_t)l*QS*DM, bqkv + (size_t)l*QS, nullptr, QKV, nullptr, M, QS, DM);
    qksample_kernel<<<B_*NH*L_, 64, 0, stream>>>(QKV, idxs + (size_t)l*L_*KS, Msc);
    topk_kernel<<<B_*NH, 64, 0, stream>>>(Msc, idx_top);
    vmean_kernel<<<B_*NH, 256, 0, stream>>>(QKV, Vmean);
    ctxfill_kernel<<<M, 512, 0, stream>>>(Vmean, CTXb);
    attn_part_kernel<<<B_*NH*NCH, 256, 0, stream>>>(QKV, idx_top, Pacc, Pm, Pl);
    attn_merge_kernel<<<B_*NH, 256, 0, stream>>>(Pacc, Pm, Pl, idx_top, CTXb);
    mfma_gemm<64,2><<<dim3(DM/64, M/128), 256, 0, stream>>>(
        CTXb, Wot + (size_t)l*DM*DM, bo + vo, X, X, nullptr, M, DM, DM);
    ln_kernel<<<M, 512, 0, stream>>>(X, nullptr, g1 + vo, beta1 + vo, X, Xb);
    mfma_gemm<128,1><<<dim3(DFF/128, M/128), 256, 0, stream>>>(
        Xb, W1t + (size_t)l*DFF*DM, bf1 + (size_t)l*DFF, nullptr, nullptr, H, M, DFF, DM);
    mfma_gemm<64,0><<<dim3(DM/64, M/128), 256, 0, stream>>>(
        H, W2t + (size_t)l*DM*DFF, bf2 + vo, nullptr, Y, nullptr, M, DM, DFF);
    ln_kernel<<<M, 512, 0, stream>>>(X, Y, g2 + vo, beta2 + vo, X, Xb);
  }
  ln_kernel<<<M, 512, 0, stream>>>(X, nullptr, gf, betaf, X, nullptr);
  poolp_kernel<<<B_*8, 512, 0, stream>>>(X, pooledP);
  cls_kernel<<<40, 64, 0, stream>>>(pooledP, Wc, bc, out);
}

// Round 7
// 759.269 us; speedup vs baseline: 1.3514x; 1.1560x over previous
//
#include <hip/hip_runtime.h>
#include <hip/hip_bf16.h>
#include <math.h>

#define B_ 4
#define L_ 1024
#define DM 512
#define NH 8
#define HD 64
#define DFF 2048
#define KS 35
#define QS 1536   // packed QKV row stride
#define CH 128    // attention key chunk
#define NCH (L_/CH)

typedef __attribute__((ext_vector_type(8))) short bf16x8;
typedef __attribute__((ext_vector_type(4))) float f32x4;

__device__ inline ushort f2b(float f){
  __hip_bfloat16 h = __float2bfloat16(f);
  return *reinterpret_cast<ushort*>(&h);
}
__device__ inline float gelu_exact(float x){
  return 0.5f*x*(1.0f+erff(x*0.7071067811865476f));
}

#define GLOAD16(g, l) __builtin_amdgcn_global_load_lds( \
    (const __attribute__((address_space(1))) void*)(g), \
    (__attribute__((address_space(3))) void*)(l), 16, 0, 0)

// ---------------- weight convert + transpose to bf16 [N][K] ----------------
__global__ __launch_bounds__(256) void wconv_kernel(const float* __restrict__ W,
    ushort* __restrict__ Wt, int K, int N)
{
  __shared__ float tile[32][33];
  int n0 = blockIdx.x*32, k0 = blockIdx.y*32;
  int tx = threadIdx.x & 31, ty = threadIdx.x >> 5;
  #pragma unroll
  for (int i = ty; i < 32; i += 8) tile[i][tx] = W[(size_t)(k0+i)*N + n0+tx];
  __syncthreads();
  #pragma unroll
  for (int i = ty; i < 32; i += 8) Wt[(size_t)(n0+i)*K + k0+tx] = f2b(tile[tx][i]);
}

__global__ __launch_bounds__(256) void bcat_kernel(const float* __restrict__ bq,
    const float* __restrict__ bk, const float* __restrict__ bv, float* __restrict__ bqkv)
{
  int i = blockIdx.x*256 + threadIdx.x;   // 0..3071
  if (i >= 2*QS) return;
  int l = i / QS, j = i - l*QS;
  const float* src = (j < 512) ? bq : (j < 1024 ? bk : bv);
  bqkv[i] = src[l*DM + (j & 511)];
}

// ---------------- bf16 MFMA GEMM, double-buffered (2-phase) ----------------
// A: [M][K] bf16; Bt: [N][K] bf16; MODE 0: f32 out, 1: gelu->bf16 out, 2: +R f32 out
template<int BN, int MODE>
__global__ __launch_bounds__(256) void mfma_gemm(
    const ushort* __restrict__ A, const ushort* __restrict__ Bt,
    const float* __restrict__ bias, const float* __restrict__ R,
    float* __restrict__ Cf, ushort* __restrict__ Cb,
    int M, int N, int K)
{
  constexpr int BM = 128, BK = 32;
  constexpr int NF = BN/32;
  constexpr int ACH = BM*4;          // 16B chunks per A tile
  constexpr int BCH = BN*4;
  __shared__ __align__(16) ushort As[2][BM*BK];
  __shared__ __align__(16) ushort Bs[2][BN*BK];
  const int t = threadIdx.x, lane = t & 63, w = t >> 6, wr = w >> 1, wc = w & 1;
  const int row0 = blockIdx.y*BM, col0 = blockIdx.x*BN;

  // staging: linear LDS dest, inverse-swizzled global source
  const ushort* aSrc[ACH/256]; int aDst[ACH/256];
  #pragma unroll
  for (int j = 0; j < ACH/256; j++) {
    int ch = j*256 + t, r = ch >> 2, cc = ch & 3, cs = cc ^ ((r >> 1) & 3);
    aSrc[j] = A + (size_t)(row0 + r)*K + cs*8;
    aDst[j] = ch*16;
  }
  const ushort* bSrc[BCH/256]; int bDst[BCH/256];
  #pragma unroll
  for (int j = 0; j < BCH/256; j++) {
    int ch = j*256 + t, r = ch >> 2, cc = ch & 3, cs = cc ^ ((r >> 1) & 3);
    bSrc[j] = Bt + (size_t)(col0 + r)*K + cs*8;
    bDst[j] = ch*16;
  }
  // fragment read offsets (swizzled)
  int aOff[4], bOff[NF];
  #pragma unroll
  for (int m = 0; m < 4; m++) {
    int r = wr*64 + m*16 + (lane & 15);
    aOff[m] = r*64 + (((lane >> 4)*16) ^ (((r >> 1) & 3) << 4));
  }
  #pragma unroll
  for (int n = 0; n < NF; n++) {
    int r = wc*(BN/2) + n*16 + (lane & 15);
    bOff[n] = r*64 + (((lane >> 4)*16) ^ (((r >> 1) & 3) << 4));
  }
  f32x4 zero = {0.f, 0.f, 0.f, 0.f};
  f32x4 acc[4][NF];
  #pragma unroll
  for (int m = 0; m < 4; m++)
    #pragma unroll
    for (int n = 0; n < NF; n++) acc[m][n] = zero;

  // prologue: stage tile 0 into buf 0
  #pragma unroll
  for (int j = 0; j < ACH/256; j++) GLOAD16(aSrc[j], (char*)As[0] + aDst[j]);
  #pragma unroll
  for (int j = 0; j < BCH/256; j++) GLOAD16(bSrc[j], (char*)Bs[0] + bDst[j]);
  __syncthreads();

  const int nk = K / BK;
  for (int ki = 0; ki < nk; ki++) {
    const int cur = ki & 1;
    if (ki + 1 < nk) {               // issue next-tile loads first (overlap with MFMA)
      const int kt = (ki + 1)*BK;
      #pragma unroll
      for (int j = 0; j < ACH/256; j++) GLOAD16(aSrc[j] + kt, (char*)As[cur^1] + aDst[j]);
      #pragma unroll
      for (int j = 0; j < BCH/256; j++) GLOAD16(bSrc[j] + kt, (char*)Bs[cur^1] + bDst[j]);
    }
    bf16x8 af[4], bfr[NF];
    #pragma unroll
    for (int m = 0; m < 4; m++) af[m] = *(const bf16x8*)((const char*)As[cur] + aOff[m]);
    #pragma unroll
    for (int n = 0; n < NF; n++) bfr[n] = *(const bf16x8*)((const char*)Bs[cur] + bOff[n]);
    #pragma unroll
    for (int m = 0; m < 4; m++)
      #pragma unroll
      for (int n = 0; n < NF; n++)
        acc[m][n] = __builtin_amdgcn_mfma_f32_16x16x32_bf16(af[m], bfr[n], acc[m][n], 0, 0, 0);
    __syncthreads();                 // drains next-tile vmem writes + this-tile LDS reads
  }
  #pragma unroll
  for (int m = 0; m < 4; m++) {
    int rb = row0 + wr*64 + m*16 + ((lane >> 4) << 2);
    #pragma unroll
    for (int n = 0; n < NF; n++) {
      int c = col0 + wc*(BN/2) + n*16 + (lane & 15);
      float bv = bias[c];
      #pragma unroll
      for (int j = 0; j < 4; j++) {
        size_t idx = (size_t)(rb + j)*N + c;
        float v = acc[m][n][j] + bv;
        if (MODE == 1)      Cb[idx] = f2b(gelu_exact(v));
        else if (MODE == 2) Cf[idx] = v + R[idx];
        else                Cf[idx] = v;
      }
    }
  }
}

// ---------------- embed + positional encoding ----------------
__global__ __launch_bounds__(512) void embed_kernel(const float* __restrict__ src,
    const float* __restrict__ Wemb, const float* __restrict__ bemb,
    float* __restrict__ X, ushort* __restrict__ Xb)
{
  int row = blockIdx.x, l = row & (L_-1), t = threadIdx.x;
  __shared__ float s_src[32];
  if (t < 32) s_src[t] = src[row*32 + t];
  __syncthreads();
  float acc = bemb[t];
  #pragma unroll
  for (int k = 0; k < 32; k++) acc += s_src[k]*Wemb[k*DM + t];
  int i2 = t & ~1;
  float freq = expf((float)i2 * (-9.210340371976184f/512.0f));
  float ang = (float)l * freq;
  acc += (t & 1) ? cosf(ang) : sinf(ang);
  size_t idx = (size_t)row*DM + t;
  X[idx] = acc;
  Xb[idx] = f2b(acc);
}

// ---------------- QK_sample -> M score (j-parallel, short chains) ----------------
__global__ __launch_bounds__(64) void qksample_kernel(const float* __restrict__ QKV,
    const int* __restrict__ idx_s, float* __restrict__ Msc)
{
  int gid = blockIdx.x;              // (b*8+h)*1024 + i
  int i = gid & (L_-1), h = (gid >> 10) & 7, b = gid >> 13;
  int t = threadIdx.x;
  int j4 = t >> 2, e4 = t & 3;       // lane = j4*4 + e4
  const float* Qrow = QKV + ((size_t)(b*L_ + i))*QS + h*HD + e4*16;
  float4 q[4];
  #pragma unroll
  for (int r = 0; r < 4; r++) q[r] = *(const float4*)(Qrow + r*4);
  const float* Kbase = QKV + 512 + h*HD + (size_t)b*L_*QS + e4*16;
  const int* idq = idx_s + i*KS;
  float mx = -3.4e38f, sm = 0.f;
  #pragma unroll
  for (int p = 0; p < 3; p++) {
    int j = p*16 + j4;
    int jc = (j < KS) ? j : 0;       // inactive lanes redo j=0 (result discarded)
    int s = idq[jc];
    const float4* Kr = (const float4*)(Kbase + (size_t)s*QS);
    float4 k0 = Kr[0], k1 = Kr[1], k2 = Kr[2], k3 = Kr[3];
    float d = q[0].x*k0.x + q[0].y*k0.y + q[0].z*k0.z + q[0].w*k0.w;
    d += q[1].x*k1.x + q[1].y*k1.y + q[1].z*k1.z + q[1].w*k1.w;
    d += q[2].x*k2.x + q[2].y*k2.y + q[2].z*k2.z + q[2].w*k2.w;
    d += q[3].x*k3.x + q[3].y*k3.y + q[3].z*k3.z + q[3].w*k3.w;
    d += __shfl_xor(d, 1);
    d += __shfl_xor(d, 2);
    if (j < KS && e4 == 0) { mx = fmaxf(mx, d); sm += d; }
  }
  // lanes with e4!=0 (and j>=KS contributions) never touched mx/sm -> identity values
  #pragma unroll
  for (int off = 4; off < 64; off <<= 1) {
    mx = fmaxf(mx, __shfl_xor(mx, off));
    sm += __shfl_xor(sm, off);
  }
  if (t == 0) Msc[gid] = mx - sm*(1.0f/KS);
}

// ---------------- single-wave top-35 (tie-break lower index) ----------------
__global__ __launch_bounds__(64) void topk_kernel(const float* __restrict__ Msc, int* __restrict__ idx_top)
{
  int bh = blockIdx.x, t = threadIdx.x;
  __shared__ float vals[L_];
  for (int i = t; i < L_; i += 64) vals[i] = Msc[(size_t)bh*L_ + i];
  __syncthreads();
  for (int sel = 0; sel < KS; sel++) {
    float bv = -3.4e38f; int bi = 0x7fffffff;
    for (int i = t; i < L_; i += 64) {
      float v = vals[i];
      if (v > bv || (v == bv && i < bi)) { bv = v; bi = i; }
    }
    #pragma unroll
    for (int off = 32; off; off >>= 1) {
      float ov = __shfl_xor(bv, off); int oi = __shfl_xor(bi, off);
      if (ov > bv || (ov == bv && oi < bi)) { bv = ov; bi = oi; }
    }
    if (t == 0) idx_top[bh*KS + sel] = bi;
    if (t == (bi & 63)) vals[bi] = -3.4e38f;
    __syncthreads();
  }
}

// ---------------- V mean over L ----------------
__global__ __launch_bounds__(256) void vmean_kernel(const float* __restrict__ QKV, float* __restrict__ Vmean)
{
  int bh = blockIdx.x, h = bh & 7, b = bh >> 3;
  int g = threadIdx.x >> 6, e = threadIdx.x & 63;
  __shared__ float p[4][64];
  const float* Vb = QKV + 1024 + h*HD + (size_t)b*L_*QS;
  float s = 0.f;
  for (int l = g; l < L_; l += 4) s += Vb[(size_t)l*QS + e];
  p[g][e] = s;
  __syncthreads();
  if (threadIdx.x < 64)
    Vmean[bh*HD + threadIdx.x] =
      (p[0][threadIdx.x]+p[1][threadIdx.x]+p[2][threadIdx.x]+p[3][threadIdx.x]) * (1.f/L_);
}

// ---------------- fill context with broadcast V-mean (bf16) ----------------
__global__ __launch_bounds__(512) void ctxfill_kernel(const float* __restrict__ Vmean, ushort* __restrict__ CTXb)
{
  int row = blockIdx.x, b = row >> 10, t = threadIdx.x;
  CTXb[(size_t)row*DM + t] = f2b(Vmean[b*DM + t]);
}

// ---------------- chunked flash attention, phase A (register-lean) ----------------
// grid: (b*8+h)*8 + chunk  (256 blocks), block 256
__global__ __launch_bounds__(256) void attn_part_kernel(const float* __restrict__ QKV,
    const int* __restrict__ idx_top,
    float* __restrict__ Pacc, float* __restrict__ Pm, float* __restrict__ Pl)
{
  int gid = blockIdx.x;
  int bh = gid >> 3, c = gid & 7;
  int h = bh & 7, b = bh >> 3;
  int t = threadIdx.x;
  __shared__ float qs[35][68];          // scaled Q rows (padded pitch)
  __shared__ float sc[35][132];         // scores -> exp'd scores
  __shared__ float sm[35], sl[35];

  // load + scale Q rows
  for (int idx = t; idx < 35*64; idx += 256) {
    int u = idx >> 6, e = idx & 63;
    int qi = idx_top[bh*KS + u];
    qs[u][e] = QKV[((size_t)(b*L_ + qi))*QS + h*HD + e] * 0.125f;
  }
  __syncthreads();

  // scores: thread k = t&127 owns one key; K row in 16 float4 regs
  {
    int k = t & 127, par = t >> 7;
    const float4* Kr = (const float4*)(QKV + ((size_t)(b*L_ + c*CH + k))*QS + 512 + h*HD);
    float4 kreg[16];
    #pragma unroll
    for (int e4 = 0; e4 < 16; e4++) kreg[e4] = Kr[e4];
    for (int u = par; u < 35; u += 2) {
      float d = 0.f;
      #pragma unroll
      for (int e4 = 0; e4 < 16; e4++) {
        float4 q4 = *(const float4*)&qs[u][e4*4];   // wave-uniform broadcast
        float4 k4 = kreg[e4];
        d += q4.x*k4.x + q4.y*k4.y + q4.z*k4.z + q4.w*k4.w;
      }
      sc[u][k] = d;
    }
  }
  __syncthreads();

  // softmax per u: 4 threads/u
  {
    int u = t >> 2, sub = t & 3;
    if (u < 35) {
      float m = -3.4e38f;
      for (int i = sub; i < 128; i += 4) m = fmaxf(m, sc[u][i]);
      m = fmaxf(m, __shfl_xor(m, 1));
      m = fmaxf(m, __shfl_xor(m, 2));
      float l = 0.f;
      for (int i = sub; i < 128; i += 4) {
        float ev = expf(sc[u][i] - m);
        sc[u][i] = ev;
        l += ev;
      }
      l += __shfl_xor(l, 1);
      l += __shfl_xor(l, 2);
      if (sub == 0) { sm[u] = m; sl[u] = l; }
    }
  }
  __syncthreads();

  // partial PV: thread = (ug, e)
  {
    int e = t & 63, ug = t >> 6;
    const float* Vb = QKV + 1024 + h*HD + ((size_t)(b*L_ + c*CH))*QS;
    float acc[9];
    #pragma unroll
    for (int iu = 0; iu < 9; iu++) acc[iu] = 0.f;
    for (int kb = 0; kb < CH; kb++) {
      float v = Vb[(size_t)kb*QS + e];
      #pragma unroll
      for (int iu = 0; iu < 9; iu++) {
        int u = ug + iu*4;
        if (u < 35) acc[iu] += sc[u][kb] * v;
      }
    }
    #pragma unroll
    for (int iu = 0; iu < 9; iu++) {
      int u = ug + iu*4;
      if (u < 35) Pacc[((size_t)gid*35 + u)*64 + e] = acc[iu];
    }
  }
  if (t < 35) { Pm[gid*35 + t] = sm[t]; Pl[gid*35 + t] = sl[t]; }
}

// ---------------- phase B: merge partials, scatter bf16 ctx ----------------
__global__ __launch_bounds__(256) void attn_merge_kernel(const float* __restrict__ Pacc,
    const float* __restrict__ Pm, const float* __restrict__ Pl,
    const int* __restrict__ idx_top, ushort* __restrict__ CTXb)
{
  int bh = blockIdx.x;
  int h = bh & 7, b = bh >> 3;
  int t = threadIdx.x;
  __shared__ float m8[NCH*35], l8[NCH*35];
  for (int i = t; i < NCH*35; i += 256) {
    int c = i / 35, u = i - c*35;
    m8[c*35 + u] = Pm[((size_t)bh*NCH + c)*35 + u];
    l8[c*35 + u] = Pl[((size_t)bh*NCH + c)*35 + u];
  }
  __syncthreads();
  int e = t & 63, ug = t >> 6;
  #pragma unroll
  for (int iu = 0; iu < 9; iu++) {
    int u = ug + iu*4;
    if (u >= 35) break;
    float M = -3.4e38f;
    #pragma unroll
    for (int c = 0; c < NCH; c++) M = fmaxf(M, m8[c*35 + u]);
    float Ltot = 0.f, o = 0.f;
    #pragma unroll
    for (int c = 0; c < NCH; c++) {
      float w = expf(m8[c*35 + u] - M);
      Ltot += w * l8[c*35 + u];
      o += w * Pacc[(((size_t)bh*NCH + c)*35 + u)*64 + e];
    }
    int qi = idx_top[bh*KS + u];
    CTXb[((size_t)(b*L_ + qi))*DM + h*HD + e] = f2b(o / Ltot);
  }
}

// ---------------- LayerNorm (optional add), f32 + bf16 out ----------------
__global__ __launch_bounds__(512) void ln_kernel(const float* __restrict__ Xa,
    const float* __restrict__ Xadd, const float* __restrict__ g, const float* __restrict__ beta,
    float* __restrict__ outf, ushort* __restrict__ outb)
{
  int row = blockIdx.x, t = threadIdx.x;
  __shared__ float red[16];
  size_t idx = (size_t)row*DM + t;
  float v = Xa[idx];
  if (Xadd) v += Xadd[idx];
  float s = v;
  #pragma unroll
  for (int off = 32; off; off >>= 1) s += __shfl_xor(s, off);
  if ((t & 63) == 0) red[t >> 6] = s;
  __syncthreads();
  float mean = 0.f;
  #pragma unroll
  for (int k = 0; k < 8; k++) mean += red[k];
  mean *= (1.f/DM);
  float d = v - mean, q = d*d;
  #pragma unroll
  for (int off = 32; off; off >>= 1) q += __shfl_xor(q, off);
  if ((t & 63) == 0) red[8 + (t >> 6)] = q;
  __syncthreads();
  float var = 0.f;
  #pragma unroll
  for (int k = 0; k < 8; k++) var += red[8 + k];
  var *= (1.f/DM);
  float r = d / sqrtf(var + 1e-5f) * g[t] + beta[t];
  outf[idx] = r;
  if (outb) outb[idx] = f2b(r);
}

// ---------------- partial mean pool + classifier ----------------
__global__ __launch_bounds__(512) void poolp_kernel(const float* __restrict__ X, float* __restrict__ pooledP)
{
  int p = blockIdx.x;
  int t = threadIdx.x;
  int b = p >> 3, seg = p & 7;
  float s = 0.f;
  const float* base = X + ((size_t)b*L_ + seg*128)*DM + t;
  for (int l = 0; l < 128; l++) s += base[(size_t)l*DM];
  pooledP[p*DM + t] = s;
}

__global__ __launch_bounds__(64) void cls_kernel(const float* __restrict__ pooledP,
    const float* __restrict__ Wc, const float* __restrict__ bc, float* __restrict__ out)
{
  int o = blockIdx.x;
  int b = o/10, c = o%10, t = threadIdx.x;
  float s = 0.f;
  for (int d = t; d < DM; d += 64) {
    float p = 0.f;
    #pragma unroll
    for (int seg = 0; seg < 8; seg++) p += pooledP[(b*8 + seg)*DM + d];
    s += p * (1.f/L_) * Wc[d*10 + c];
  }
  #pragma unroll
  for (int off = 32; off; off >>= 1) s += __shfl_xor(s, off);
  if (t == 0) out[o] = bc[c] + s;
}

extern "C" void kernel_launch(void* const* d_in, const int* in_sizes, int n_in,
                              void* d_out, int out_size, void* d_ws, size_t ws_size,
                              hipStream_t stream)
{
  const float* src   = (const float*)d_in[0];
  const int*   idxs  = (const int*)d_in[1];
  const float* Wemb  = (const float*)d_in[2];
  const float* bemb  = (const float*)d_in[3];
  const float* Wq    = (const float*)d_in[4];
  const float* bq    = (const float*)d_in[5];
  const float* Wk    = (const float*)d_in[6];
  const float* bk    = (const float*)d_in[7];
  const float* Wv    = (const float*)d_in[8];
  const float* bv    = (const float*)d_in[9];
  const float* Wo    = (const float*)d_in[10];
  const float* bo    = (const float*)d_in[11];
  const float* g1    = (const float*)d_in[12];
  const float* beta1 = (const float*)d_in[13];
  const float* W1    = (const float*)d_in[14];
  const float* bf1   = (const float*)d_in[15];
  const float* W2    = (const float*)d_in[16];
  const float* bf2   = (const float*)d_in[17];
  const float* g2    = (const float*)d_in[18];
  const float* beta2 = (const float*)d_in[19];
  const float* gf    = (const float*)d_in[20];
  const float* betaf = (const float*)d_in[21];
  const float* Wc    = (const float*)d_in[22];
  const float* bc    = (const float*)d_in[23];
  float* out = (float*)d_out;

  float* wsf = (float*)d_ws;
  float*  X     = wsf;                              // [0, 2097152)
  ushort* Xb    = (ushort*)(wsf + 2097152);         // [2097152, 3145728)
  ushort* CTXb  = (ushort*)(wsf + 3145728);         // [3145728, 4194304)
  float*  QKV   = wsf + 4194304;                    // [4194304, 10485760)  LIVE during attention
  ushort* H     = (ushort*)(wsf + 4194304);         // FFN hidden bf16 (QKV dead by FFN1)
  float*  Y     = wsf + 8388608;                    // [8388608, 10485760)  FFN2 out (QKV dead)
  // attention partials: alias Xb (dead between QKV-GEMM and ln1)
  float*  Pacc  = wsf + 2097152;                    // 573,440 fl <= Xb's 1,048,576
  ushort* Wqkvt = (ushort*)(wsf + 10485760);        // 786,432 fl
  ushort* Wot   = (ushort*)(wsf + 11272192);        // 262,144 fl
  ushort* W1t   = (ushort*)(wsf + 11534336);        // 1,048,576 fl
  ushort* W2t   = (ushort*)(wsf + 12582912);        // 1,048,576 fl
  float*  bqkv  = wsf + 13631488;                   // 3,072
  float*  Msc   = wsf + 13634560;                   // 32,768 (dead after topk)
  float*  Pm    = wsf + 13634560;                   // alias Msc: 8,960
  float*  Pl    = wsf + 13634560 + 8960;            // alias Msc: 8,960
  float*  Vmean = wsf + 13667328;                   // 2,048
  float*  pooledP = wsf + 13669376;                 // 16,384
  int*    idx_top = (int*)(wsf + 13685760);         // 1,120

  for (int l = 0; l < 2; l++) {
    wconv_kernel<<<dim3(DM/32, DM/32), 256, 0, stream>>>(Wq + (size_t)l*DM*DM, Wqkvt + ((size_t)l*QS +    0)*DM, DM, DM);
    wconv_kernel<<<dim3(DM/32, DM/32), 256, 0, stream>>>(Wk + (size_t)l*DM*DM, Wqkvt + ((size_t)l*QS +  512)*DM, DM, DM);
    wconv_kernel<<<dim3(DM/32, DM/32), 256, 0, stream>>>(Wv + (size_t)l*DM*DM, Wqkvt + ((size_t)l*QS + 1024)*DM, DM, DM);
    wconv_kernel<<<dim3(DM/32, DM/32), 256, 0, stream>>>(Wo + (size_t)l*DM*DM, Wot + (size_t)l*DM*DM, DM, DM);
    wconv_kernel<<<dim3(DFF/32, DM/32), 256, 0, stream>>>(W1 + (size_t)l*DM*DFF, W1t + (size_t)l*DFF*DM, DM, DFF);
    wconv_kernel<<<dim3(DM/32, DFF/32), 256, 0, stream>>>(W2 + (size_t)l*DFF*DM, W2t + (size_t)l*DM*DFF, DFF, DM);
  }
  bcat_kernel<<<12, 256, 0, stream>>>(bq, bk, bv, bqkv);

  const int M = B_ * L_; // 4096
  embed_kernel<<<M, 512, 0, stream>>>(src, Wemb, bemb, X, Xb);

  for (int l = 0; l < 2; l++) {
    const size_t vo = (size_t)l*DM;
    mfma_gemm<128,0><<<dim3(QS/128, M/128), 256, 0, stream>>>(
        Xb, Wqkvt + (size_t)l*QS*DM, bqkv + (size_t)l*QS, nullptr, QKV, nullptr, M, QS, DM);
    qksample_kernel<<<B_*NH*L_, 64, 0, stream>>>(QKV, idxs + (size_t)l*L_*KS, Msc);
    topk_kernel<<<B_*NH, 64, 0, stream>>>(Msc, idx_top);
    vmean_kernel<<<B_*NH, 256, 0, stream>>>(QKV, Vmean);
    ctxfill_kernel<<<M, 512, 0, stream>>>(Vmean, CTXb);
    attn_part_kernel<<<B_*NH*NCH, 256, 0, stream>>>(QKV, idx_top, Pacc, Pm, Pl);
    attn_merge_kernel<<<B_*NH, 256, 0, stream>>>(Pacc, Pm, Pl, idx_top, CTXb);
    mfma_gemm<64,2><<<dim3(DM/64, M/128), 256, 0, stream>>>(
        CTXb, Wot + (size_t)l*DM*DM, bo + vo, X, X, nullptr, M, DM, DM);
    ln_kernel<<<M, 512, 0, stream>>>(X, nullptr, g1 + vo, beta1 + vo, X, Xb);
    mfma_gemm<128,1><<<dim3(DFF/128, M/128), 256, 0, stream>>>(
        Xb, W1t + (size_t)l*DFF*DM, bf1 + (size_t)l*DFF, nullptr, nullptr, H, M, DFF, DM);
    mfma_gemm<64,0><<<dim3(DM/64, M/128), 256, 0, stream>>>(
        H, W2t + (size_t)l*DM*DFF, bf2 + vo, nullptr, Y, nullptr, M, DM, DFF);
    ln_kernel<<<M, 512, 0, stream>>>(X, Y, g2 + vo, beta2 + vo, X, Xb);
  }
  ln_kernel<<<M, 512, 0, stream>>>(X, nullptr, gf, betaf, X, nullptr);
  poolp_kernel<<<B_*8, 512, 0, stream>>>(X, pooledP);
  cls_kernel<<<40, 64, 0, stream>>>(pooledP, Wc, bc, out);
}

// Round 8
// 739.686 us; speedup vs baseline: 1.3872x; 1.0265x over previous
//
#include <hip/hip_runtime.h>
#include <hip/hip_bf16.h>
#include <math.h>

#define B_ 4
#define L_ 1024
#define DM 512
#define NH 8
#define HD 64
#define DFF 2048
#define KS 35
#define QS 1536   // packed QKV row stride
#define CH 128    // attention key chunk
#define NCH (L_/CH)

typedef __attribute__((ext_vector_type(8))) short bf16x8;
typedef __attribute__((ext_vector_type(4))) float f32x4;

__device__ inline ushort f2b(float f){
  __hip_bfloat16 h = __float2bfloat16(f);
  return *reinterpret_cast<ushort*>(&h);
}
__device__ inline float gelu_exact(float x){
  return 0.5f*x*(1.0f+erff(x*0.7071067811865476f));
}

#define GLOAD16(g, l) __builtin_amdgcn_global_load_lds( \
    (const __attribute__((address_space(1))) void*)(g), \
    (__attribute__((address_space(3))) void*)(l), 16, 0, 0)

// ---------------- weight convert + transpose to bf16 [N][K] ----------------
__global__ __launch_bounds__(256) void wconv_kernel(const float* __restrict__ W,
    ushort* __restrict__ Wt, int K, int N)
{
  __shared__ float tile[32][33];
  int n0 = blockIdx.x*32, k0 = blockIdx.y*32;
  int tx = threadIdx.x & 31, ty = threadIdx.x >> 5;
  #pragma unroll
  for (int i = ty; i < 32; i += 8) tile[i][tx] = W[(size_t)(k0+i)*N + n0+tx];
  __syncthreads();
  #pragma unroll
  for (int i = ty; i < 32; i += 8) Wt[(size_t)(n0+i)*K + k0+tx] = f2b(tile[tx][i]);
}

__global__ __launch_bounds__(256) void bcat_kernel(const float* __restrict__ bq,
    const float* __restrict__ bk, const float* __restrict__ bv, float* __restrict__ bqkv)
{
  int i = blockIdx.x*256 + threadIdx.x;   // 0..3071
  if (i >= 2*QS) return;
  int l = i / QS, j = i - l*QS;
  const float* src = (j < 512) ? bq : (j < 1024 ? bk : bv);
  bqkv[i] = src[l*DM + (j & 511)];
}

// ---------------- bf16 MFMA GEMM, double-buffered (2-phase) ----------------
// A: [M][K] bf16; Bt: [N][K] bf16; MODE 0: f32 out, 1: gelu->bf16 out, 2: +R f32 out
template<int BN, int MODE>
__global__ __launch_bounds__(256) void mfma_gemm(
    const ushort* __restrict__ A, const ushort* __restrict__ Bt,
    const float* __restrict__ bias, const float* __restrict__ R,
    float* __restrict__ Cf, ushort* __restrict__ Cb,
    int M, int N, int K)
{
  constexpr int BM = 128, BK = 32;
  constexpr int NF = BN/32;
  constexpr int ACH = BM*4;          // 16B chunks per A tile
  constexpr int BCH = BN*4;
  __shared__ __align__(16) ushort As[2][BM*BK];
  __shared__ __align__(16) ushort Bs[2][BN*BK];
  const int t = threadIdx.x, lane = t & 63, w = t >> 6, wr = w >> 1, wc = w & 1;
  const int row0 = blockIdx.y*BM, col0 = blockIdx.x*BN;

  // staging: linear LDS dest, inverse-swizzled global source
  const ushort* aSrc[ACH/256]; int aDst[ACH/256];
  #pragma unroll
  for (int j = 0; j < ACH/256; j++) {
    int ch = j*256 + t, r = ch >> 2, cc = ch & 3, cs = cc ^ ((r >> 1) & 3);
    aSrc[j] = A + (size_t)(row0 + r)*K + cs*8;
    aDst[j] = ch*16;
  }
  const ushort* bSrc[BCH/256]; int bDst[BCH/256];
  #pragma unroll
  for (int j = 0; j < BCH/256; j++) {
    int ch = j*256 + t, r = ch >> 2, cc = ch & 3, cs = cc ^ ((r >> 1) & 3);
    bSrc[j] = Bt + (size_t)(col0 + r)*K + cs*8;
    bDst[j] = ch*16;
  }
  // fragment read offsets (swizzled)
  int aOff[4], bOff[NF];
  #pragma unroll
  for (int m = 0; m < 4; m++) {
    int r = wr*64 + m*16 + (lane & 15);
    aOff[m] = r*64 + (((lane >> 4)*16) ^ (((r >> 1) & 3) << 4));
  }
  #pragma unroll
  for (int n = 0; n < NF; n++) {
    int r = wc*(BN/2) + n*16 + (lane & 15);
    bOff[n] = r*64 + (((lane >> 4)*16) ^ (((r >> 1) & 3) << 4));
  }
  f32x4 zero = {0.f, 0.f, 0.f, 0.f};
  f32x4 acc[4][NF];
  #pragma unroll
  for (int m = 0; m < 4; m++)
    #pragma unroll
    for (int n = 0; n < NF; n++) acc[m][n] = zero;

  // prologue: stage tile 0 into buf 0
  #pragma unroll
  for (int j = 0; j < ACH/256; j++) GLOAD16(aSrc[j], (char*)As[0] + aDst[j]);
  #pragma unroll
  for (int j = 0; j < BCH/256; j++) GLOAD16(bSrc[j], (char*)Bs[0] + bDst[j]);
  __syncthreads();

  const int nk = K / BK;
  for (int ki = 0; ki < nk; ki++) {
    const int cur = ki & 1;
    if (ki + 1 < nk) {               // issue next-tile loads first (overlap with MFMA)
      const int kt = (ki + 1)*BK;
      #pragma unroll
      for (int j = 0; j < ACH/256; j++) GLOAD16(aSrc[j] + kt, (char*)As[cur^1] + aDst[j]);
      #pragma unroll
      for (int j = 0; j < BCH/256; j++) GLOAD16(bSrc[j] + kt, (char*)Bs[cur^1] + bDst[j]);
    }
    bf16x8 af[4], bfr[NF];
    #pragma unroll
    for (int m = 0; m < 4; m++) af[m] = *(const bf16x8*)((const char*)As[cur] + aOff[m]);
    #pragma unroll
    for (int n = 0; n < NF; n++) bfr[n] = *(const bf16x8*)((const char*)Bs[cur] + bOff[n]);
    #pragma unroll
    for (int m = 0; m < 4; m++)
      #pragma unroll
      for (int n = 0; n < NF; n++)
        acc[m][n] = __builtin_amdgcn_mfma_f32_16x16x32_bf16(af[m], bfr[n], acc[m][n], 0, 0, 0);
    __syncthreads();                 // drains next-tile vmem writes + this-tile LDS reads
  }
  #pragma unroll
  for (int m = 0; m < 4; m++) {
    int rb = row0 + wr*64 + m*16 + ((lane >> 4) << 2);
    #pragma unroll
    for (int n = 0; n < NF; n++) {
      int c = col0 + wc*(BN/2) + n*16 + (lane & 15);
      float bv = bias[c];
      #pragma unroll
      for (int j = 0; j < 4; j++) {
        size_t idx = (size_t)(rb + j)*N + c;
        float v = acc[m][n][j] + bv;
        if (MODE == 1)      Cb[idx] = f2b(gelu_exact(v));
        else if (MODE == 2) Cf[idx] = v + R[idx];
        else                Cf[idx] = v;
      }
    }
  }
}

// ---------------- embed + positional encoding ----------------
__global__ __launch_bounds__(512) void embed_kernel(const float* __restrict__ src,
    const float* __restrict__ Wemb, const float* __restrict__ bemb,
    float* __restrict__ X, ushort* __restrict__ Xb)
{
  int row = blockIdx.x, l = row & (L_-1), t = threadIdx.x;
  __shared__ float s_src[32];
  if (t < 32) s_src[t] = src[row*32 + t];
  __syncthreads();
  float acc = bemb[t];
  #pragma unroll
  for (int k = 0; k < 32; k++) acc += s_src[k]*Wemb[k*DM + t];
  int i2 = t & ~1;
  float freq = expf((float)i2 * (-9.210340371976184f/512.0f));
  float ang = (float)l * freq;
  acc += (t & 1) ? cosf(ang) : sinf(ang);
  size_t idx = (size_t)row*DM + t;
  X[idx] = acc;
  Xb[idx] = f2b(acc);
}

// ---------------- QK_sample -> M score (j-parallel, short chains) ----------------
__global__ __launch_bounds__(64) void qksample_kernel(const float* __restrict__ QKV,
    const int* __restrict__ idx_s, float* __restrict__ Msc)
{
  int gid = blockIdx.x;              // (b*8+h)*1024 + i
  int i = gid & (L_-1), h = (gid >> 10) & 7, b = gid >> 13;
  int t = threadIdx.x;
  int j4 = t >> 2, e4 = t & 3;       // lane = j4*4 + e4
  const float* Qrow = QKV + ((size_t)(b*L_ + i))*QS + h*HD + e4*16;
  float4 q[4];
  #pragma unroll
  for (int r = 0; r < 4; r++) q[r] = *(const float4*)(Qrow + r*4);
  const float* Kbase = QKV + 512 + h*HD + (size_t)b*L_*QS + e4*16;
  const int* idq = idx_s + i*KS;
  float mx = -3.4e38f, sm = 0.f;
  #pragma unroll
  for (int p = 0; p < 3; p++) {
    int j = p*16 + j4;
    int jc = (j < KS) ? j : 0;       // inactive lanes redo j=0 (result discarded)
    int s = idq[jc];
    const float4* Kr = (const float4*)(Kbase + (size_t)s*QS);
    float4 k0 = Kr[0], k1 = Kr[1], k2 = Kr[2], k3 = Kr[3];
    float d = q[0].x*k0.x + q[0].y*k0.y + q[0].z*k0.z + q[0].w*k0.w;
    d += q[1].x*k1.x + q[1].y*k1.y + q[1].z*k1.z + q[1].w*k1.w;
    d += q[2].x*k2.x + q[2].y*k2.y + q[2].z*k2.z + q[2].w*k2.w;
    d += q[3].x*k3.x + q[3].y*k3.y + q[3].z*k3.z + q[3].w*k3.w;
    d += __shfl_xor(d, 1);
    d += __shfl_xor(d, 2);
    if (j < KS && e4 == 0) { mx = fmaxf(mx, d); sm += d; }
  }
  #pragma unroll
  for (int off = 4; off < 64; off <<= 1) {
    mx = fmaxf(mx, __shfl_xor(mx, off));
    sm += __shfl_xor(sm, off);
  }
  if (t == 0) Msc[gid] = mx - sm*(1.0f/KS);
}

// ---------------- single-wave top-35 (tie-break lower index) ----------------
__global__ __launch_bounds__(64) void topk_kernel(const float* __restrict__ Msc, int* __restrict__ idx_top)
{
  int bh = blockIdx.x, t = threadIdx.x;
  __shared__ float vals[L_];
  for (int i = t; i < L_; i += 64) vals[i] = Msc[(size_t)bh*L_ + i];
  __syncthreads();
  for (int sel = 0; sel < KS; sel++) {
    float bv = -3.4e38f; int bi = 0x7fffffff;
    for (int i = t; i < L_; i += 64) {
      float v = vals[i];
      if (v > bv || (v == bv && i < bi)) { bv = v; bi = i; }
    }
    #pragma unroll
    for (int off = 32; off; off >>= 1) {
      float ov = __shfl_xor(bv, off); int oi = __shfl_xor(bi, off);
      if (ov > bv || (ov == bv && oi < bi)) { bv = ov; bi = oi; }
    }
    if (t == 0) idx_top[bh*KS + sel] = bi;
    if (t == (bi & 63)) vals[bi] = -3.4e38f;
    __syncthreads();
  }
}

// ---------------- V mean over L ----------------
__global__ __launch_bounds__(256) void vmean_kernel(const float* __restrict__ QKV, float* __restrict__ Vmean)
{
  int bh = blockIdx.x, h = bh & 7, b = bh >> 3;
  int g = threadIdx.x >> 6, e = threadIdx.x & 63;
  __shared__ float p[4][64];
  const float* Vb = QKV + 1024 + h*HD + (size_t)b*L_*QS;
  float s = 0.f;
  for (int l = g; l < L_; l += 4) s += Vb[(size_t)l*QS + e];
  p[g][e] = s;
  __syncthreads();
  if (threadIdx.x < 64)
    Vmean[bh*HD + threadIdx.x] =
      (p[0][threadIdx.x]+p[1][threadIdx.x]+p[2][threadIdx.x]+p[3][threadIdx.x]) * (1.f/L_);
}

// ---------------- fill context with broadcast V-mean (bf16) ----------------
__global__ __launch_bounds__(512) void ctxfill_kernel(const float* __restrict__ Vmean, ushort* __restrict__ CTXb)
{
  int row = blockIdx.x, b = row >> 10, t = threadIdx.x;
  CTXb[(size_t)row*DM + t] = f2b(Vmean[b*DM + t]);
}

// ---------------- chunked flash attention, phase A (query-split ×4 for occupancy) ----
// grid: ((b*8+h)*8 + chunk)*4 + q  (1024 blocks), block 256
__global__ __launch_bounds__(256) void attn_part_kernel(const float* __restrict__ QKV,
    const int* __restrict__ idx_top,
    float* __restrict__ Pacc, float* __restrict__ Pm, float* __restrict__ Pl)
{
  int gid = blockIdx.x;
  int q = gid & 3, c = (gid >> 2) & 7, bh = gid >> 5;
  int h = bh & 7, b = bh >> 3;
  int chunk = bh*NCH + c;            // Pacc/Pm/Pl slot (same layout as before)
  int u0 = q*9;
  int NU = (q == 3) ? 8 : 9;
  int t = threadIdx.x;
  __shared__ float qs[9][68];          // scaled Q rows (padded pitch)
  __shared__ float sc[9][132];         // scores -> exp'd scores
  __shared__ float sm[9], sl[9];

  // load + scale this block's Q rows
  for (int idx = t; idx < NU*64; idx += 256) {
    int ul = idx >> 6, e = idx & 63;
    int qi = idx_top[bh*KS + u0 + ul];
    qs[ul][e] = QKV[((size_t)(b*L_ + qi))*QS + h*HD + e] * 0.125f;
  }
  __syncthreads();

  // scores: thread k = t&127 owns one key; K row in 16 float4 regs
  {
    int k = t & 127, par = t >> 7;
    const float4* Kr = (const float4*)(QKV + ((size_t)(b*L_ + c*CH + k))*QS + 512 + h*HD);
    float4 kreg[16];
    #pragma unroll
    for (int e4 = 0; e4 < 16; e4++) kreg[e4] = Kr[e4];
    for (int ul = par; ul < NU; ul += 2) {
      float d = 0.f;
      #pragma unroll
      for (int e4 = 0; e4 < 16; e4++) {
        float4 q4 = *(const float4*)&qs[ul][e4*4];   // wave-uniform broadcast
        float4 k4 = kreg[e4];
        d += q4.x*k4.x + q4.y*k4.y + q4.z*k4.z + q4.w*k4.w;
      }
      sc[ul][k] = d;
    }
  }
  __syncthreads();

  // softmax per ul: 4 threads/row
  {
    int ul = t >> 2, sub = t & 3;
    if (ul < NU) {
      float m = -3.4e38f;
      for (int i = sub; i < 128; i += 4) m = fmaxf(m, sc[ul][i]);
      m = fmaxf(m, __shfl_xor(m, 1));
      m = fmaxf(m, __shfl_xor(m, 2));
      float l = 0.f;
      for (int i = sub; i < 128; i += 4) {
        float ev = expf(sc[ul][i] - m);
        sc[ul][i] = ev;
        l += ev;
      }
      l += __shfl_xor(l, 1);
      l += __shfl_xor(l, 2);
      if (sub == 0) { sm[ul] = m; sl[ul] = l; }
    }
  }
  __syncthreads();

  // partial PV: thread = (ug, e); ul in {ug, ug+4, ug+8}
  {
    int e = t & 63, ug = t >> 6;
    const float* Vb = QKV + 1024 + h*HD + ((size_t)(b*L_ + c*CH))*QS;
    float acc[3] = {0.f, 0.f, 0.f};
    for (int kb = 0; kb < CH; kb++) {
      float v = Vb[(size_t)kb*QS + e];
      #pragma unroll
      for (int iu = 0; iu < 3; iu++) {
        int ul = ug + iu*4;
        if (ul < NU) acc[iu] += sc[ul][kb] * v;     // sc read is wave-uniform broadcast
      }
    }
    #pragma unroll
    for (int iu = 0; iu < 3; iu++) {
      int ul = ug + iu*4;
      if (ul < NU) Pacc[((size_t)chunk*35 + u0 + ul)*64 + e] = acc[iu];
    }
  }
  if (t < NU) { Pm[chunk*35 + u0 + t] = sm[t]; Pl[chunk*35 + u0 + t] = sl[t]; }
}

// ---------------- phase B: merge partials, scatter bf16 ctx ----------------
__global__ __launch_bounds__(256) void attn_merge_kernel(const float* __restrict__ Pacc,
    const float* __restrict__ Pm, const float* __restrict__ Pl,
    const int* __restrict__ idx_top, ushort* __restrict__ CTXb)
{
  int bh = blockIdx.x;
  int h = bh & 7, b = bh >> 3;
  int t = threadIdx.x;
  __shared__ float m8[NCH*35], l8[NCH*35];
  for (int i = t; i < NCH*35; i += 256) {
    int c = i / 35, u = i - c*35;
    m8[c*35 + u] = Pm[((size_t)bh*NCH + c)*35 + u];
    l8[c*35 + u] = Pl[((size_t)bh*NCH + c)*35 + u];
  }
  __syncthreads();
  int e = t & 63, ug = t >> 6;
  #pragma unroll
  for (int iu = 0; iu < 9; iu++) {
    int u = ug + iu*4;
    if (u >= 35) break;
    float M = -3.4e38f;
    #pragma unroll
    for (int c = 0; c < NCH; c++) M = fmaxf(M, m8[c*35 + u]);
    float Ltot = 0.f, o = 0.f;
    #pragma unroll
    for (int c = 0; c < NCH; c++) {
      float w = expf(m8[c*35 + u] - M);
      Ltot += w * l8[c*35 + u];
      o += w * Pacc[(((size_t)bh*NCH + c)*35 + u)*64 + e];
    }
    int qi = idx_top[bh*KS + u];
    CTXb[((size_t)(b*L_ + qi))*DM + h*HD + e] = f2b(o / Ltot);
  }
}

// ---------------- LayerNorm (optional add), f32 + bf16 out ----------------
__global__ __launch_bounds__(512) void ln_kernel(const float* __restrict__ Xa,
    const float* __restrict__ Xadd, const float* __restrict__ g, const float* __restrict__ beta,
    float* __restrict__ outf, ushort* __restrict__ outb)
{
  int row = blockIdx.x, t = threadIdx.x;
  __shared__ float red[16];
  size_t idx = (size_t)row*DM + t;
  float v = Xa[idx];
  if (Xadd) v += Xadd[idx];
  float s = v;
  #pragma unroll
  for (int off = 32; off; off >>= 1) s += __shfl_xor(s, off);
  if ((t & 63) == 0) red[t >> 6] = s;
  __syncthreads();
  float mean = 0.f;
  #pragma unroll
  for (int k = 0; k < 8; k++) mean += red[k];
  mean *= (1.f/DM);
  float d = v - mean, q = d*d;
  #pragma unroll
  for (int off = 32; off; off >>= 1) q += __shfl_xor(q, off);
  if ((t & 63) == 0) red[8 + (t >> 6)] = q;
  __syncthreads();
  float var = 0.f;
  #pragma unroll
  for (int k = 0; k < 8; k++) var += red[8 + k];
  var *= (1.f/DM);
  float r = d / sqrtf(var + 1e-5f) * g[t] + beta[t];
  outf[idx] = r;
  if (outb) outb[idx] = f2b(r);
}

// ---------------- partial mean pool + classifier ----------------
__global__ __launch_bounds__(512) void poolp_kernel(const float* __restrict__ X, float* __restrict__ pooledP)
{
  int p = blockIdx.x;
  int t = threadIdx.x;
  int b = p >> 3, seg = p & 7;
  float s = 0.f;
  const float* base = X + ((size_t)b*L_ + seg*128)*DM + t;
  for (int l = 0; l < 128; l++) s += base[(size_t)l*DM];
  pooledP[p*DM + t] = s;
}

__global__ __launch_bounds__(64) void cls_kernel(const float* __restrict__ pooledP,
    const float* __restrict__ Wc, const float* __restrict__ bc, float* __restrict__ out)
{
  int o = blockIdx.x;
  int b = o/10, c = o%10, t = threadIdx.x;
  float s = 0.f;
  for (int d = t; d < DM; d += 64) {
    float p = 0.f;
    #pragma unroll
    for (int seg = 0; seg < 8; seg++) p += pooledP[(b*8 + seg)*DM + d];
    s += p * (1.f/L_) * Wc[d*10 + c];
  }
  #pragma unroll
  for (int off = 32; off; off >>= 1) s += __shfl_xor(s, off);
  if (t == 0) out[o] = bc[c] + s;
}

extern "C" void kernel_launch(void* const* d_in, const int* in_sizes, int n_in,
                              void* d_out, int out_size, void* d_ws, size_t ws_size,
                              hipStream_t stream)
{
  const float* src   = (const float*)d_in[0];
  const int*   idxs  = (const int*)d_in[1];
  const float* Wemb  = (const float*)d_in[2];
  const float* bemb  = (const float*)d_in[3];
  const float* Wq    = (const float*)d_in[4];
  const float* bq    = (const float*)d_in[5];
  const float* Wk    = (const float*)d_in[6];
  const float* bk    = (const float*)d_in[7];
  const float* Wv    = (const float*)d_in[8];
  const float* bv    = (const float*)d_in[9];
  const float* Wo    = (const float*)d_in[10];
  const float* bo    = (const float*)d_in[11];
  const float* g1    = (const float*)d_in[12];
  const float* beta1 = (const float*)d_in[13];
  const float* W1    = (const float*)d_in[14];
  const float* bf1   = (const float*)d_in[15];
  const float* W2    = (const float*)d_in[16];
  const float* bf2   = (const float*)d_in[17];
  const float* g2    = (const float*)d_in[18];
  const float* beta2 = (const float*)d_in[19];
  const float* gf    = (const float*)d_in[20];
  const float* betaf = (const float*)d_in[21];
  const float* Wc    = (const float*)d_in[22];
  const float* bc    = (const float*)d_in[23];
  float* out = (float*)d_out;

  float* wsf = (float*)d_ws;
  float*  X     = wsf;                              // [0, 2097152)
  ushort* Xb    = (ushort*)(wsf + 2097152);         // [2097152, 3145728)
  ushort* CTXb  = (ushort*)(wsf + 3145728);         // [3145728, 4194304)
  float*  QKV   = wsf + 4194304;                    // [4194304, 10485760)  LIVE during attention
  ushort* H     = (ushort*)(wsf + 4194304);         // FFN hidden bf16 (QKV dead by FFN1)
  float*  Y     = wsf + 8388608;                    // [8388608, 10485760)  FFN2 out (QKV dead)
  // attention partials: alias Xb (dead between QKV-GEMM and ln1)
  float*  Pacc  = wsf + 2097152;                    // 573,440 fl <= Xb's 1,048,576
  ushort* Wqkvt = (ushort*)(wsf + 10485760);        // 786,432 fl
  ushort* Wot   = (ushort*)(wsf + 11272192);        // 262,144 fl
  ushort* W1t   = (ushort*)(wsf + 11534336);        // 1,048,576 fl
  ushort* W2t   = (ushort*)(wsf + 12582912);        // 1,048,576 fl
  float*  bqkv  = wsf + 13631488;                   // 3,072
  float*  Msc   = wsf + 13634560;                   // 32,768 (dead after topk)
  float*  Pm    = wsf + 13634560;                   // alias Msc: 8,960
  float*  Pl    = wsf + 13634560 + 8960;            // alias Msc: 8,960
  float*  Vmean = wsf + 13667328;                   // 2,048
  float*  pooledP = wsf + 13669376;                 // 16,384
  int*    idx_top = (int*)(wsf + 13685760);         // 1,120

  for (int l = 0; l < 2; l++) {
    wconv_kernel<<<dim3(DM/32, DM/32), 256, 0, stream>>>(Wq + (size_t)l*DM*DM, Wqkvt + ((size_t)l*QS +    0)*DM, DM, DM);
    wconv_kernel<<<dim3(DM/32, DM/32), 256, 0, stream>>>(Wk + (size_t)l*DM*DM, Wqkvt + ((size_t)l*QS +  512)*DM, DM, DM);
    wconv_kernel<<<dim3(DM/32, DM/32), 256, 0, stream>>>(Wv + (size_t)l*DM*DM, Wqkvt + ((size_t)l*QS + 1024)*DM, DM, DM);
    wconv_kernel<<<dim3(DM/32, DM/32), 256, 0, stream>>>(Wo + (size_t)l*DM*DM, Wot + (size_t)l*DM*DM, DM, DM);
    wconv_kernel<<<dim3(DFF/32, DM/32), 256, 0, stream>>>(W1 + (size_t)l*DM*DFF, W1t + (size_t)l*DFF*DM, DM, DFF);
    wconv_kernel<<<dim3(DM/32, DFF/32), 256, 0, stream>>>(W2 + (size_t)l*DFF*DM, W2t + (size_t)l*DM*DFF, DFF, DM);
  }
  bcat_kernel<<<12, 256, 0, stream>>>(bq, bk, bv, bqkv);

  const int M = B_ * L_; // 4096
  embed_kernel<<<M, 512, 0, stream>>>(src, Wemb, bemb, X, Xb);

  for (int l = 0; l < 2; l++) {
    const size_t vo = (size_t)l*DM;
    mfma_gemm<128,0><<<dim3(QS/128, M/128), 256, 0, stream>>>(
        Xb, Wqkvt + (size_t)l*QS*DM, bqkv + (size_t)l*QS, nullptr, QKV, nullptr, M, QS, DM);
    qksample_kernel<<<B_*NH*L_, 64, 0, stream>>>(QKV, idxs + (size_t)l*L_*KS, Msc);
    topk_kernel<<<B_*NH, 64, 0, stream>>>(Msc, idx_top);
    vmean_kernel<<<B_*NH, 256, 0, stream>>>(QKV, Vmean);
    ctxfill_kernel<<<M, 512, 0, stream>>>(Vmean, CTXb);
    attn_part_kernel<<<B_*NH*NCH*4, 256, 0, stream>>>(QKV, idx_top, Pacc, Pm, Pl);
    attn_merge_kernel<<<B_*NH, 256, 0, stream>>>(Pacc, Pm, Pl, idx_top, CTXb);
    mfma_gemm<64,2><<<dim3(DM/64, M/128), 256, 0, stream>>>(
        CTXb, Wot + (size_t)l*DM*DM, bo + vo, X, X, nullptr, M, DM, DM);
    ln_kernel<<<M, 512, 0, stream>>>(X, nullptr, g1 + vo, beta1 + vo, X, Xb);
    mfma_gemm<128,1><<<dim3(DFF/128, M/128), 256, 0, stream>>>(
        Xb, W1t + (size_t)l*DFF*DM, bf1 + (size_t)l*DFF, nullptr, nullptr, H, M, DFF, DM);
    mfma_gemm<64,0><<<dim3(DM/64, M/128), 256, 0, stream>>>(
        H, W2t + (size_t)l*DM*DFF, bf2 + vo, nullptr, Y, nullptr, M, DM, DFF);
    ln_kernel<<<M, 512, 0, stream>>>(X, Y, g2 + vo, beta2 + vo, X, Xb);
  }
  ln_kernel<<<M, 512, 0, stream>>>(X, nullptr, gf, betaf, X, nullptr);
  poolp_kernel<<<B_*8, 512, 0, stream>>>(X, pooledP);
  cls_kernel<<<40, 64, 0, stream>>>(pooledP, Wc, bc, out);
}

// Round 9
// 677.582 us; speedup vs baseline: 1.5143x; 1.0917x over previous
//
#include <hip/hip_runtime.h>
#include <hip/hip_bf16.h>
#include <math.h>

#define B_ 4
#define L_ 1024
#define DM 512
#define NH 8
#define HD 64
#define DFF 2048
#define KS 35
#define QS 1536   // packed QKV row stride
#define CH 128    // attention key chunk
#define NCH (L_/CH)

typedef __attribute__((ext_vector_type(8))) short bf16x8;
typedef __attribute__((ext_vector_type(4))) float f32x4;

__device__ inline ushort f2b(float f){
  __hip_bfloat16 h = __float2bfloat16(f);
  return *reinterpret_cast<ushort*>(&h);
}
__device__ inline float gelu_exact(float x){
  return 0.5f*x*(1.0f+erff(x*0.7071067811865476f));
}

#define GLOAD16(g, l) __builtin_amdgcn_global_load_lds( \
    (const __attribute__((address_space(1))) void*)(g), \
    (__attribute__((address_space(3))) void*)(l), 16, 0, 0)

// ---------------- weight convert + transpose to bf16 [N][K] ----------------
__global__ __launch_bounds__(256) void wconv_kernel(const float* __restrict__ W,
    ushort* __restrict__ Wt, int K, int N)
{
  __shared__ float tile[32][33];
  int n0 = blockIdx.x*32, k0 = blockIdx.y*32;
  int tx = threadIdx.x & 31, ty = threadIdx.x >> 5;
  #pragma unroll
  for (int i = ty; i < 32; i += 8) tile[i][tx] = W[(size_t)(k0+i)*N + n0+tx];
  __syncthreads();
  #pragma unroll
  for (int i = ty; i < 32; i += 8) Wt[(size_t)(n0+i)*K + k0+tx] = f2b(tile[tx][i]);
}

__global__ __launch_bounds__(256) void bcat_kernel(const float* __restrict__ bq,
    const float* __restrict__ bk, const float* __restrict__ bv, float* __restrict__ bqkv)
{
  int i = blockIdx.x*256 + threadIdx.x;   // 0..3071
  if (i >= 2*QS) return;
  int l = i / QS, j = i - l*QS;
  const float* src = (j < 512) ? bq : (j < 1024 ? bk : bv);
  bqkv[i] = src[l*DM + (j & 511)];
}

// ---------------- bf16 MFMA GEMM, double-buffered (2-phase) ----------------
// A: [M][K] bf16; Bt: [N][K] bf16; MODE 0: f32 out, 1: gelu->bf16 out, 2: +R f32 out
template<int BN, int MODE>
__global__ __launch_bounds__(256) void mfma_gemm(
    const ushort* __restrict__ A, const ushort* __restrict__ Bt,
    const float* __restrict__ bias, const float* __restrict__ R,
    float* __restrict__ Cf, ushort* __restrict__ Cb,
    int M, int N, int K)
{
  constexpr int BM = 128, BK = 32;
  constexpr int NF = BN/32;
  constexpr int ACH = BM*4;          // 16B chunks per A tile
  constexpr int BCH = BN*4;
  __shared__ __align__(16) ushort As[2][BM*BK];
  __shared__ __align__(16) ushort Bs[2][BN*BK];
  const int t = threadIdx.x, lane = t & 63, w = t >> 6, wr = w >> 1, wc = w & 1;
  const int row0 = blockIdx.y*BM, col0 = blockIdx.x*BN;

  // staging: linear LDS dest, inverse-swizzled global source
  const ushort* aSrc[ACH/256]; int aDst[ACH/256];
  #pragma unroll
  for (int j = 0; j < ACH/256; j++) {
    int ch = j*256 + t, r = ch >> 2, cc = ch & 3, cs = cc ^ ((r >> 1) & 3);
    aSrc[j] = A + (size_t)(row0 + r)*K + cs*8;
    aDst[j] = ch*16;
  }
  const ushort* bSrc[BCH/256]; int bDst[BCH/256];
  #pragma unroll
  for (int j = 0; j < BCH/256; j++) {
    int ch = j*256 + t, r = ch >> 2, cc = ch & 3, cs = cc ^ ((r >> 1) & 3);
    bSrc[j] = Bt + (size_t)(col0 + r)*K + cs*8;
    bDst[j] = ch*16;
  }
  // fragment read offsets (swizzled)
  int aOff[4], bOff[NF];
  #pragma unroll
  for (int m = 0; m < 4; m++) {
    int r = wr*64 + m*16 + (lane & 15);
    aOff[m] = r*64 + (((lane >> 4)*16) ^ (((r >> 1) & 3) << 4));
  }
  #pragma unroll
  for (int n = 0; n < NF; n++) {
    int r = wc*(BN/2) + n*16 + (lane & 15);
    bOff[n] = r*64 + (((lane >> 4)*16) ^ (((r >> 1) & 3) << 4));
  }
  f32x4 zero = {0.f, 0.f, 0.f, 0.f};
  f32x4 acc[4][NF];
  #pragma unroll
  for (int m = 0; m < 4; m++)
    #pragma unroll
    for (int n = 0; n < NF; n++) acc[m][n] = zero;

  // prologue: stage tile 0 into buf 0
  #pragma unroll
  for (int j = 0; j < ACH/256; j++) GLOAD16(aSrc[j], (char*)As[0] + aDst[j]);
  #pragma unroll
  for (int j = 0; j < BCH/256; j++) GLOAD16(bSrc[j], (char*)Bs[0] + bDst[j]);
  __syncthreads();

  const int nk = K / BK;
  for (int ki = 0; ki < nk; ki++) {
    const int cur = ki & 1;
    if (ki + 1 < nk) {               // issue next-tile loads first (overlap with MFMA)
      const int kt = (ki + 1)*BK;
      #pragma unroll
      for (int j = 0; j < ACH/256; j++) GLOAD16(aSrc[j] + kt, (char*)As[cur^1] + aDst[j]);
      #pragma unroll
      for (int j = 0; j < BCH/256; j++) GLOAD16(bSrc[j] + kt, (char*)Bs[cur^1] + bDst[j]);
    }
    bf16x8 af[4], bfr[NF];
    #pragma unroll
    for (int m = 0; m < 4; m++) af[m] = *(const bf16x8*)((const char*)As[cur] + aOff[m]);
    #pragma unroll
    for (int n = 0; n < NF; n++) bfr[n] = *(const bf16x8*)((const char*)Bs[cur] + bOff[n]);
    #pragma unroll
    for (int m = 0; m < 4; m++)
      #pragma unroll
      for (int n = 0; n < NF; n++)
        acc[m][n] = __builtin_amdgcn_mfma_f32_16x16x32_bf16(af[m], bfr[n], acc[m][n], 0, 0, 0);
    __syncthreads();                 // drains next-tile vmem writes + this-tile LDS reads
  }
  #pragma unroll
  for (int m = 0; m < 4; m++) {
    int rb = row0 + wr*64 + m*16 + ((lane >> 4) << 2);
    #pragma unroll
    for (int n = 0; n < NF; n++) {
      int c = col0 + wc*(BN/2) + n*16 + (lane & 15);
      float bv = bias[c];
      #pragma unroll
      for (int j = 0; j < 4; j++) {
        size_t idx = (size_t)(rb + j)*N + c;
        float v = acc[m][n][j] + bv;
        if (MODE == 1)      Cb[idx] = f2b(gelu_exact(v));
        else if (MODE == 2) Cf[idx] = v + R[idx];
        else                Cf[idx] = v;
      }
    }
  }
}

// ---------------- embed + positional encoding ----------------
__global__ __launch_bounds__(512) void embed_kernel(const float* __restrict__ src,
    const float* __restrict__ Wemb, const float* __restrict__ bemb,
    float* __restrict__ X, ushort* __restrict__ Xb)
{
  int row = blockIdx.x, l = row & (L_-1), t = threadIdx.x;
  __shared__ float s_src[32];
  if (t < 32) s_src[t] = src[row*32 + t];
  __syncthreads();
  float acc = bemb[t];
  #pragma unroll
  for (int k = 0; k < 32; k++) acc += s_src[k]*Wemb[k*DM + t];
  int i2 = t & ~1;
  float freq = expf((float)i2 * (-9.210340371976184f/512.0f));
  float ang = (float)l * freq;
  acc += (t & 1) ? cosf(ang) : sinf(ang);
  size_t idx = (size_t)row*DM + t;
  X[idx] = acc;
  Xb[idx] = f2b(acc);
}

// ---------------- QK_sample -> M score (j-parallel, short chains) ----------------
__global__ __launch_bounds__(64) void qksample_kernel(const float* __restrict__ QKV,
    const int* __restrict__ idx_s, float* __restrict__ Msc)
{
  int gid = blockIdx.x;              // (b*8+h)*1024 + i
  int i = gid & (L_-1), h = (gid >> 10) & 7, b = gid >> 13;
  int t = threadIdx.x;
  int j4 = t >> 2, e4 = t & 3;       // lane = j4*4 + e4
  const float* Qrow = QKV + ((size_t)(b*L_ + i))*QS + h*HD + e4*16;
  float4 q[4];
  #pragma unroll
  for (int r = 0; r < 4; r++) q[r] = *(const float4*)(Qrow + r*4);
  const float* Kbase = QKV + 512 + h*HD + (size_t)b*L_*QS + e4*16;
  const int* idq = idx_s + i*KS;
  float mx = -3.4e38f, sm = 0.f;
  #pragma unroll
  for (int p = 0; p < 3; p++) {
    int j = p*16 + j4;
    int jc = (j < KS) ? j : 0;       // inactive lanes redo j=0 (result discarded)
    int s = idq[jc];
    const float4* Kr = (const float4*)(Kbase + (size_t)s*QS);
    float4 k0 = Kr[0], k1 = Kr[1], k2 = Kr[2], k3 = Kr[3];
    float d = q[0].x*k0.x + q[0].y*k0.y + q[0].z*k0.z + q[0].w*k0.w;
    d += q[1].x*k1.x + q[1].y*k1.y + q[1].z*k1.z + q[1].w*k1.w;
    d += q[2].x*k2.x + q[2].y*k2.y + q[2].z*k2.z + q[2].w*k2.w;
    d += q[3].x*k3.x + q[3].y*k3.y + q[3].z*k3.z + q[3].w*k3.w;
    d += __shfl_xor(d, 1);
    d += __shfl_xor(d, 2);
    if (j < KS && e4 == 0) { mx = fmaxf(mx, d); sm += d; }
  }
  #pragma unroll
  for (int off = 4; off < 64; off <<= 1) {
    mx = fmaxf(mx, __shfl_xor(mx, off));
    sm += __shfl_xor(sm, off);
  }
  if (t == 0) Msc[gid] = mx - sm*(1.0f/KS);
}

// ---------------- register-resident top-35 (tie-break lower index) ----------------
// 64 lanes x 16 register values; no LDS, no barriers (wave-lockstep)
__global__ __launch_bounds__(64) void topk_kernel(const float* __restrict__ Msc, int* __restrict__ idx_top)
{
  int bh = blockIdx.x, t = threadIdx.x;
  float v[16];
  #pragma unroll
  for (int r = 0; r < 16; r++) v[r] = Msc[(size_t)bh*L_ + r*64 + t];
  for (int sel = 0; sel < KS; sel++) {
    // local argmax over the 16 register slots (idx = r*64+t increases with r,
    // strict > keeps the lowest index on equality)
    float bv = -3.4e38f; int br = 0;
    #pragma unroll
    for (int r = 0; r < 16; r++) {
      bool gt = v[r] > bv;
      bv = gt ? v[r] : bv;
      br = gt ? r : br;
    }
    int bi = br*64 + t;
    // wave argmax with lower-index tie-break
    #pragma unroll
    for (int off = 32; off; off >>= 1) {
      float ov = __shfl_xor(bv, off); int oi = __shfl_xor(bi, off);
      if (ov > bv || (ov == bv && oi < bi)) { bv = ov; bi = oi; }
    }
    if (t == 0) idx_top[bh*KS + sel] = bi;
    // owning lane removes the selected value
    if ((bi & 63) == t) v[bi >> 6] = -3.4e38f;
  }
}

// ---------------- V mean over L ----------------
__global__ __launch_bounds__(256) void vmean_kernel(const float* __restrict__ QKV, float* __restrict__ Vmean)
{
  int bh = blockIdx.x, h = bh & 7, b = bh >> 3;
  int g = threadIdx.x >> 6, e = threadIdx.x & 63;
  __shared__ float p[4][64];
  const float* Vb = QKV + 1024 + h*HD + (size_t)b*L_*QS;
  float s = 0.f;
  for (int l = g; l < L_; l += 4) s += Vb[(size_t)l*QS + e];
  p[g][e] = s;
  __syncthreads();
  if (threadIdx.x < 64)
    Vmean[bh*HD + threadIdx.x] =
      (p[0][threadIdx.x]+p[1][threadIdx.x]+p[2][threadIdx.x]+p[3][threadIdx.x]) * (1.f/L_);
}

// ---------------- fill context with broadcast V-mean (bf16) ----------------
__global__ __launch_bounds__(512) void ctxfill_kernel(const float* __restrict__ Vmean, ushort* __restrict__ CTXb)
{
  int row = blockIdx.x, b = row >> 10, t = threadIdx.x;
  CTXb[(size_t)row*DM + t] = f2b(Vmean[b*DM + t]);
}

// ---------------- chunked flash attention, phase A (query-split ×4 for occupancy) ----
// grid: ((b*8+h)*8 + chunk)*4 + q  (1024 blocks), block 256
__global__ __launch_bounds__(256) void attn_part_kernel(const float* __restrict__ QKV,
    const int* __restrict__ idx_top,
    float* __restrict__ Pacc, float* __restrict__ Pm, float* __restrict__ Pl)
{
  int gid = blockIdx.x;
  int q = gid & 3, c = (gid >> 2) & 7, bh = gid >> 5;
  int h = bh & 7, b = bh >> 3;
  int chunk = bh*NCH + c;            // Pacc/Pm/Pl slot (same layout as before)
  int u0 = q*9;
  int NU = (q == 3) ? 8 : 9;
  int t = threadIdx.x;
  __shared__ float qs[9][68];          // scaled Q rows (padded pitch)
  __shared__ float sc[9][132];         // scores -> exp'd scores
  __shared__ float sm[9], sl[9];

  // load + scale this block's Q rows
  for (int idx = t; idx < NU*64; idx += 256) {
    int ul = idx >> 6, e = idx & 63;
    int qi = idx_top[bh*KS + u0 + ul];
    qs[ul][e] = QKV[((size_t)(b*L_ + qi))*QS + h*HD + e] * 0.125f;
  }
  __syncthreads();

  // scores: thread k = t&127 owns one key; K row in 16 float4 regs
  {
    int k = t & 127, par = t >> 7;
    const float4* Kr = (const float4*)(QKV + ((size_t)(b*L_ + c*CH + k))*QS + 512 + h*HD);
    float4 kreg[16];
    #pragma unroll
    for (int e4 = 0; e4 < 16; e4++) kreg[e4] = Kr[e4];
    for (int ul = par; ul < NU; ul += 2) {
      float d = 0.f;
      #pragma unroll
      for (int e4 = 0; e4 < 16; e4++) {
        float4 q4 = *(const float4*)&qs[ul][e4*4];   // wave-uniform broadcast
        float4 k4 = kreg[e4];
        d += q4.x*k4.x + q4.y*k4.y + q4.z*k4.z + q4.w*k4.w;
      }
      sc[ul][k] = d;
    }
  }
  __syncthreads();

  // softmax per ul: 4 threads/row
  {
    int ul = t >> 2, sub = t & 3;
    if (ul < NU) {
      float m = -3.4e38f;
      for (int i = sub; i < 128; i += 4) m = fmaxf(m, sc[ul][i]);
      m = fmaxf(m, __shfl_xor(m, 1));
      m = fmaxf(m, __shfl_xor(m, 2));
      float l = 0.f;
      for (int i = sub; i < 128; i += 4) {
        float ev = expf(sc[ul][i] - m);
        sc[ul][i] = ev;
        l += ev;
      }
      l += __shfl_xor(l, 1);
      l += __shfl_xor(l, 2);
      if (sub == 0) { sm[ul] = m; sl[ul] = l; }
    }
  }
  __syncthreads();

  // partial PV: thread = (ug, e); ul in {ug, ug+4, ug+8}
  {
    int e = t & 63, ug = t >> 6;
    const float* Vb = QKV + 1024 + h*HD + ((size_t)(b*L_ + c*CH))*QS;
    float acc[3] = {0.f, 0.f, 0.f};
    for (int kb = 0; kb < CH; kb++) {
      float v = Vb[(size_t)kb*QS + e];
      #pragma unroll
      for (int iu = 0; iu < 3; iu++) {
        int ul = ug + iu*4;
        if (ul < NU) acc[iu] += sc[ul][kb] * v;     // sc read is wave-uniform broadcast
      }
    }
    #pragma unroll
    for (int iu = 0; iu < 3; iu++) {
      int ul = ug + iu*4;
      if (ul < NU) Pacc[((size_t)chunk*35 + u0 + ul)*64 + e] = acc[iu];
    }
  }
  if (t < NU) { Pm[chunk*35 + u0 + t] = sm[t]; Pl[chunk*35 + u0 + t] = sl[t]; }
}

// ---------------- phase B: merge partials, scatter bf16 ctx ----------------
__global__ __launch_bounds__(256) void attn_merge_kernel(const float* __restrict__ Pacc,
    const float* __restrict__ Pm, const float* __restrict__ Pl,
    const int* __restrict__ idx_top, ushort* __restrict__ CTXb)
{
  int bh = blockIdx.x;
  int h = bh & 7, b = bh >> 3;
  int t = threadIdx.x;
  __shared__ float m8[NCH*35], l8[NCH*35];
  for (int i = t; i < NCH*35; i += 256) {
    int c = i / 35, u = i - c*35;
    m8[c*35 + u] = Pm[((size_t)bh*NCH + c)*35 + u];
    l8[c*35 + u] = Pl[((size_t)bh*NCH + c)*35 + u];
  }
  __syncthreads();
  int e = t & 63, ug = t >> 6;
  #pragma unroll
  for (int iu = 0; iu < 9; iu++) {
    int u = ug + iu*4;
    if (u >= 35) break;
    float M = -3.4e38f;
    #pragma unroll
    for (int c = 0; c < NCH; c++) M = fmaxf(M, m8[c*35 + u]);
    float Ltot = 0.f, o = 0.f;
    #pragma unroll
    for (int c = 0; c < NCH; c++) {
      float w = expf(m8[c*35 + u] - M);
      Ltot += w * l8[c*35 + u];
      o += w * Pacc[(((size_t)bh*NCH + c)*35 + u)*64 + e];
    }
    int qi = idx_top[bh*KS + u];
    CTXb[((size_t)(b*L_ + qi))*DM + h*HD + e] = f2b(o / Ltot);
  }
}

// ---------------- LayerNorm (optional add), f32 + bf16 out ----------------
__global__ __launch_bounds__(512) void ln_kernel(const float* __restrict__ Xa,
    const float* __restrict__ Xadd, const float* __restrict__ g, const float* __restrict__ beta,
    float* __restrict__ outf, ushort* __restrict__ outb)
{
  int row = blockIdx.x, t = threadIdx.x;
  __shared__ float red[16];
  size_t idx = (size_t)row*DM + t;
  float v = Xa[idx];
  if (Xadd) v += Xadd[idx];
  float s = v;
  #pragma unroll
  for (int off = 32; off; off >>= 1) s += __shfl_xor(s, off);
  if ((t & 63) == 0) red[t >> 6] = s;
  __syncthreads();
  float mean = 0.f;
  #pragma unroll
  for (int k = 0; k < 8; k++) mean += red[k];
  mean *= (1.f/DM);
  float d = v - mean, q = d*d;
  #pragma unroll
  for (int off = 32; off; off >>= 1) q += __shfl_xor(q, off);
  if ((t & 63) == 0) red[8 + (t >> 6)] = q;
  __syncthreads();
  float var = 0.f;
  #pragma unroll
  for (int k = 0; k < 8; k++) var += red[8 + k];
  var *= (1.f/DM);
  float r = d / sqrtf(var + 1e-5f) * g[t] + beta[t];
  outf[idx] = r;
  if (outb) outb[idx] = f2b(r);
}

// ---------------- partial mean pool + classifier ----------------
__global__ __launch_bounds__(512) void poolp_kernel(const float* __restrict__ X, float* __restrict__ pooledP)
{
  int p = blockIdx.x;
  int t = threadIdx.x;
  int b = p >> 3, seg = p & 7;
  float s = 0.f;
  const float* base = X + ((size_t)b*L_ + seg*128)*DM + t;
  for (int l = 0; l < 128; l++) s += base[(size_t)l*DM];
  pooledP[p*DM + t] = s;
}

__global__ __launch_bounds__(64) void cls_kernel(const float* __restrict__ pooledP,
    const float* __restrict__ Wc, const float* __restrict__ bc, float* __restrict__ out)
{
  int o = blockIdx.x;
  int b = o/10, c = o%10, t = threadIdx.x;
  float s = 0.f;
  for (int d = t; d < DM; d += 64) {
    float p = 0.f;
    #pragma unroll
    for (int seg = 0; seg < 8; seg++) p += pooledP[(b*8 + seg)*DM + d];
    s += p * (1.f/L_) * Wc[d*10 + c];
  }
  #pragma unroll
  for (int off = 32; off; off >>= 1) s += __shfl_xor(s, off);
  if (t == 0) out[o] = bc[c] + s;
}

extern "C" void kernel_launch(void* const* d_in, const int* in_sizes, int n_in,
                              void* d_out, int out_size, void* d_ws, size_t ws_size,
                              hipStream_t stream)
{
  const float* src   = (const float*)d_in[0];
  const int*   idxs  = (const int*)d_in[1];
  const float* Wemb  = (const float*)d_in[2];
  const float* bemb  = (const float*)d_in[3];
  const float* Wq    = (const float*)d_in[4];
  const float* bq    = (const float*)d_in[5];
  const float* Wk    = (const float*)d_in[6];
  const float* bk    = (const float*)d_in[7];
  const float* Wv    = (const float*)d_in[8];
  const float* bv    = (const float*)d_in[9];
  const float* Wo    = (const float*)d_in[10];
  const float* bo    = (const float*)d_in[11];
  const float* g1    = (const float*)d_in[12];
  const float* beta1 = (const float*)d_in[13];
  const float* W1    = (const float*)d_in[14];
  const float* bf1   = (const float*)d_in[15];
  const float* W2    = (const float*)d_in[16];
  const float* bf2   = (const float*)d_in[17];
  const float* g2    = (const float*)d_in[18];
  const float* beta2 = (const float*)d_in[19];
  const float* gf    = (const float*)d_in[20];
  const float* betaf = (const float*)d_in[21];
  const float* Wc    = (const float*)d_in[22];
  const float* bc    = (const float*)d_in[23];
  float* out = (float*)d_out;

  float* wsf = (float*)d_ws;
  float*  X     = wsf;                              // [0, 2097152)
  ushort* Xb    = (ushort*)(wsf + 2097152);         // [2097152, 3145728)
  ushort* CTXb  = (ushort*)(wsf + 3145728);         // [3145728, 4194304)
  float*  QKV   = wsf + 4194304;                    // [4194304, 10485760)  LIVE during attention
  ushort* H     = (ushort*)(wsf + 4194304);         // FFN hidden bf16 (QKV dead by FFN1)
  float*  Y     = wsf + 8388608;                    // [8388608, 10485760)  FFN2 out (QKV dead)
  // attention partials: alias Xb (dead between QKV-GEMM and ln1)
  float*  Pacc  = wsf + 2097152;                    // 573,440 fl <= Xb's 1,048,576
  ushort* Wqkvt = (ushort*)(wsf + 10485760);        // 786,432 fl
  ushort* Wot   = (ushort*)(wsf + 11272192);        // 262,144 fl
  ushort* W1t   = (ushort*)(wsf + 11534336);        // 1,048,576 fl
  ushort* W2t   = (ushort*)(wsf + 12582912);        // 1,048,576 fl
  float*  bqkv  = wsf + 13631488;                   // 3,072
  float*  Msc   = wsf + 13634560;                   // 32,768 (dead after topk)
  float*  Pm    = wsf + 13634560;                   // alias Msc: 8,960
  float*  Pl    = wsf + 13634560 + 8960;            // alias Msc: 8,960
  float*  Vmean = wsf + 13667328;                   // 2,048
  float*  pooledP = wsf + 13669376;                 // 16,384
  int*    idx_top = (int*)(wsf + 13685760);         // 1,120

  for (int l = 0; l < 2; l++) {
    wconv_kernel<<<dim3(DM/32, DM/32), 256, 0, stream>>>(Wq + (size_t)l*DM*DM, Wqkvt + ((size_t)l*QS +    0)*DM, DM, DM);
    wconv_kernel<<<dim3(DM/32, DM/32), 256, 0, stream>>>(Wk + (size_t)l*DM*DM, Wqkvt + ((size_t)l*QS +  512)*DM, DM, DM);
    wconv_kernel<<<dim3(DM/32, DM/32), 256, 0, stream>>>(Wv + (size_t)l*DM*DM, Wqkvt + ((size_t)l*QS + 1024)*DM, DM, DM);
    wconv_kernel<<<dim3(DM/32, DM/32), 256, 0, stream>>>(Wo + (size_t)l*DM*DM, Wot + (size_t)l*DM*DM, DM, DM);
    wconv_kernel<<<dim3(DFF/32, DM/32), 256, 0, stream>>>(W1 + (size_t)l*DM*DFF, W1t + (size_t)l*DFF*DM, DM, DFF);
    wconv_kernel<<<dim3(DM/32, DFF/32), 256, 0, stream>>>(W2 + (size_t)l*DFF*DM, W2t + (size_t)l*DM*DFF, DFF, DM);
  }
  bcat_kernel<<<12, 256, 0, stream>>>(bq, bk, bv, bqkv);

  const int M = B_ * L_; // 4096
  embed_kernel<<<M, 512, 0, stream>>>(src, Wemb, bemb, X, Xb);

  for (int l = 0; l < 2; l++) {
    const size_t vo = (size_t)l*DM;
    mfma_gemm<128,0><<<dim3(QS/128, M/128), 256, 0, stream>>>(
        Xb, Wqkvt + (size_t)l*QS*DM, bqkv + (size_t)l*QS, nullptr, QKV, nullptr, M, QS, DM);
    qksample_kernel<<<B_*NH*L_, 64, 0, stream>>>(QKV, idxs + (size_t)l*L_*KS, Msc);
    topk_kernel<<<B_*NH, 64, 0, stream>>>(Msc, idx_top);
    vmean_kernel<<<B_*NH, 256, 0, stream>>>(QKV, Vmean);
    ctxfill_kernel<<<M, 512, 0, stream>>>(Vmean, CTXb);
    attn_part_kernel<<<B_*NH*NCH*4, 256, 0, stream>>>(QKV, idx_top, Pacc, Pm, Pl);
    attn_merge_kernel<<<B_*NH, 256, 0, stream>>>(Pacc, Pm, Pl, idx_top, CTXb);
    mfma_gemm<64,2><<<dim3(DM/64, M/128), 256, 0, stream>>>(
        CTXb, Wot + (size_t)l*DM*DM, bo + vo, X, X, nullptr, M, DM, DM);
    ln_kernel<<<M, 512, 0, stream>>>(X, nullptr, g1 + vo, beta1 + vo, X, Xb);
    mfma_gemm<128,1><<<dim3(DFF/128, M/128), 256, 0, stream>>>(
        Xb, W1t + (size_t)l*DFF*DM, bf1 + (size_t)l*DFF, nullptr, nullptr, H, M, DFF, DM);
    mfma_gemm<64,0><<<dim3(DM/64, M/128), 256, 0, stream>>>(
        H, W2t + (size_t)l*DM*DFF, bf2 + vo, nullptr, Y, nullptr, M, DM, DFF);
    ln_kernel<<<M, 512, 0, stream>>>(X, Y, g2 + vo, beta2 + vo, X, Xb);
  }
  ln_kernel<<<M, 512, 0, stream>>>(X, nullptr, gf, betaf, X, nullptr);
  poolp_kernel<<<B_*8, 512, 0, stream>>>(X, pooledP);
  cls_kernel<<<40, 64, 0, stream>>>(pooledP, Wc, bc, out);
}

// Round 10
// 567.082 us; speedup vs baseline: 1.8094x; 1.1949x over previous
//
#include <hip/hip_runtime.h>
#include <hip/hip_bf16.h>
#include <math.h>

#define B_ 4
#define L_ 1024
#define DM 512
#define NH 8
#define HD 64
#define DFF 2048
#define KS 35
#define QS 1536   // packed QKV row stride
#define CH 128    // attention key chunk
#define NCH (L_/CH)
#define VSEG 16   // V-mean segments per head

typedef __attribute__((ext_vector_type(8))) short bf16x8;
typedef __attribute__((ext_vector_type(4))) float f32x4;

__device__ inline ushort f2b(float f){
  __hip_bfloat16 h = __float2bfloat16(f);
  return *reinterpret_cast<ushort*>(&h);
}
__device__ inline float gelu_exact(float x){
  return 0.5f*x*(1.0f+erff(x*0.7071067811865476f));
}

#define GLOAD16(g, l) __builtin_amdgcn_global_load_lds( \
    (const __attribute__((address_space(1))) void*)(g), \
    (__attribute__((address_space(3))) void*)(l), 16, 0, 0)

// ---------------- weight convert + transpose to bf16 [N][K] ----------------
__global__ __launch_bounds__(256) void wconv_kernel(const float* __restrict__ W,
    ushort* __restrict__ Wt, int K, int N)
{
  __shared__ float tile[32][33];
  int n0 = blockIdx.x*32, k0 = blockIdx.y*32;
  int tx = threadIdx.x & 31, ty = threadIdx.x >> 5;
  #pragma unroll
  for (int i = ty; i < 32; i += 8) tile[i][tx] = W[(size_t)(k0+i)*N + n0+tx];
  __syncthreads();
  #pragma unroll
  for (int i = ty; i < 32; i += 8) Wt[(size_t)(n0+i)*K + k0+tx] = f2b(tile[tx][i]);
}

__global__ __launch_bounds__(256) void bcat_kernel(const float* __restrict__ bq,
    const float* __restrict__ bk, const float* __restrict__ bv, float* __restrict__ bqkv)
{
  int i = blockIdx.x*256 + threadIdx.x;   // 0..3071
  if (i >= 2*QS) return;
  int l = i / QS, j = i - l*QS;
  const float* src = (j < 512) ? bq : (j < 1024 ? bk : bv);
  bqkv[i] = src[l*DM + (j & 511)];
}

// ---------------- bf16 MFMA GEMM, double-buffered (2-phase) ----------------
// A: [M][K] bf16; Bt: [N][K] bf16; MODE 0: f32 out, 1: gelu->bf16 out, 2: +R f32 out
template<int BN, int MODE>
__global__ __launch_bounds__(256) void mfma_gemm(
    const ushort* __restrict__ A, const ushort* __restrict__ Bt,
    const float* __restrict__ bias, const float* __restrict__ R,
    float* __restrict__ Cf, ushort* __restrict__ Cb,
    int M, int N, int K)
{
  constexpr int BM = 128, BK = 32;
  constexpr int NF = BN/32;
  constexpr int ACH = BM*4;          // 16B chunks per A tile
  constexpr int BCH = BN*4;
  __shared__ __align__(16) ushort As[2][BM*BK];
  __shared__ __align__(16) ushort Bs[2][BN*BK];
  const int t = threadIdx.x, lane = t & 63, w = t >> 6, wr = w >> 1, wc = w & 1;
  const int row0 = blockIdx.y*BM, col0 = blockIdx.x*BN;

  // staging: linear LDS dest, inverse-swizzled global source
  const ushort* aSrc[ACH/256]; int aDst[ACH/256];
  #pragma unroll
  for (int j = 0; j < ACH/256; j++) {
    int ch = j*256 + t, r = ch >> 2, cc = ch & 3, cs = cc ^ ((r >> 1) & 3);
    aSrc[j] = A + (size_t)(row0 + r)*K + cs*8;
    aDst[j] = ch*16;
  }
  const ushort* bSrc[BCH/256]; int bDst[BCH/256];
  #pragma unroll
  for (int j = 0; j < BCH/256; j++) {
    int ch = j*256 + t, r = ch >> 2, cc = ch & 3, cs = cc ^ ((r >> 1) & 3);
    bSrc[j] = Bt + (size_t)(col0 + r)*K + cs*8;
    bDst[j] = ch*16;
  }
  // fragment read offsets (swizzled)
  int aOff[4], bOff[NF];
  #pragma unroll
  for (int m = 0; m < 4; m++) {
    int r = wr*64 + m*16 + (lane & 15);
    aOff[m] = r*64 + (((lane >> 4)*16) ^ (((r >> 1) & 3) << 4));
  }
  #pragma unroll
  for (int n = 0; n < NF; n++) {
    int r = wc*(BN/2) + n*16 + (lane & 15);
    bOff[n] = r*64 + (((lane >> 4)*16) ^ (((r >> 1) & 3) << 4));
  }
  f32x4 zero = {0.f, 0.f, 0.f, 0.f};
  f32x4 acc[4][NF];
  #pragma unroll
  for (int m = 0; m < 4; m++)
    #pragma unroll
    for (int n = 0; n < NF; n++) acc[m][n] = zero;

  // prologue: stage tile 0 into buf 0
  #pragma unroll
  for (int j = 0; j < ACH/256; j++) GLOAD16(aSrc[j], (char*)As[0] + aDst[j]);
  #pragma unroll
  for (int j = 0; j < BCH/256; j++) GLOAD16(bSrc[j], (char*)Bs[0] + bDst[j]);
  __syncthreads();

  const int nk = K / BK;
  for (int ki = 0; ki < nk; ki++) {
    const int cur = ki & 1;
    if (ki + 1 < nk) {               // issue next-tile loads first (overlap with MFMA)
      const int kt = (ki + 1)*BK;
      #pragma unroll
      for (int j = 0; j < ACH/256; j++) GLOAD16(aSrc[j] + kt, (char*)As[cur^1] + aDst[j]);
      #pragma unroll
      for (int j = 0; j < BCH/256; j++) GLOAD16(bSrc[j] + kt, (char*)Bs[cur^1] + bDst[j]);
    }
    bf16x8 af[4], bfr[NF];
    #pragma unroll
    for (int m = 0; m < 4; m++) af[m] = *(const bf16x8*)((const char*)As[cur] + aOff[m]);
    #pragma unroll
    for (int n = 0; n < NF; n++) bfr[n] = *(const bf16x8*)((const char*)Bs[cur] + bOff[n]);
    #pragma unroll
    for (int m = 0; m < 4; m++)
      #pragma unroll
      for (int n = 0; n < NF; n++)
        acc[m][n] = __builtin_amdgcn_mfma_f32_16x16x32_bf16(af[m], bfr[n], acc[m][n], 0, 0, 0);
    __syncthreads();                 // drains next-tile vmem writes + this-tile LDS reads
  }
  #pragma unroll
  for (int m = 0; m < 4; m++) {
    int rb = row0 + wr*64 + m*16 + ((lane >> 4) << 2);
    #pragma unroll
    for (int n = 0; n < NF; n++) {
      int c = col0 + wc*(BN/2) + n*16 + (lane & 15);
      float bv = bias[c];
      #pragma unroll
      for (int j = 0; j < 4; j++) {
        size_t idx = (size_t)(rb + j)*N + c;
        float v = acc[m][n][j] + bv;
        if (MODE == 1)      Cb[idx] = f2b(gelu_exact(v));
        else if (MODE == 2) Cf[idx] = v + R[idx];
        else                Cf[idx] = v;
      }
    }
  }
}

// ---------------- embed + positional encoding ----------------
__global__ __launch_bounds__(512) void embed_kernel(const float* __restrict__ src,
    const float* __restrict__ Wemb, const float* __restrict__ bemb,
    float* __restrict__ X, ushort* __restrict__ Xb)
{
  int row = blockIdx.x, l = row & (L_-1), t = threadIdx.x;
  __shared__ float s_src[32];
  if (t < 32) s_src[t] = src[row*32 + t];
  __syncthreads();
  float acc = bemb[t];
  #pragma unroll
  for (int k = 0; k < 32; k++) acc += s_src[k]*Wemb[k*DM + t];
  int i2 = t & ~1;
  float freq = expf((float)i2 * (-9.210340371976184f/512.0f));
  float ang = (float)l * freq;
  acc += (t & 1) ? cosf(ang) : sinf(ang);
  size_t idx = (size_t)row*DM + t;
  X[idx] = acc;
  Xb[idx] = f2b(acc);
}

// ---------------- QK_sample -> M score (j-parallel, short chains) ----------------
__global__ __launch_bounds__(64) void qksample_kernel(const float* __restrict__ QKV,
    const int* __restrict__ idx_s, float* __restrict__ Msc)
{
  int gid = blockIdx.x;              // (b*8+h)*1024 + i
  int i = gid & (L_-1), h = (gid >> 10) & 7, b = gid >> 13;
  int t = threadIdx.x;
  int j4 = t >> 2, e4 = t & 3;       // lane = j4*4 + e4
  const float* Qrow = QKV + ((size_t)(b*L_ + i))*QS + h*HD + e4*16;
  float4 q[4];
  #pragma unroll
  for (int r = 0; r < 4; r++) q[r] = *(const float4*)(Qrow + r*4);
  const float* Kbase = QKV + 512 + h*HD + (size_t)b*L_*QS + e4*16;
  const int* idq = idx_s + i*KS;
  float mx = -3.4e38f, sm = 0.f;
  #pragma unroll
  for (int p = 0; p < 3; p++) {
    int j = p*16 + j4;
    int jc = (j < KS) ? j : 0;       // inactive lanes redo j=0 (result discarded)
    int s = idq[jc];
    const float4* Kr = (const float4*)(Kbase + (size_t)s*QS);
    float4 k0 = Kr[0], k1 = Kr[1], k2 = Kr[2], k3 = Kr[3];
    float d = q[0].x*k0.x + q[0].y*k0.y + q[0].z*k0.z + q[0].w*k0.w;
    d += q[1].x*k1.x + q[1].y*k1.y + q[1].z*k1.z + q[1].w*k1.w;
    d += q[2].x*k2.x + q[2].y*k2.y + q[2].z*k2.z + q[2].w*k2.w;
    d += q[3].x*k3.x + q[3].y*k3.y + q[3].z*k3.z + q[3].w*k3.w;
    d += __shfl_xor(d, 1);
    d += __shfl_xor(d, 2);
    if (j < KS && e4 == 0) { mx = fmaxf(mx, d); sm += d; }
  }
  #pragma unroll
  for (int off = 4; off < 64; off <<= 1) {
    mx = fmaxf(mx, __shfl_xor(mx, off));
    sm += __shfl_xor(sm, off);
  }
  if (t == 0) Msc[gid] = mx - sm*(1.0f/KS);
}

// ---------------- register-resident top-35 (tie-break lower index) ----------------
__global__ __launch_bounds__(64) void topk_kernel(const float* __restrict__ Msc, int* __restrict__ idx_top)
{
  int bh = blockIdx.x, t = threadIdx.x;
  float v[16];
  #pragma unroll
  for (int r = 0; r < 16; r++) v[r] = Msc[(size_t)bh*L_ + r*64 + t];
  for (int sel = 0; sel < KS; sel++) {
    float bv = -3.4e38f; int br = 0;
    #pragma unroll
    for (int r = 0; r < 16; r++) {
      bool gt = v[r] > bv;
      bv = gt ? v[r] : bv;
      br = gt ? r : br;
    }
    int bi = br*64 + t;
    #pragma unroll
    for (int off = 32; off; off >>= 1) {
      float ov = __shfl_xor(bv, off); int oi = __shfl_xor(bi, off);
      if (ov > bv || (ov == bv && oi < bi)) { bv = ov; bi = oi; }
    }
    if (t == 0) idx_top[bh*KS + sel] = bi;
    if ((bi & 63) == t) v[bi >> 6] = -3.4e38f;
  }
}

// ---------------- V mean over L: segmented partials + merge (occupancy) ----------------
__global__ __launch_bounds__(64) void vmean_part_kernel(const float* __restrict__ QKV,
    float* __restrict__ VmeanP)
{
  int gid = blockIdx.x;              // bh*VSEG + seg  (512 blocks)
  int seg = gid & (VSEG-1), bh = gid >> 4;
  int h = bh & 7, b = bh >> 3;
  int e = threadIdx.x;
  const float* Vb = QKV + 1024 + h*HD + ((size_t)(b*L_ + seg*(L_/VSEG)))*QS;
  float s = 0.f;
  #pragma unroll 4
  for (int l = 0; l < L_/VSEG; l++) s += Vb[(size_t)l*QS + e];
  VmeanP[gid*HD + e] = s;
}

__global__ __launch_bounds__(64) void vmean_merge_kernel(const float* __restrict__ VmeanP,
    float* __restrict__ Vmean)
{
  int bh = blockIdx.x, e = threadIdx.x;
  float s = 0.f;
  #pragma unroll
  for (int seg = 0; seg < VSEG; seg++) s += VmeanP[(bh*VSEG + seg)*HD + e];
  Vmean[bh*HD + e] = s * (1.f/L_);
}

// ---------------- fill context with broadcast V-mean (bf16) ----------------
__global__ __launch_bounds__(512) void ctxfill_kernel(const float* __restrict__ Vmean, ushort* __restrict__ CTXb)
{
  int row = blockIdx.x, b = row >> 10, t = threadIdx.x;
  CTXb[(size_t)row*DM + t] = f2b(Vmean[b*DM + t]);
}

// ---------------- chunked flash attention, phase A (query-split ×4 for occupancy) ----
// grid: ((b*8+h)*8 + chunk)*4 + q  (1024 blocks), block 256
__global__ __launch_bounds__(256) void attn_part_kernel(const float* __restrict__ QKV,
    const int* __restrict__ idx_top,
    float* __restrict__ Pacc, float* __restrict__ Pm, float* __restrict__ Pl)
{
  int gid = blockIdx.x;
  int q = gid & 3, c = (gid >> 2) & 7, bh = gid >> 5;
  int h = bh & 7, b = bh >> 3;
  int chunk = bh*NCH + c;            // Pacc/Pm/Pl slot (same layout as before)
  int u0 = q*9;
  int NU = (q == 3) ? 8 : 9;
  int t = threadIdx.x;
  __shared__ float qs[9][68];          // scaled Q rows (padded pitch)
  __shared__ float sc[9][132];         // scores -> exp'd scores
  __shared__ float sm[9], sl[9];

  // load + scale this block's Q rows
  for (int idx = t; idx < NU*64; idx += 256) {
    int ul = idx >> 6, e = idx & 63;
    int qi = idx_top[bh*KS + u0 + ul];
    qs[ul][e] = QKV[((size_t)(b*L_ + qi))*QS + h*HD + e] * 0.125f;
  }
  __syncthreads();

  // scores: thread k = t&127 owns one key; K row in 16 float4 regs
  {
    int k = t & 127, par = t >> 7;
    const float4* Kr = (const float4*)(QKV + ((size_t)(b*L_ + c*CH + k))*QS + 512 + h*HD);
    float4 kreg[16];
    #pragma unroll
    for (int e4 = 0; e4 < 16; e4++) kreg[e4] = Kr[e4];
    for (int ul = par; ul < NU; ul += 2) {
      float d = 0.f;
      #pragma unroll
      for (int e4 = 0; e4 < 16; e4++) {
        float4 q4 = *(const float4*)&qs[ul][e4*4];   // wave-uniform broadcast
        float4 k4 = kreg[e4];
        d += q4.x*k4.x + q4.y*k4.y + q4.z*k4.z + q4.w*k4.w;
      }
      sc[ul][k] = d;
    }
  }
  __syncthreads();

  // softmax per ul: 4 threads/row
  {
    int ul = t >> 2, sub = t & 3;
    if (ul < NU) {
      float m = -3.4e38f;
      for (int i = sub; i < 128; i += 4) m = fmaxf(m, sc[ul][i]);
      m = fmaxf(m, __shfl_xor(m, 1));
      m = fmaxf(m, __shfl_xor(m, 2));
      float l = 0.f;
      for (int i = sub; i < 128; i += 4) {
        float ev = expf(sc[ul][i] - m);
        sc[ul][i] = ev;
        l += ev;
      }
      l += __shfl_xor(l, 1);
      l += __shfl_xor(l, 2);
      if (sub == 0) { sm[ul] = m; sl[ul] = l; }
    }
  }
  __syncthreads();

  // partial PV: thread = (ug, e); ul in {ug, ug+4, ug+8}
  {
    int e = t & 63, ug = t >> 6;
    const float* Vb = QKV + 1024 + h*HD + ((size_t)(b*L_ + c*CH))*QS;
    float acc[3] = {0.f, 0.f, 0.f};
    for (int kb = 0; kb < CH; kb++) {
      float v = Vb[(size_t)kb*QS + e];
      #pragma unroll
      for (int iu = 0; iu < 3; iu++) {
        int ul = ug + iu*4;
        if (ul < NU) acc[iu] += sc[ul][kb] * v;     // sc read is wave-uniform broadcast
      }
    }
    #pragma unroll
    for (int iu = 0; iu < 3; iu++) {
      int ul = ug + iu*4;
      if (ul < NU) Pacc[((size_t)chunk*35 + u0 + ul)*64 + e] = acc[iu];
    }
  }
  if (t < NU) { Pm[chunk*35 + u0 + t] = sm[t]; Pl[chunk*35 + u0 + t] = sl[t]; }
}

// ---------------- phase B: merge partials, scatter bf16 ctx ----------------
__global__ __launch_bounds__(256) void attn_merge_kernel(const float* __restrict__ Pacc,
    const float* __restrict__ Pm, const float* __restrict__ Pl,
    const int* __restrict__ idx_top, ushort* __restrict__ CTXb)
{
  int bh = blockIdx.x;
  int h = bh & 7, b = bh >> 3;
  int t = threadIdx.x;
  __shared__ float m8[NCH*35], l8[NCH*35];
  for (int i = t; i < NCH*35; i += 256) {
    int c = i / 35, u = i - c*35;
    m8[c*35 + u] = Pm[((size_t)bh*NCH + c)*35 + u];
    l8[c*35 + u] = Pl[((size_t)bh*NCH + c)*35 + u];
  }
  __syncthreads();
  int e = t & 63, ug = t >> 6;
  #pragma unroll
  for (int iu = 0; iu < 9; iu++) {
    int u = ug + iu*4;
    if (u >= 35) break;
    float M = -3.4e38f;
    #pragma unroll
    for (int c = 0; c < NCH; c++) M = fmaxf(M, m8[c*35 + u]);
    float Ltot = 0.f, o = 0.f;
    #pragma unroll
    for (int c = 0; c < NCH; c++) {
      float w = expf(m8[c*35 + u] - M);
      Ltot += w * l8[c*35 + u];
      o += w * Pacc[(((size_t)bh*NCH + c)*35 + u)*64 + e];
    }
    int qi = idx_top[bh*KS + u];
    CTXb[((size_t)(b*L_ + qi))*DM + h*HD + e] = f2b(o / Ltot);
  }
}

// ---------------- LayerNorm (optional add), f32 + bf16 out ----------------
__global__ __launch_bounds__(512) void ln_kernel(const float* __restrict__ Xa,
    const float* __restrict__ Xadd, const float* __restrict__ g, const float* __restrict__ beta,
    float* __restrict__ outf, ushort* __restrict__ outb)
{
  int row = blockIdx.x, t = threadIdx.x;
  __shared__ float red[16];
  size_t idx = (size_t)row*DM + t;
  float v = Xa[idx];
  if (Xadd) v += Xadd[idx];
  float s = v;
  #pragma unroll
  for (int off = 32; off; off >>= 1) s += __shfl_xor(s, off);
  if ((t & 63) == 0) red[t >> 6] = s;
  __syncthreads();
  float mean = 0.f;
  #pragma unroll
  for (int k = 0; k < 8; k++) mean += red[k];
  mean *= (1.f/DM);
  float d = v - mean, q = d*d;
  #pragma unroll
  for (int off = 32; off; off >>= 1) q += __shfl_xor(q, off);
  if ((t & 63) == 0) red[8 + (t >> 6)] = q;
  __syncthreads();
  float var = 0.f;
  #pragma unroll
  for (int k = 0; k < 8; k++) var += red[8 + k];
  var *= (1.f/DM);
  float r = d / sqrtf(var + 1e-5f) * g[t] + beta[t];
  outf[idx] = r;
  if (outb) outb[idx] = f2b(r);
}

// ---------------- partial mean pool + classifier ----------------
__global__ __launch_bounds__(512) void poolp_kernel(const float* __restrict__ X, float* __restrict__ pooledP)
{
  int p = blockIdx.x;
  int t = threadIdx.x;
  int b = p >> 3, seg = p & 7;
  float s = 0.f;
  const float* base = X + ((size_t)b*L_ + seg*128)*DM + t;
  for (int l = 0; l < 128; l++) s += base[(size_t)l*DM];
  pooledP[p*DM + t] = s;
}

__global__ __launch_bounds__(64) void cls_kernel(const float* __restrict__ pooledP,
    const float* __restrict__ Wc, const float* __restrict__ bc, float* __restrict__ out)
{
  int o = blockIdx.x;
  int b = o/10, c = o%10, t = threadIdx.x;
  float s = 0.f;
  for (int d = t; d < DM; d += 64) {
    float p = 0.f;
    #pragma unroll
    for (int seg = 0; seg < 8; seg++) p += pooledP[(b*8 + seg)*DM + d];
    s += p * (1.f/L_) * Wc[d*10 + c];
  }
  #pragma unroll
  for (int off = 32; off; off >>= 1) s += __shfl_xor(s, off);
  if (t == 0) out[o] = bc[c] + s;
}

extern "C" void kernel_launch(void* const* d_in, const int* in_sizes, int n_in,
                              void* d_out, int out_size, void* d_ws, size_t ws_size,
                              hipStream_t stream)
{
  const float* src   = (const float*)d_in[0];
  const int*   idxs  = (const int*)d_in[1];
  const float* Wemb  = (const float*)d_in[2];
  const float* bemb  = (const float*)d_in[3];
  const float* Wq    = (const float*)d_in[4];
  const float* bq    = (const float*)d_in[5];
  const float* Wk    = (const float*)d_in[6];
  const float* bk    = (const float*)d_in[7];
  const float* Wv    = (const float*)d_in[8];
  const float* bv    = (const float*)d_in[9];
  const float* Wo    = (const float*)d_in[10];
  const float* bo    = (const float*)d_in[11];
  const float* g1    = (const float*)d_in[12];
  const float* beta1 = (const float*)d_in[13];
  const float* W1    = (const float*)d_in[14];
  const float* bf1   = (const float*)d_in[15];
  const float* W2    = (const float*)d_in[16];
  const float* bf2   = (const float*)d_in[17];
  const float* g2    = (const float*)d_in[18];
  const float* beta2 = (const float*)d_in[19];
  const float* gf    = (const float*)d_in[20];
  const float* betaf = (const float*)d_in[21];
  const float* Wc    = (const float*)d_in[22];
  const float* bc    = (const float*)d_in[23];
  float* out = (float*)d_out;

  float* wsf = (float*)d_ws;
  float*  X     = wsf;                              // [0, 2097152)
  ushort* Xb    = (ushort*)(wsf + 2097152);         // [2097152, 3145728)
  ushort* CTXb  = (ushort*)(wsf + 3145728);         // [3145728, 4194304)
  float*  QKV   = wsf + 4194304;                    // [4194304, 10485760)  LIVE during attention
  ushort* H     = (ushort*)(wsf + 4194304);         // FFN hidden bf16 (QKV dead by FFN1)
  float*  Y     = wsf + 8388608;                    // [8388608, 10485760)  FFN2 out (QKV dead)
  // attention scratch: alias Xb (dead between QKV-GEMM read and ln1 rewrite)
  float*  Pacc  = wsf + 2097152;                    // 573,440 fl
  float*  VmeanP = wsf + 2670592;                   // 32,768 fl (ends 2703360 < 3145728)
  ushort* Wqkvt = (ushort*)(wsf + 10485760);        // 786,432 fl
  ushort* Wot   = (ushort*)(wsf + 11272192);        // 262,144 fl
  ushort* W1t   = (ushort*)(wsf + 11534336);        // 1,048,576 fl
  ushort* W2t   = (ushort*)(wsf + 12582912);        // 1,048,576 fl
  float*  bqkv  = wsf + 13631488;                   // 3,072
  float*  Msc   = wsf + 13634560;                   // 32,768 (dead after topk)
  float*  Pm    = wsf + 13634560;                   // alias Msc: 8,960
  float*  Pl    = wsf + 13634560 + 8960;            // alias Msc: 8,960
  float*  Vmean = wsf + 13667328;                   // 2,048
  float*  pooledP = wsf + 13669376;                 // 16,384
  int*    idx_top = (int*)(wsf + 13685760);         // 1,120

  for (int l = 0; l < 2; l++) {
    wconv_kernel<<<dim3(DM/32, DM/32), 256, 0, stream>>>(Wq + (size_t)l*DM*DM, Wqkvt + ((size_t)l*QS +    0)*DM, DM, DM);
    wconv_kernel<<<dim3(DM/32, DM/32), 256, 0, stream>>>(Wk + (size_t)l*DM*DM, Wqkvt + ((size_t)l*QS +  512)*DM, DM, DM);
    wconv_kernel<<<dim3(DM/32, DM/32), 256, 0, stream>>>(Wv + (size_t)l*DM*DM, Wqkvt + ((size_t)l*QS + 1024)*DM, DM, DM);
    wconv_kernel<<<dim3(DM/32, DM/32), 256, 0, stream>>>(Wo + (size_t)l*DM*DM, Wot + (size_t)l*DM*DM, DM, DM);
    wconv_kernel<<<dim3(DFF/32, DM/32), 256, 0, stream>>>(W1 + (size_t)l*DM*DFF, W1t + (size_t)l*DFF*DM, DM, DFF);
    wconv_kernel<<<dim3(DM/32, DFF/32), 256, 0, stream>>>(W2 + (size_t)l*DFF*DM, W2t + (size_t)l*DM*DFF, DFF, DM);
  }
  bcat_kernel<<<12, 256, 0, stream>>>(bq, bk, bv, bqkv);

  const int M = B_ * L_; // 4096
  embed_kernel<<<M, 512, 0, stream>>>(src, Wemb, bemb, X, Xb);

  for (int l = 0; l < 2; l++) {
    const size_t vo = (size_t)l*DM;
    mfma_gemm<128,0><<<dim3(QS/128, M/128), 256, 0, stream>>>(
        Xb, Wqkvt + (size_t)l*QS*DM, bqkv + (size_t)l*QS, nullptr, QKV, nullptr, M, QS, DM);
    qksample_kernel<<<B_*NH*L_, 64, 0, stream>>>(QKV, idxs + (size_t)l*L_*KS, Msc);
    topk_kernel<<<B_*NH, 64, 0, stream>>>(Msc, idx_top);
    vmean_part_kernel<<<B_*NH*VSEG, 64, 0, stream>>>(QKV, VmeanP);
    vmean_merge_kernel<<<B_*NH, 64, 0, stream>>>(VmeanP, Vmean);
    ctxfill_kernel<<<M, 512, 0, stream>>>(Vmean, CTXb);
    attn_part_kernel<<<B_*NH*NCH*4, 256, 0, stream>>>(QKV, idx_top, Pacc, Pm, Pl);
    attn_merge_kernel<<<B_*NH, 256, 0, stream>>>(Pacc, Pm, Pl, idx_top, CTXb);
    mfma_gemm<64,2><<<dim3(DM/64, M/128), 256, 0, stream>>>(
        CTXb, Wot + (size_t)l*DM*DM, bo + vo, X, X, nullptr, M, DM, DM);
    ln_kernel<<<M, 512, 0, stream>>>(X, nullptr, g1 + vo, beta1 + vo, X, Xb);
    mfma_gemm<128,1><<<dim3(DFF/128, M/128), 256, 0, stream>>>(
        Xb, W1t + (size_t)l*DFF*DM, bf1 + (size_t)l*DFF, nullptr, nullptr, H, M, DFF, DM);
    mfma_gemm<64,0><<<dim3(DM/64, M/128), 256, 0, stream>>>(
        H, W2t + (size_t)l*DM*DFF, bf2 + vo, nullptr, Y, nullptr, M, DM, DFF);
    ln_kernel<<<M, 512, 0, stream>>>(X, Y, g2 + vo, beta2 + vo, X, Xb);
  }
  ln_kernel<<<M, 512, 0, stream>>>(X, nullptr, gf, betaf, X, nullptr);
  poolp_kernel<<<B_*8, 512, 0, stream>>>(X, pooledP);
  cls_kernel<<<40, 64, 0, stream>>>(pooledP, Wc, bc, out);
}

// Round 11
// 519.121 us; speedup vs baseline: 1.9765x; 1.0924x over previous
//
#include <hip/hip_runtime.h>
#include <hip/hip_bf16.h>
#include <math.h>

#define B_ 4
#define L_ 1024
#define DM 512
#define NH 8
#define HD 64
#define DFF 2048
#define KS 35
#define QS 1536   // packed QKV row stride
#define CH 128    // attention key chunk
#define NCH (L_/CH)
#define VSEG 16   // V-mean segments per head

typedef __attribute__((ext_vector_type(8))) short bf16x8;
typedef __attribute__((ext_vector_type(4))) float f32x4;

__device__ inline ushort f2b(float f){
  __hip_bfloat16 h = __float2bfloat16(f);
  return *reinterpret_cast<ushort*>(&h);
}
__device__ inline float gelu_exact(float x){
  return 0.5f*x*(1.0f+erff(x*0.7071067811865476f));
}

#define GLOAD16(g, l) __builtin_amdgcn_global_load_lds( \
    (const __attribute__((address_space(1))) void*)(g), \
    (__attribute__((address_space(3))) void*)(l), 16, 0, 0)

// ---------------- weight convert + transpose to bf16 [N][K] ----------------
__global__ __launch_bounds__(256) void wconv_kernel(const float* __restrict__ W,
    ushort* __restrict__ Wt, int K, int N)
{
  __shared__ float tile[32][33];
  int n0 = blockIdx.x*32, k0 = blockIdx.y*32;
  int tx = threadIdx.x & 31, ty = threadIdx.x >> 5;
  #pragma unroll
  for (int i = ty; i < 32; i += 8) tile[i][tx] = W[(size_t)(k0+i)*N + n0+tx];
  __syncthreads();
  #pragma unroll
  for (int i = ty; i < 32; i += 8) Wt[(size_t)(n0+i)*K + k0+tx] = f2b(tile[tx][i]);
}

__global__ __launch_bounds__(256) void bcat_kernel(const float* __restrict__ bq,
    const float* __restrict__ bk, const float* __restrict__ bv, float* __restrict__ bqkv)
{
  int i = blockIdx.x*256 + threadIdx.x;   // 0..3071
  if (i >= 2*QS) return;
  int l = i / QS, j = i - l*QS;
  const float* src = (j < 512) ? bq : (j < 1024 ? bk : bv);
  bqkv[i] = src[l*DM + (j & 511)];
}

// ---------------- bf16 MFMA GEMM, double-buffered (2-phase) ----------------
// A: [M][K] bf16; Bt: [N][K] bf16; MODE 0: f32 out, 1: gelu->bf16 out, 2: +R f32 out
template<int BN, int MODE>
__global__ __launch_bounds__(256) void mfma_gemm(
    const ushort* __restrict__ A, const ushort* __restrict__ Bt,
    const float* __restrict__ bias, const float* __restrict__ R,
    float* __restrict__ Cf, ushort* __restrict__ Cb,
    int M, int N, int K)
{
  constexpr int BM = 128, BK = 32;
  constexpr int NF = BN/32;
  constexpr int ACH = BM*4;          // 16B chunks per A tile
  constexpr int BCH = BN*4;
  __shared__ __align__(16) ushort As[2][BM*BK];
  __shared__ __align__(16) ushort Bs[2][BN*BK];
  const int t = threadIdx.x, lane = t & 63, w = t >> 6, wr = w >> 1, wc = w & 1;
  const int row0 = blockIdx.y*BM, col0 = blockIdx.x*BN;

  // staging: linear LDS dest, inverse-swizzled global source
  const ushort* aSrc[ACH/256]; int aDst[ACH/256];
  #pragma unroll
  for (int j = 0; j < ACH/256; j++) {
    int ch = j*256 + t, r = ch >> 2, cc = ch & 3, cs = cc ^ ((r >> 1) & 3);
    aSrc[j] = A + (size_t)(row0 + r)*K + cs*8;
    aDst[j] = ch*16;
  }
  const ushort* bSrc[BCH/256]; int bDst[BCH/256];
  #pragma unroll
  for (int j = 0; j < BCH/256; j++) {
    int ch = j*256 + t, r = ch >> 2, cc = ch & 3, cs = cc ^ ((r >> 1) & 3);
    bSrc[j] = Bt + (size_t)(col0 + r)*K + cs*8;
    bDst[j] = ch*16;
  }
  // fragment read offsets (swizzled)
  int aOff[4], bOff[NF];
  #pragma unroll
  for (int m = 0; m < 4; m++) {
    int r = wr*64 + m*16 + (lane & 15);
    aOff[m] = r*64 + (((lane >> 4)*16) ^ (((r >> 1) & 3) << 4));
  }
  #pragma unroll
  for (int n = 0; n < NF; n++) {
    int r = wc*(BN/2) + n*16 + (lane & 15);
    bOff[n] = r*64 + (((lane >> 4)*16) ^ (((r >> 1) & 3) << 4));
  }
  f32x4 zero = {0.f, 0.f, 0.f, 0.f};
  f32x4 acc[4][NF];
  #pragma unroll
  for (int m = 0; m < 4; m++)
    #pragma unroll
    for (int n = 0; n < NF; n++) acc[m][n] = zero;

  // prologue: stage tile 0 into buf 0
  #pragma unroll
  for (int j = 0; j < ACH/256; j++) GLOAD16(aSrc[j], (char*)As[0] + aDst[j]);
  #pragma unroll
  for (int j = 0; j < BCH/256; j++) GLOAD16(bSrc[j], (char*)Bs[0] + bDst[j]);
  __syncthreads();

  const int nk = K / BK;
  for (int ki = 0; ki < nk; ki++) {
    const int cur = ki & 1;
    if (ki + 1 < nk) {               // issue next-tile loads first (overlap with MFMA)
      const int kt = (ki + 1)*BK;
      #pragma unroll
      for (int j = 0; j < ACH/256; j++) GLOAD16(aSrc[j] + kt, (char*)As[cur^1] + aDst[j]);
      #pragma unroll
      for (int j = 0; j < BCH/256; j++) GLOAD16(bSrc[j] + kt, (char*)Bs[cur^1] + bDst[j]);
    }
    bf16x8 af[4], bfr[NF];
    #pragma unroll
    for (int m = 0; m < 4; m++) af[m] = *(const bf16x8*)((const char*)As[cur] + aOff[m]);
    #pragma unroll
    for (int n = 0; n < NF; n++) bfr[n] = *(const bf16x8*)((const char*)Bs[cur] + bOff[n]);
    #pragma unroll
    for (int m = 0; m < 4; m++)
      #pragma unroll
      for (int n = 0; n < NF; n++)
        acc[m][n] = __builtin_amdgcn_mfma_f32_16x16x32_bf16(af[m], bfr[n], acc[m][n], 0, 0, 0);
    __syncthreads();                 // drains next-tile vmem writes + this-tile LDS reads
  }
  #pragma unroll
  for (int m = 0; m < 4; m++) {
    int rb = row0 + wr*64 + m*16 + ((lane >> 4) << 2);
    #pragma unroll
    for (int n = 0; n < NF; n++) {
      int c = col0 + wc*(BN/2) + n*16 + (lane & 15);
      float bv = bias[c];
      #pragma unroll
      for (int j = 0; j < 4; j++) {
        size_t idx = (size_t)(rb + j)*N + c;
        float v = acc[m][n][j] + bv;
        if (MODE == 1)      Cb[idx] = f2b(gelu_exact(v));
        else if (MODE == 2) Cf[idx] = v + R[idx];
        else                Cf[idx] = v;
      }
    }
  }
}

// ---------------- embed + positional encoding ----------------
__global__ __launch_bounds__(512) void embed_kernel(const float* __restrict__ src,
    const float* __restrict__ Wemb, const float* __restrict__ bemb,
    float* __restrict__ X, ushort* __restrict__ Xb)
{
  int row = blockIdx.x, l = row & (L_-1), t = threadIdx.x;
  __shared__ float s_src[32];
  if (t < 32) s_src[t] = src[row*32 + t];
  __syncthreads();
  float acc = bemb[t];
  #pragma unroll
  for (int k = 0; k < 32; k++) acc += s_src[k]*Wemb[k*DM + t];
  int i2 = t & ~1;
  float freq = expf((float)i2 * (-9.210340371976184f/512.0f));
  float ang = (float)l * freq;
  acc += (t & 1) ? cosf(ang) : sinf(ang);
  size_t idx = (size_t)row*DM + t;
  X[idx] = acc;
  Xb[idx] = f2b(acc);
}

// ---------------- QK_sample -> M score (j-parallel, short chains) ----------------
__global__ __launch_bounds__(64) void qksample_kernel(const float* __restrict__ QKV,
    const int* __restrict__ idx_s, float* __restrict__ Msc)
{
  int gid = blockIdx.x;              // (b*8+h)*1024 + i
  int i = gid & (L_-1), h = (gid >> 10) & 7, b = gid >> 13;
  int t = threadIdx.x;
  int j4 = t >> 2, e4 = t & 3;       // lane = j4*4 + e4
  const float* Qrow = QKV + ((size_t)(b*L_ + i))*QS + h*HD + e4*16;
  float4 q[4];
  #pragma unroll
  for (int r = 0; r < 4; r++) q[r] = *(const float4*)(Qrow + r*4);
  const float* Kbase = QKV + 512 + h*HD + (size_t)b*L_*QS + e4*16;
  const int* idq = idx_s + i*KS;
  float mx = -3.4e38f, sm = 0.f;
  #pragma unroll
  for (int p = 0; p < 3; p++) {
    int j = p*16 + j4;
    int jc = (j < KS) ? j : 0;       // inactive lanes redo j=0 (result discarded)
    int s = idq[jc];
    const float4* Kr = (const float4*)(Kbase + (size_t)s*QS);
    float4 k0 = Kr[0], k1 = Kr[1], k2 = Kr[2], k3 = Kr[3];
    float d = q[0].x*k0.x + q[0].y*k0.y + q[0].z*k0.z + q[0].w*k0.w;
    d += q[1].x*k1.x + q[1].y*k1.y + q[1].z*k1.z + q[1].w*k1.w;
    d += q[2].x*k2.x + q[2].y*k2.y + q[2].z*k2.z + q[2].w*k2.w;
    d += q[3].x*k3.x + q[3].y*k3.y + q[3].z*k3.z + q[3].w*k3.w;
    d += __shfl_xor(d, 1);
    d += __shfl_xor(d, 2);
    if (j < KS && e4 == 0) { mx = fmaxf(mx, d); sm += d; }
  }
  #pragma unroll
  for (int off = 4; off < 64; off <<= 1) {
    mx = fmaxf(mx, __shfl_xor(mx, off));
    sm += __shfl_xor(sm, off);
  }
  if (t == 0) Msc[gid] = mx - sm*(1.0f/KS);
}

// ---------------- register-resident top-35 (tie-break lower index) ----------------
__global__ __launch_bounds__(64) void topk_kernel(const float* __restrict__ Msc, int* __restrict__ idx_top)
{
  int bh = blockIdx.x, t = threadIdx.x;
  float v[16];
  #pragma unroll
  for (int r = 0; r < 16; r++) v[r] = Msc[(size_t)bh*L_ + r*64 + t];
  for (int sel = 0; sel < KS; sel++) {
    float bv = -3.4e38f; int br = 0;
    #pragma unroll
    for (int r = 0; r < 16; r++) {
      bool gt = v[r] > bv;
      bv = gt ? v[r] : bv;
      br = gt ? r : br;
    }
    int bi = br*64 + t;
    #pragma unroll
    for (int off = 32; off; off >>= 1) {
      float ov = __shfl_xor(bv, off); int oi = __shfl_xor(bi, off);
      if (ov > bv || (ov == bv && oi < bi)) { bv = ov; bi = oi; }
    }
    if (t == 0) idx_top[bh*KS + sel] = bi;
    if ((bi & 63) == t) v[bi >> 6] = -3.4e38f;
  }
}

// ---------------- V mean over L: segmented partials + merge (occupancy) ----------------
__global__ __launch_bounds__(64) void vmean_part_kernel(const float* __restrict__ QKV,
    float* __restrict__ VmeanP)
{
  int gid = blockIdx.x;              // bh*VSEG + seg  (512 blocks)
  int seg = gid & (VSEG-1), bh = gid >> 4;
  int h = bh & 7, b = bh >> 3;
  int e = threadIdx.x;
  const float* Vb = QKV + 1024 + h*HD + ((size_t)(b*L_ + seg*(L_/VSEG)))*QS;
  float s = 0.f;
  for (int l0 = 0; l0 < L_/VSEG; l0 += 8) {
    float vv[8];
    #pragma unroll
    for (int j = 0; j < 8; j++) vv[j] = Vb[(size_t)(l0+j)*QS + e];
    #pragma unroll
    for (int j = 0; j < 8; j++) s += vv[j];
  }
  VmeanP[gid*HD + e] = s;
}

__global__ __launch_bounds__(64) void vmean_merge_kernel(const float* __restrict__ VmeanP,
    float* __restrict__ Vmean)
{
  int bh = blockIdx.x, e = threadIdx.x;
  float s = 0.f;
  #pragma unroll
  for (int seg = 0; seg < VSEG; seg++) s += VmeanP[(bh*VSEG + seg)*HD + e];
  Vmean[bh*HD + e] = s * (1.f/L_);
}

// ---------------- fill context with broadcast V-mean (bf16) ----------------
__global__ __launch_bounds__(512) void ctxfill_kernel(const float* __restrict__ Vmean, ushort* __restrict__ CTXb)
{
  int row = blockIdx.x, b = row >> 10, t = threadIdx.x;
  CTXb[(size_t)row*DM + t] = f2b(Vmean[b*DM + t]);
}

// ---------------- chunked flash attention, phase A (query-split ×4, pipelined PV) ----
// grid: ((b*8+h)*8 + chunk)*4 + q  (1024 blocks), block 256
__global__ __launch_bounds__(256) void attn_part_kernel(const float* __restrict__ QKV,
    const int* __restrict__ idx_top,
    float* __restrict__ Pacc, float* __restrict__ Pm, float* __restrict__ Pl)
{
  int gid = blockIdx.x;
  int q = gid & 3, c = (gid >> 2) & 7, bh = gid >> 5;
  int h = bh & 7, b = bh >> 3;
  int chunk = bh*NCH + c;            // Pacc/Pm/Pl slot (same layout as before)
  int u0 = q*9;
  int NU = (q == 3) ? 8 : 9;
  int t = threadIdx.x;
  __shared__ float qs[9][68];          // scaled Q rows (padded pitch)
  __shared__ float sc[9][132];         // scores -> exp'd scores
  __shared__ float sm[9], sl[9];

  // load + scale this block's Q rows
  for (int idx = t; idx < NU*64; idx += 256) {
    int ul = idx >> 6, e = idx & 63;
    int qi = idx_top[bh*KS + u0 + ul];
    qs[ul][e] = QKV[((size_t)(b*L_ + qi))*QS + h*HD + e] * 0.125f;
  }
  __syncthreads();

  // scores: thread k = t&127 owns one key; K row in 16 float4 regs
  {
    int k = t & 127, par = t >> 7;
    const float4* Kr = (const float4*)(QKV + ((size_t)(b*L_ + c*CH + k))*QS + 512 + h*HD);
    float4 kreg[16];
    #pragma unroll
    for (int e4 = 0; e4 < 16; e4++) kreg[e4] = Kr[e4];
    for (int ul = par; ul < NU; ul += 2) {
      float d = 0.f;
      #pragma unroll
      for (int e4 = 0; e4 < 16; e4++) {
        float4 q4 = *(const float4*)&qs[ul][e4*4];   // wave-uniform broadcast
        float4 k4 = kreg[e4];
        d += q4.x*k4.x + q4.y*k4.y + q4.z*k4.z + q4.w*k4.w;
      }
      sc[ul][k] = d;
    }
  }
  __syncthreads();

  // softmax per ul: 4 threads/row
  {
    int ul = t >> 2, sub = t & 3;
    if (ul < NU) {
      float m = -3.4e38f;
      for (int i = sub; i < 128; i += 4) m = fmaxf(m, sc[ul][i]);
      m = fmaxf(m, __shfl_xor(m, 1));
      m = fmaxf(m, __shfl_xor(m, 2));
      float l = 0.f;
      for (int i = sub; i < 128; i += 4) {
        float ev = expf(sc[ul][i] - m);
        sc[ul][i] = ev;
        l += ev;
      }
      l += __shfl_xor(l, 1);
      l += __shfl_xor(l, 2);
      if (sub == 0) { sm[ul] = m; sl[ul] = l; }
    }
  }
  __syncthreads();

  // partial PV: thread = (ug, e); 8-deep manual load pipeline (ILP — the round-10 fix)
  {
    int e = t & 63, ug = t >> 6;
    const float* Vb = QKV + 1024 + h*HD + ((size_t)(b*L_ + c*CH))*QS;
    float acc[3] = {0.f, 0.f, 0.f};
    for (int kb0 = 0; kb0 < CH; kb0 += 8) {
      float vv[8];
      #pragma unroll
      for (int j = 0; j < 8; j++) vv[j] = Vb[(size_t)(kb0 + j)*QS + e];   // 8 loads in flight
      #pragma unroll
      for (int j = 0; j < 8; j++) {
        #pragma unroll
        for (int iu = 0; iu < 3; iu++) {
          int ul = ug + iu*4;
          if (ul < NU) acc[iu] += sc[ul][kb0 + j] * vv[j];   // sc read is wave-uniform broadcast
        }
      }
    }
    #pragma unroll
    for (int iu = 0; iu < 3; iu++) {
      int ul = ug + iu*4;
      if (ul < NU) Pacc[((size_t)chunk*35 + u0 + ul)*64 + e] = acc[iu];
    }
  }
  if (t < NU) { Pm[chunk*35 + u0 + t] = sm[t]; Pl[chunk*35 + u0 + t] = sl[t]; }
}

// ---------------- phase B: merge partials, scatter bf16 ctx ----------------
__global__ __launch_bounds__(256) void attn_merge_kernel(const float* __restrict__ Pacc,
    const float* __restrict__ Pm, const float* __restrict__ Pl,
    const int* __restrict__ idx_top, ushort* __restrict__ CTXb)
{
  int bh = blockIdx.x;
  int h = bh & 7, b = bh >> 3;
  int t = threadIdx.x;
  __shared__ float m8[NCH*35], l8[NCH*35];
  for (int i = t; i < NCH*35; i += 256) {
    int c = i / 35, u = i - c*35;
    m8[c*35 + u] = Pm[((size_t)bh*NCH + c)*35 + u];
    l8[c*35 + u] = Pl[((size_t)bh*NCH + c)*35 + u];
  }
  __syncthreads();
  int e = t & 63, ug = t >> 6;
  #pragma unroll
  for (int iu = 0; iu < 9; iu++) {
    int u = ug + iu*4;
    if (u >= 35) break;
    float M = -3.4e38f;
    #pragma unroll
    for (int c = 0; c < NCH; c++) M = fmaxf(M, m8[c*35 + u]);
    float Ltot = 0.f, o = 0.f;
    #pragma unroll
    for (int c = 0; c < NCH; c++) {
      float w = expf(m8[c*35 + u] - M);
      Ltot += w * l8[c*35 + u];
      o += w * Pacc[(((size_t)bh*NCH + c)*35 + u)*64 + e];
    }
    int qi = idx_top[bh*KS + u];
    CTXb[((size_t)(b*L_ + qi))*DM + h*HD + e] = f2b(o / Ltot);
  }
}

// ---------------- LayerNorm (optional add), f32 + bf16 out ----------------
__global__ __launch_bounds__(512) void ln_kernel(const float* __restrict__ Xa,
    const float* __restrict__ Xadd, const float* __restrict__ g, const float* __restrict__ beta,
    float* __restrict__ outf, ushort* __restrict__ outb)
{
  int row = blockIdx.x, t = threadIdx.x;
  __shared__ float red[16];
  size_t idx = (size_t)row*DM + t;
  float v = Xa[idx];
  if (Xadd) v += Xadd[idx];
  float s = v;
  #pragma unroll
  for (int off = 32; off; off >>= 1) s += __shfl_xor(s, off);
  if ((t & 63) == 0) red[t >> 6] = s;
  __syncthreads();
  float mean = 0.f;
  #pragma unroll
  for (int k = 0; k < 8; k++) mean += red[k];
  mean *= (1.f/DM);
  float d = v - mean, q = d*d;
  #pragma unroll
  for (int off = 32; off; off >>= 1) q += __shfl_xor(q, off);
  if ((t & 63) == 0) red[8 + (t >> 6)] = q;
  __syncthreads();
  float var = 0.f;
  #pragma unroll
  for (int k = 0; k < 8; k++) var += red[8 + k];
  var *= (1.f/DM);
  float r = d / sqrtf(var + 1e-5f) * g[t] + beta[t];
  outf[idx] = r;
  if (outb) outb[idx] = f2b(r);
}

// ---------------- partial mean pool + classifier ----------------
__global__ __launch_bounds__(512) void poolp_kernel(const float* __restrict__ X, float* __restrict__ pooledP)
{
  int p = blockIdx.x;
  int t = threadIdx.x;
  int b = p >> 3, seg = p & 7;
  float s = 0.f;
  const float* base = X + ((size_t)b*L_ + seg*128)*DM + t;
  for (int l = 0; l < 128; l++) s += base[(size_t)l*DM];
  pooledP[p*DM + t] = s;
}

__global__ __launch_bounds__(64) void cls_kernel(const float* __restrict__ pooledP,
    const float* __restrict__ Wc, const float* __restrict__ bc, float* __restrict__ out)
{
  int o = blockIdx.x;
  int b = o/10, c = o%10, t = threadIdx.x;
  float s = 0.f;
  for (int d = t; d < DM; d += 64) {
    float p = 0.f;
    #pragma unroll
    for (int seg = 0; seg < 8; seg++) p += pooledP[(b*8 + seg)*DM + d];
    s += p * (1.f/L_) * Wc[d*10 + c];
  }
  #pragma unroll
  for (int off = 32; off; off >>= 1) s += __shfl_xor(s, off);
  if (t == 0) out[o] = bc[c] + s;
}

extern "C" void kernel_launch(void* const* d_in, const int* in_sizes, int n_in,
                              void* d_out, int out_size, void* d_ws, size_t ws_size,
                              hipStream_t stream)
{
  const float* src   = (const float*)d_in[0];
  const int*   idxs  = (const int*)d_in[1];
  const float* Wemb  = (const float*)d_in[2];
  const float* bemb  = (const float*)d_in[3];
  const float* Wq    = (const float*)d_in[4];
  const float* bq    = (const float*)d_in[5];
  const float* Wk    = (const float*)d_in[6];
  const float* bk    = (const float*)d_in[7];
  const float* Wv    = (const float*)d_in[8];
  const float* bv    = (const float*)d_in[9];
  const float* Wo    = (const float*)d_in[10];
  const float* bo    = (const float*)d_in[11];
  const float* g1    = (const float*)d_in[12];
  const float* beta1 = (const float*)d_in[13];
  const float* W1    = (const float*)d_in[14];
  const float* bf1   = (const float*)d_in[15];
  const float* W2    = (const float*)d_in[16];
  const float* bf2   = (const float*)d_in[17];
  const float* g2    = (const float*)d_in[18];
  const float* beta2 = (const float*)d_in[19];
  const float* gf    = (const float*)d_in[20];
  const float* betaf = (const float*)d_in[21];
  const float* Wc    = (const float*)d_in[22];
  const float* bc    = (const float*)d_in[23];
  float* out = (float*)d_out;

  float* wsf = (float*)d_ws;
  float*  X     = wsf;                              // [0, 2097152)
  ushort* Xb    = (ushort*)(wsf + 2097152);         // [2097152, 3145728)
  ushort* CTXb  = (ushort*)(wsf + 3145728);         // [3145728, 4194304)
  float*  QKV   = wsf + 4194304;                    // [4194304, 10485760)  LIVE during attention
  ushort* H     = (ushort*)(wsf + 4194304);         // FFN hidden bf16 (QKV dead by FFN1)
  float*  Y     = wsf + 8388608;                    // [8388608, 10485760)  FFN2 out (QKV dead)
  // attention scratch: alias Xb (dead between QKV-GEMM read and ln1 rewrite)
  float*  Pacc  = wsf + 2097152;                    // 573,440 fl
  float*  VmeanP = wsf + 2670592;                   // 32,768 fl (ends 2703360 < 3145728)
  ushort* Wqkvt = (ushort*)(wsf + 10485760);        // 786,432 fl
  ushort* Wot   = (ushort*)(wsf + 11272192);        // 262,144 fl
  ushort* W1t   = (ushort*)(wsf + 11534336);        // 1,048,576 fl
  ushort* W2t   = (ushort*)(wsf + 12582912);        // 1,048,576 fl
  float*  bqkv  = wsf + 13631488;                   // 3,072
  float*  Msc   = wsf + 13634560;                   // 32,768 (dead after topk)
  float*  Pm    = wsf + 13634560;                   // alias Msc: 8,960
  float*  Pl    = wsf + 13634560 + 8960;            // alias Msc: 8,960
  float*  Vmean = wsf + 13667328;                   // 2,048
  float*  pooledP = wsf + 13669376;                 // 16,384
  int*    idx_top = (int*)(wsf + 13685760);         // 1,120

  for (int l = 0; l < 2; l++) {
    wconv_kernel<<<dim3(DM/32, DM/32), 256, 0, stream>>>(Wq + (size_t)l*DM*DM, Wqkvt + ((size_t)l*QS +    0)*DM, DM, DM);
    wconv_kernel<<<dim3(DM/32, DM/32), 256, 0, stream>>>(Wk + (size_t)l*DM*DM, Wqkvt + ((size_t)l*QS +  512)*DM, DM, DM);
    wconv_kernel<<<dim3(DM/32, DM/32), 256, 0, stream>>>(Wv + (size_t)l*DM*DM, Wqkvt + ((size_t)l*QS + 1024)*DM, DM, DM);
    wconv_kernel<<<dim3(DM/32, DM/32), 256, 0, stream>>>(Wo + (size_t)l*DM*DM, Wot + (size_t)l*DM*DM, DM, DM);
    wconv_kernel<<<dim3(DFF/32, DM/32), 256, 0, stream>>>(W1 + (size_t)l*DM*DFF, W1t + (size_t)l*DFF*DM, DM, DFF);
    wconv_kernel<<<dim3(DM/32, DFF/32), 256, 0, stream>>>(W2 + (size_t)l*DFF*DM, W2t + (size_t)l*DM*DFF, DFF, DM);
  }
  bcat_kernel<<<12, 256, 0, stream>>>(bq, bk, bv, bqkv);

  const int M = B_ * L_; // 4096
  embed_kernel<<<M, 512, 0, stream>>>(src, Wemb, bemb, X, Xb);

  for (int l = 0; l < 2; l++) {
    const size_t vo = (size_t)l*DM;
    mfma_gemm<128,0><<<dim3(QS/128, M/128), 256, 0, stream>>>(
        Xb, Wqkvt + (size_t)l*QS*DM, bqkv + (size_t)l*QS, nullptr, QKV, nullptr, M, QS, DM);
    qksample_kernel<<<B_*NH*L_, 64, 0, stream>>>(QKV, idxs + (size_t)l*L_*KS, Msc);
    topk_kernel<<<B_*NH, 64, 0, stream>>>(Msc, idx_top);
    vmean_part_kernel<<<B_*NH*VSEG, 64, 0, stream>>>(QKV, VmeanP);
    vmean_merge_kernel<<<B_*NH, 64, 0, stream>>>(VmeanP, Vmean);
    ctxfill_kernel<<<M, 512, 0, stream>>>(Vmean, CTXb);
    attn_part_kernel<<<B_*NH*NCH*4, 256, 0, stream>>>(QKV, idx_top, Pacc, Pm, Pl);
    attn_merge_kernel<<<B_*NH, 256, 0, stream>>>(Pacc, Pm, Pl, idx_top, CTXb);
    mfma_gemm<64,2><<<dim3(DM/64, M/128), 256, 0, stream>>>(
        CTXb, Wot + (size_t)l*DM*DM, bo + vo, X, X, nullptr, M, DM, DM);
    ln_kernel<<<M, 512, 0, stream>>>(X, nullptr, g1 + vo, beta1 + vo, X, Xb);
    mfma_gemm<128,1><<<dim3(DFF/128, M/128), 256, 0, stream>>>(
        Xb, W1t + (size_t)l*DFF*DM, bf1 + (size_t)l*DFF, nullptr, nullptr, H, M, DFF, DM);
    mfma_gemm<64,0><<<dim3(DM/64, M/128), 256, 0, stream>>>(
        H, W2t + (size_t)l*DM*DFF, bf2 + vo, nullptr, Y, nullptr, M, DM, DFF);
    ln_kernel<<<M, 512, 0, stream>>>(X, Y, g2 + vo, beta2 + vo, X, Xb);
  }
  ln_kernel<<<M, 512, 0, stream>>>(X, nullptr, gf, betaf, X, nullptr);
  poolp_kernel<<<B_*8, 512, 0, stream>>>(X, pooledP);
  cls_kernel<<<40, 64, 0, stream>>>(pooledP, Wc, bc, out);
}

// Round 12
// 497.821 us; speedup vs baseline: 2.0611x; 1.0428x over previous
//
#include <hip/hip_runtime.h>
#include <hip/hip_bf16.h>
#include <math.h>

#define B_ 4
#define L_ 1024
#define DM 512
#define NH 8
#define HD 64
#define DFF 2048
#define KS 35
#define QS 1536   // packed QKV row stride
#define CH 128    // attention key chunk
#define NCH (L_/CH)
#define VSEG 16   // V-mean segments per head

typedef __attribute__((ext_vector_type(8))) short bf16x8;
typedef __attribute__((ext_vector_type(4))) float f32x4;

__device__ inline ushort f2b(float f){
  __hip_bfloat16 h = __float2bfloat16(f);
  return *reinterpret_cast<ushort*>(&h);
}
__device__ inline float gelu_exact(float x){
  return 0.5f*x*(1.0f+erff(x*0.7071067811865476f));
}

#define GLOAD16(g, l) __builtin_amdgcn_global_load_lds( \
    (const __attribute__((address_space(1))) void*)(g), \
    (__attribute__((address_space(3))) void*)(l), 16, 0, 0)

// ---------------- weight convert + transpose to bf16 [N][K] ----------------
__global__ __launch_bounds__(256) void wconv_kernel(const float* __restrict__ W,
    ushort* __restrict__ Wt, int K, int N)
{
  __shared__ float tile[32][33];
  int n0 = blockIdx.x*32, k0 = blockIdx.y*32;
  int tx = threadIdx.x & 31, ty = threadIdx.x >> 5;
  #pragma unroll
  for (int i = ty; i < 32; i += 8) tile[i][tx] = W[(size_t)(k0+i)*N + n0+tx];
  __syncthreads();
  #pragma unroll
  for (int i = ty; i < 32; i += 8) Wt[(size_t)(n0+i)*K + k0+tx] = f2b(tile[tx][i]);
}

__global__ __launch_bounds__(256) void bcat_kernel(const float* __restrict__ bq,
    const float* __restrict__ bk, const float* __restrict__ bv, float* __restrict__ bqkv)
{
  int i = blockIdx.x*256 + threadIdx.x;   // 0..3071
  if (i >= 2*QS) return;
  int l = i / QS, j = i - l*QS;
  const float* src = (j < 512) ? bq : (j < 1024 ? bk : bv);
  bqkv[i] = src[l*DM + (j & 511)];
}

// ---------------- bf16 MFMA GEMM, double-buffered, BM/BN templated, XCD-swizzled ----
// A: [M][K] bf16; Bt: [N][K] bf16; MODE 0: f32 out, 1: gelu->bf16 out, 2: +R f32 out
template<int BM, int BN, int MODE>
__global__ __launch_bounds__(256) void mfma_gemm(
    const ushort* __restrict__ A, const ushort* __restrict__ Bt,
    const float* __restrict__ bias, const float* __restrict__ R,
    float* __restrict__ Cf, ushort* __restrict__ Cb,
    int M, int N, int K)
{
  constexpr int BK = 32;
  constexpr int MF = BM/32;          // A fragments per wave
  constexpr int NF = BN/32;          // B fragments per wave
  constexpr int AIT = BM*4/256;      // staging iters for A tile (16B chunks / 256 thr)
  constexpr int BIT = BN*4/256;
  __shared__ __align__(16) ushort As[2][BM*BK];
  __shared__ __align__(16) ushort Bs[2][BN*BK];
  const int t = threadIdx.x, lane = t & 63, w = t >> 6, wr = w >> 1, wc = w & 1;

  // XCD-chunked bijective swizzle (all grids are multiples of 8)
  const int gx = gridDim.x;
  const int nwg = gx * gridDim.y;
  const int bid = blockIdx.y*gx + blockIdx.x;
  const int swz = (bid & 7)*(nwg >> 3) + (bid >> 3);
  const int row0 = (swz / gx)*BM, col0 = (swz % gx)*BN;

  // staging: linear LDS dest, inverse-swizzled global source
  const ushort* aSrc[AIT]; int aDst[AIT];
  #pragma unroll
  for (int j = 0; j < AIT; j++) {
    int ch = j*256 + t, r = ch >> 2, cc = ch & 3, cs = cc ^ ((r >> 1) & 3);
    aSrc[j] = A + (size_t)(row0 + r)*K + cs*8;
    aDst[j] = ch*16;
  }
  const ushort* bSrc[BIT]; int bDst[BIT];
  #pragma unroll
  for (int j = 0; j < BIT; j++) {
    int ch = j*256 + t, r = ch >> 2, cc = ch & 3, cs = cc ^ ((r >> 1) & 3);
    bSrc[j] = Bt + (size_t)(col0 + r)*K + cs*8;
    bDst[j] = ch*16;
  }
  // fragment read offsets (swizzled)
  int aOff[MF], bOff[NF];
  #pragma unroll
  for (int m = 0; m < MF; m++) {
    int r = wr*(BM/2) + m*16 + (lane & 15);
    aOff[m] = r*64 + (((lane >> 4)*16) ^ (((r >> 1) & 3) << 4));
  }
  #pragma unroll
  for (int n = 0; n < NF; n++) {
    int r = wc*(BN/2) + n*16 + (lane & 15);
    bOff[n] = r*64 + (((lane >> 4)*16) ^ (((r >> 1) & 3) << 4));
  }
  f32x4 zero = {0.f, 0.f, 0.f, 0.f};
  f32x4 acc[MF][NF];
  #pragma unroll
  for (int m = 0; m < MF; m++)
    #pragma unroll
    for (int n = 0; n < NF; n++) acc[m][n] = zero;

  // prologue: stage tile 0 into buf 0
  #pragma unroll
  for (int j = 0; j < AIT; j++) GLOAD16(aSrc[j], (char*)As[0] + aDst[j]);
  #pragma unroll
  for (int j = 0; j < BIT; j++) GLOAD16(bSrc[j], (char*)Bs[0] + bDst[j]);
  __syncthreads();

  const int nk = K / BK;
  for (int ki = 0; ki < nk; ki++) {
    const int cur = ki & 1;
    if (ki + 1 < nk) {               // issue next-tile loads first (overlap with MFMA)
      const int kt = (ki + 1)*BK;
      #pragma unroll
      for (int j = 0; j < AIT; j++) GLOAD16(aSrc[j] + kt, (char*)As[cur^1] + aDst[j]);
      #pragma unroll
      for (int j = 0; j < BIT; j++) GLOAD16(bSrc[j] + kt, (char*)Bs[cur^1] + bDst[j]);
    }
    bf16x8 af[MF], bfr[NF];
    #pragma unroll
    for (int m = 0; m < MF; m++) af[m] = *(const bf16x8*)((const char*)As[cur] + aOff[m]);
    #pragma unroll
    for (int n = 0; n < NF; n++) bfr[n] = *(const bf16x8*)((const char*)Bs[cur] + bOff[n]);
    #pragma unroll
    for (int m = 0; m < MF; m++)
      #pragma unroll
      for (int n = 0; n < NF; n++)
        acc[m][n] = __builtin_amdgcn_mfma_f32_16x16x32_bf16(af[m], bfr[n], acc[m][n], 0, 0, 0);
    __syncthreads();                 // drains next-tile vmem writes + this-tile LDS reads
  }
  #pragma unroll
  for (int m = 0; m < MF; m++) {
    int rb = row0 + wr*(BM/2) + m*16 + ((lane >> 4) << 2);
    #pragma unroll
    for (int n = 0; n < NF; n++) {
      int c = col0 + wc*(BN/2) + n*16 + (lane & 15);
      float bv = bias[c];
      #pragma unroll
      for (int j = 0; j < 4; j++) {
        size_t idx = (size_t)(rb + j)*N + c;
        float v = acc[m][n][j] + bv;
        if (MODE == 1)      Cb[idx] = f2b(gelu_exact(v));
        else if (MODE == 2) Cf[idx] = v + R[idx];
        else                Cf[idx] = v;
      }
    }
  }
}

// ---------------- embed + positional encoding ----------------
__global__ __launch_bounds__(512) void embed_kernel(const float* __restrict__ src,
    const float* __restrict__ Wemb, const float* __restrict__ bemb,
    float* __restrict__ X, ushort* __restrict__ Xb)
{
  int row = blockIdx.x, l = row & (L_-1), t = threadIdx.x;
  __shared__ float s_src[32];
  if (t < 32) s_src[t] = src[row*32 + t];
  __syncthreads();
  float acc = bemb[t];
  #pragma unroll
  for (int k = 0; k < 32; k++) acc += s_src[k]*Wemb[k*DM + t];
  int i2 = t & ~1;
  float freq = expf((float)i2 * (-9.210340371976184f/512.0f));
  float ang = (float)l * freq;
  acc += (t & 1) ? cosf(ang) : sinf(ang);
  size_t idx = (size_t)row*DM + t;
  X[idx] = acc;
  Xb[idx] = f2b(acc);
}

// ---------------- QK_sample -> M score (j-parallel, short chains) ----------------
__global__ __launch_bounds__(64) void qksample_kernel(const float* __restrict__ QKV,
    const int* __restrict__ idx_s, float* __restrict__ Msc)
{
  int gid = blockIdx.x;              // (b*8+h)*1024 + i
  int i = gid & (L_-1), h = (gid >> 10) & 7, b = gid >> 13;
  int t = threadIdx.x;
  int j4 = t >> 2, e4 = t & 3;       // lane = j4*4 + e4
  const float* Qrow = QKV + ((size_t)(b*L_ + i))*QS + h*HD + e4*16;
  float4 q[4];
  #pragma unroll
  for (int r = 0; r < 4; r++) q[r] = *(const float4*)(Qrow + r*4);
  const float* Kbase = QKV + 512 + h*HD + (size_t)b*L_*QS + e4*16;
  const int* idq = idx_s + i*KS;
  float mx = -3.4e38f, sm = 0.f;
  #pragma unroll
  for (int p = 0; p < 3; p++) {
    int j = p*16 + j4;
    int jc = (j < KS) ? j : 0;       // inactive lanes redo j=0 (result discarded)
    int s = idq[jc];
    const float4* Kr = (const float4*)(Kbase + (size_t)s*QS);
    float4 k0 = Kr[0], k1 = Kr[1], k2 = Kr[2], k3 = Kr[3];
    float d = q[0].x*k0.x + q[0].y*k0.y + q[0].z*k0.z + q[0].w*k0.w;
    d += q[1].x*k1.x + q[1].y*k1.y + q[1].z*k1.z + q[1].w*k1.w;
    d += q[2].x*k2.x + q[2].y*k2.y + q[2].z*k2.z + q[2].w*k2.w;
    d += q[3].x*k3.x + q[3].y*k3.y + q[3].z*k3.z + q[3].w*k3.w;
    d += __shfl_xor(d, 1);
    d += __shfl_xor(d, 2);
    if (j < KS && e4 == 0) { mx = fmaxf(mx, d); sm += d; }
  }
  #pragma unroll
  for (int off = 4; off < 64; off <<= 1) {
    mx = fmaxf(mx, __shfl_xor(mx, off));
    sm += __shfl_xor(sm, off);
  }
  if (t == 0) Msc[gid] = mx - sm*(1.0f/KS);
}

// ---------------- register-resident top-35 (tie-break lower index) ----------------
__global__ __launch_bounds__(64) void topk_kernel(const float* __restrict__ Msc, int* __restrict__ idx_top)
{
  int bh = blockIdx.x, t = threadIdx.x;
  float v[16];
  #pragma unroll
  for (int r = 0; r < 16; r++) v[r] = Msc[(size_t)bh*L_ + r*64 + t];
  for (int sel = 0; sel < KS; sel++) {
    float bv = -3.4e38f; int br = 0;
    #pragma unroll
    for (int r = 0; r < 16; r++) {
      bool gt = v[r] > bv;
      bv = gt ? v[r] : bv;
      br = gt ? r : br;
    }
    int bi = br*64 + t;
    #pragma unroll
    for (int off = 32; off; off >>= 1) {
      float ov = __shfl_xor(bv, off); int oi = __shfl_xor(bi, off);
      if (ov > bv || (ov == bv && oi < bi)) { bv = ov; bi = oi; }
    }
    if (t == 0) idx_top[bh*KS + sel] = bi;
    if ((bi & 63) == t) v[bi >> 6] = -3.4e38f;
  }
}

// ---------------- V mean over L: segmented partials + merge (occupancy) ----------------
__global__ __launch_bounds__(64) void vmean_part_kernel(const float* __restrict__ QKV,
    float* __restrict__ VmeanP)
{
  int gid = blockIdx.x;              // bh*VSEG + seg  (512 blocks)
  int seg = gid & (VSEG-1), bh = gid >> 4;
  int h = bh & 7, b = bh >> 3;
  int e = threadIdx.x;
  const float* Vb = QKV + 1024 + h*HD + ((size_t)(b*L_ + seg*(L_/VSEG)))*QS;
  float s = 0.f;
  for (int l0 = 0; l0 < L_/VSEG; l0 += 8) {
    float vv[8];
    #pragma unroll
    for (int j = 0; j < 8; j++) vv[j] = Vb[(size_t)(l0+j)*QS + e];
    #pragma unroll
    for (int j = 0; j < 8; j++) s += vv[j];
  }
  VmeanP[gid*HD + e] = s;
}

__global__ __launch_bounds__(64) void vmean_merge_kernel(const float* __restrict__ VmeanP,
    float* __restrict__ Vmean)
{
  int bh = blockIdx.x, e = threadIdx.x;
  float s = 0.f;
  #pragma unroll
  for (int seg = 0; seg < VSEG; seg++) s += VmeanP[(bh*VSEG + seg)*HD + e];
  Vmean[bh*HD + e] = s * (1.f/L_);
}

// ---------------- fill context with broadcast V-mean (bf16) ----------------
__global__ __launch_bounds__(512) void ctxfill_kernel(const float* __restrict__ Vmean, ushort* __restrict__ CTXb)
{
  int row = blockIdx.x, b = row >> 10, t = threadIdx.x;
  CTXb[(size_t)row*DM + t] = f2b(Vmean[b*DM + t]);
}

// ---------------- chunked flash attention, phase A (query-split ×4, pipelined PV) ----
// grid: ((b*8+h)*8 + chunk)*4 + q  (1024 blocks), block 256
__global__ __launch_bounds__(256) void attn_part_kernel(const float* __restrict__ QKV,
    const int* __restrict__ idx_top,
    float* __restrict__ Pacc, float* __restrict__ Pm, float* __restrict__ Pl)
{
  int gid = blockIdx.x;
  int q = gid & 3, c = (gid >> 2) & 7, bh = gid >> 5;
  int h = bh & 7, b = bh >> 3;
  int chunk = bh*NCH + c;            // Pacc/Pm/Pl slot (same layout as before)
  int u0 = q*9;
  int NU = (q == 3) ? 8 : 9;
  int t = threadIdx.x;
  __shared__ float qs[9][68];          // scaled Q rows (padded pitch)
  __shared__ float sc[9][132];         // scores -> exp'd scores
  __shared__ float sm[9], sl[9];

  // load + scale this block's Q rows
  for (int idx = t; idx < NU*64; idx += 256) {
    int ul = idx >> 6, e = idx & 63;
    int qi = idx_top[bh*KS + u0 + ul];
    qs[ul][e] = QKV[((size_t)(b*L_ + qi))*QS + h*HD + e] * 0.125f;
  }
  __syncthreads();

  // scores: thread k = t&127 owns one key; K row in 16 float4 regs
  {
    int k = t & 127, par = t >> 7;
    const float4* Kr = (const float4*)(QKV + ((size_t)(b*L_ + c*CH + k))*QS + 512 + h*HD);
    float4 kreg[16];
    #pragma unroll
    for (int e4 = 0; e4 < 16; e4++) kreg[e4] = Kr[e4];
    for (int ul = par; ul < NU; ul += 2) {
      float d = 0.f;
      #pragma unroll
      for (int e4 = 0; e4 < 16; e4++) {
        float4 q4 = *(const float4*)&qs[ul][e4*4];   // wave-uniform broadcast
        float4 k4 = kreg[e4];
        d += q4.x*k4.x + q4.y*k4.y + q4.z*k4.z + q4.w*k4.w;
      }
      sc[ul][k] = d;
    }
  }
  __syncthreads();

  // softmax per ul: 4 threads/row
  {
    int ul = t >> 2, sub = t & 3;
    if (ul < NU) {
      float m = -3.4e38f;
      for (int i = sub; i < 128; i += 4) m = fmaxf(m, sc[ul][i]);
      m = fmaxf(m, __shfl_xor(m, 1));
      m = fmaxf(m, __shfl_xor(m, 2));
      float l = 0.f;
      for (int i = sub; i < 128; i += 4) {
        float ev = expf(sc[ul][i] - m);
        sc[ul][i] = ev;
        l += ev;
      }
      l += __shfl_xor(l, 1);
      l += __shfl_xor(l, 2);
      if (sub == 0) { sm[ul] = m; sl[ul] = l; }
    }
  }
  __syncthreads();

  // partial PV: thread = (ug, e); 8-deep manual load pipeline (ILP)
  {
    int e = t & 63, ug = t >> 6;
    const float* Vb = QKV + 1024 + h*HD + ((size_t)(b*L_ + c*CH))*QS;
    float acc[3] = {0.f, 0.f, 0.f};
    for (int kb0 = 0; kb0 < CH; kb0 += 8) {
      float vv[8];
      #pragma unroll
      for (int j = 0; j < 8; j++) vv[j] = Vb[(size_t)(kb0 + j)*QS + e];   // 8 loads in flight
      #pragma unroll
      for (int j = 0; j < 8; j++) {
        #pragma unroll
        for (int iu = 0; iu < 3; iu++) {
          int ul = ug + iu*4;
          if (ul < NU) acc[iu] += sc[ul][kb0 + j] * vv[j];   // sc read is wave-uniform broadcast
        }
      }
    }
    #pragma unroll
    for (int iu = 0; iu < 3; iu++) {
      int ul = ug + iu*4;
      if (ul < NU) Pacc[((size_t)chunk*35 + u0 + ul)*64 + e] = acc[iu];
    }
  }
  if (t < NU) { Pm[chunk*35 + u0 + t] = sm[t]; Pl[chunk*35 + u0 + t] = sl[t]; }
}

// ---------------- phase B: merge partials, scatter bf16 ctx ----------------
__global__ __launch_bounds__(256) void attn_merge_kernel(const float* __restrict__ Pacc,
    const float* __restrict__ Pm, const float* __restrict__ Pl,
    const int* __restrict__ idx_top, ushort* __restrict__ CTXb)
{
  int bh = blockIdx.x;
  int h = bh & 7, b = bh >> 3;
  int t = threadIdx.x;
  __shared__ float m8[NCH*35], l8[NCH*35];
  for (int i = t; i < NCH*35; i += 256) {
    int c = i / 35, u = i - c*35;
    m8[c*35 + u] = Pm[((size_t)bh*NCH + c)*35 + u];
    l8[c*35 + u] = Pl[((size_t)bh*NCH + c)*35 + u];
  }
  __syncthreads();
  int e = t & 63, ug = t >> 6;
  #pragma unroll
  for (int iu = 0; iu < 9; iu++) {
    int u = ug + iu*4;
    if (u >= 35) break;
    float M = -3.4e38f;
    #pragma unroll
    for (int c = 0; c < NCH; c++) M = fmaxf(M, m8[c*35 + u]);
    float Ltot = 0.f, o = 0.f;
    #pragma unroll
    for (int c = 0; c < NCH; c++) {
      float w = expf(m8[c*35 + u] - M);
      Ltot += w * l8[c*35 + u];
      o += w * Pacc[(((size_t)bh*NCH + c)*35 + u)*64 + e];
    }
    int qi = idx_top[bh*KS + u];
    CTXb[((size_t)(b*L_ + qi))*DM + h*HD + e] = f2b(o / Ltot);
  }
}

// ---------------- LayerNorm (optional add), f32 + bf16 out ----------------
__global__ __launch_bounds__(512) void ln_kernel(const float* __restrict__ Xa,
    const float* __restrict__ Xadd, const float* __restrict__ g, const float* __restrict__ beta,
    float* __restrict__ outf, ushort* __restrict__ outb)
{
  int row = blockIdx.x, t = threadIdx.x;
  __shared__ float red[16];
  size_t idx = (size_t)row*DM + t;
  float v = Xa[idx];
  if (Xadd) v += Xadd[idx];
  float s = v;
  #pragma unroll
  for (int off = 32; off; off >>= 1) s += __shfl_xor(s, off);
  if ((t & 63) == 0) red[t >> 6] = s;
  __syncthreads();
  float mean = 0.f;
  #pragma unroll
  for (int k = 0; k < 8; k++) mean += red[k];
  mean *= (1.f/DM);
  float d = v - mean, q = d*d;
  #pragma unroll
  for (int off = 32; off; off >>= 1) q += __shfl_xor(q, off);
  if ((t & 63) == 0) red[8 + (t >> 6)] = q;
  __syncthreads();
  float var = 0.f;
  #pragma unroll
  for (int k = 0; k < 8; k++) var += red[8 + k];
  var *= (1.f/DM);
  float r = d / sqrtf(var + 1e-5f) * g[t] + beta[t];
  outf[idx] = r;
  if (outb) outb[idx] = f2b(r);
}

// ---------------- partial mean pool + classifier ----------------
__global__ __launch_bounds__(512) void poolp_kernel(const float* __restrict__ X, float* __restrict__ pooledP)
{
  int p = blockIdx.x;
  int t = threadIdx.x;
  int b = p >> 3, seg = p & 7;
  float s = 0.f;
  const float* base = X + ((size_t)b*L_ + seg*128)*DM + t;
  for (int l = 0; l < 128; l++) s += base[(size_t)l*DM];
  pooledP[p*DM + t] = s;
}

__global__ __launch_bounds__(64) void cls_kernel(const float* __restrict__ pooledP,
    const float* __restrict__ Wc, const float* __restrict__ bc, float* __restrict__ out)
{
  int o = blockIdx.x;
  int b = o/10, c = o%10, t = threadIdx.x;
  float s = 0.f;
  for (int d = t; d < DM; d += 64) {
    float p = 0.f;
    #pragma unroll
    for (int seg = 0; seg < 8; seg++) p += pooledP[(b*8 + seg)*DM + d];
    s += p * (1.f/L_) * Wc[d*10 + c];
  }
  #pragma unroll
  for (int off = 32; off; off >>= 1) s += __shfl_xor(s, off);
  if (t == 0) out[o] = bc[c] + s;
}

extern "C" void kernel_launch(void* const* d_in, const int* in_sizes, int n_in,
                              void* d_out, int out_size, void* d_ws, size_t ws_size,
                              hipStream_t stream)
{
  const float* src   = (const float*)d_in[0];
  const int*   idxs  = (const int*)d_in[1];
  const float* Wemb  = (const float*)d_in[2];
  const float* bemb  = (const float*)d_in[3];
  const float* Wq    = (const float*)d_in[4];
  const float* bq    = (const float*)d_in[5];
  const float* Wk    = (const float*)d_in[6];
  const float* bk    = (const float*)d_in[7];
  const float* Wv    = (const float*)d_in[8];
  const float* bv    = (const float*)d_in[9];
  const float* Wo    = (const float*)d_in[10];
  const float* bo    = (const float*)d_in[11];
  const float* g1    = (const float*)d_in[12];
  const float* beta1 = (const float*)d_in[13];
  const float* W1    = (const float*)d_in[14];
  const float* bf1   = (const float*)d_in[15];
  const float* W2    = (const float*)d_in[16];
  const float* bf2   = (const float*)d_in[17];
  const float* g2    = (const float*)d_in[18];
  const float* beta2 = (const float*)d_in[19];
  const float* gf    = (const float*)d_in[20];
  const float* betaf = (const float*)d_in[21];
  const float* Wc    = (const float*)d_in[22];
  const float* bc    = (const float*)d_in[23];
  float* out = (float*)d_out;

  float* wsf = (float*)d_ws;
  float*  X     = wsf;                              // [0, 2097152)
  ushort* Xb    = (ushort*)(wsf + 2097152);         // [2097152, 3145728)
  ushort* CTXb  = (ushort*)(wsf + 3145728);         // [3145728, 4194304)
  float*  QKV   = wsf + 4194304;                    // [4194304, 10485760)  LIVE during attention
  ushort* H     = (ushort*)(wsf + 4194304);         // FFN hidden bf16 (QKV dead by FFN1)
  float*  Y     = wsf + 8388608;                    // [8388608, 10485760)  FFN2 out (QKV dead)
  // attention scratch: alias Xb (dead between QKV-GEMM read and ln1 rewrite)
  float*  Pacc  = wsf + 2097152;                    // 573,440 fl
  float*  VmeanP = wsf + 2670592;                   // 32,768 fl (ends 2703360 < 3145728)
  ushort* Wqkvt = (ushort*)(wsf + 10485760);        // 786,432 fl
  ushort* Wot   = (ushort*)(wsf + 11272192);        // 262,144 fl
  ushort* W1t   = (ushort*)(wsf + 11534336);        // 1,048,576 fl
  ushort* W2t   = (ushort*)(wsf + 12582912);        // 1,048,576 fl
  float*  bqkv  = wsf + 13631488;                   // 3,072
  float*  Msc   = wsf + 13634560;                   // 32,768 (dead after topk)
  float*  Pm    = wsf + 13634560;                   // alias Msc: 8,960
  float*  Pl    = wsf + 13634560 + 8960;            // alias Msc: 8,960
  float*  Vmean = wsf + 13667328;                   // 2,048
  float*  pooledP = wsf + 13669376;                 // 16,384
  int*    idx_top = (int*)(wsf + 13685760);         // 1,120

  for (int l = 0; l < 2; l++) {
    wconv_kernel<<<dim3(DM/32, DM/32), 256, 0, stream>>>(Wq + (size_t)l*DM*DM, Wqkvt + ((size_t)l*QS +    0)*DM, DM, DM);
    wconv_kernel<<<dim3(DM/32, DM/32), 256, 0, stream>>>(Wk + (size_t)l*DM*DM, Wqkvt + ((size_t)l*QS +  512)*DM, DM, DM);
    wconv_kernel<<<dim3(DM/32, DM/32), 256, 0, stream>>>(Wv + (size_t)l*DM*DM, Wqkvt + ((size_t)l*QS + 1024)*DM, DM, DM);
    wconv_kernel<<<dim3(DM/32, DM/32), 256, 0, stream>>>(Wo + (size_t)l*DM*DM, Wot + (size_t)l*DM*DM, DM, DM);
    wconv_kernel<<<dim3(DFF/32, DM/32), 256, 0, stream>>>(W1 + (size_t)l*DM*DFF, W1t + (size_t)l*DFF*DM, DM, DFF);
    wconv_kernel<<<dim3(DM/32, DFF/32), 256, 0, stream>>>(W2 + (size_t)l*DFF*DM, W2t + (size_t)l*DM*DFF, DFF, DM);
  }
  bcat_kernel<<<12, 256, 0, stream>>>(bq, bk, bv, bqkv);

  const int M = B_ * L_; // 4096
  embed_kernel<<<M, 512, 0, stream>>>(src, Wemb, bemb, X, Xb);

  for (int l = 0; l < 2; l++) {
    const size_t vo = (size_t)l*DM;
    // QKV: [4096,512] x [512,1536] -> 12x64 = 768 blocks
    mfma_gemm<64,128,0><<<dim3(QS/128, M/64), 256, 0, stream>>>(
        Xb, Wqkvt + (size_t)l*QS*DM, bqkv + (size_t)l*QS, nullptr, QKV, nullptr, M, QS, DM);
    qksample_kernel<<<B_*NH*L_, 64, 0, stream>>>(QKV, idxs + (size_t)l*L_*KS, Msc);
    topk_kernel<<<B_*NH, 64, 0, stream>>>(Msc, idx_top);
    vmean_part_kernel<<<B_*NH*VSEG, 64, 0, stream>>>(QKV, VmeanP);
    vmean_merge_kernel<<<B_*NH, 64, 0, stream>>>(VmeanP, Vmean);
    ctxfill_kernel<<<M, 512, 0, stream>>>(Vmean, CTXb);
    attn_part_kernel<<<B_*NH*NCH*4, 256, 0, stream>>>(QKV, idx_top, Pacc, Pm, Pl);
    attn_merge_kernel<<<B_*NH, 256, 0, stream>>>(Pacc, Pm, Pl, idx_top, CTXb);
    // Wo + residual: [4096,512] x [512,512] -> 8x64 = 512 blocks
    mfma_gemm<64,64,2><<<dim3(DM/64, M/64), 256, 0, stream>>>(
        CTXb, Wot + (size_t)l*DM*DM, bo + vo, X, X, nullptr, M, DM, DM);
    ln_kernel<<<M, 512, 0, stream>>>(X, nullptr, g1 + vo, beta1 + vo, X, Xb);
    // FFN1: [4096,512] x [512,2048] -> 16x64 = 1024 blocks
    mfma_gemm<64,128,1><<<dim3(DFF/128, M/64), 256, 0, stream>>>(
        Xb, W1t + (size_t)l*DFF*DM, bf1 + (size_t)l*DFF, nullptr, nullptr, H, M, DFF, DM);
    // FFN2: [4096,2048] x [2048,512] -> 8x64 = 512 blocks
    mfma_gemm<64,64,0><<<dim3(DM/64, M/64), 256, 0, stream>>>(
        H, W2t + (size_t)l*DM*DFF, bf2 + vo, nullptr, Y, nullptr, M, DM, DFF);
    ln_kernel<<<M, 512, 0, stream>>>(X, Y, g2 + vo, beta2 + vo, X, Xb);
  }
  ln_kernel<<<M, 512, 0, stream>>>(X, nullptr, gf, betaf, X, nullptr);
  poolp_kernel<<<B_*8, 512, 0, stream>>>(X, pooledP);
  cls_kernel<<<40, 64, 0, stream>>>(pooledP, Wc, bc, out);
}

// Round 13
// 476.213 us; speedup vs baseline: 2.1546x; 1.0454x over previous
//
#include <hip/hip_runtime.h>
#include <hip/hip_bf16.h>
#include <math.h>

#define B_ 4
#define L_ 1024
#define DM 512
#define NH 8
#define HD 64
#define DFF 2048
#define KS 35
#define QS 1536   // packed QKV row stride
#define CH 128    // attention key chunk
#define NCH (L_/CH)
#define VSEG 16   // V-mean segments per head

typedef __attribute__((ext_vector_type(8))) short bf16x8;
typedef __attribute__((ext_vector_type(4))) float f32x4;

__device__ inline ushort f2b(float f){
  __hip_bfloat16 h = __float2bfloat16(f);
  return *reinterpret_cast<ushort*>(&h);
}
__device__ inline float gelu_exact(float x){
  return 0.5f*x*(1.0f+erff(x*0.7071067811865476f));
}

#define GLOAD16(g, l) __builtin_amdgcn_global_load_lds( \
    (const __attribute__((address_space(1))) void*)(g), \
    (__attribute__((address_space(3))) void*)(l), 16, 0, 0)

// ---------------- weight convert + transpose to bf16 [N][K] (layer-batched) ----------
__global__ __launch_bounds__(256) void wconv_kernel(const float* __restrict__ W,
    ushort* __restrict__ Wt, int K, int N, size_t sStride, size_t dStride)
{
  W  += (size_t)blockIdx.z * sStride;
  Wt += (size_t)blockIdx.z * dStride;
  __shared__ float tile[32][33];
  int n0 = blockIdx.x*32, k0 = blockIdx.y*32;
  int tx = threadIdx.x & 31, ty = threadIdx.x >> 5;
  #pragma unroll
  for (int i = ty; i < 32; i += 8) tile[i][tx] = W[(size_t)(k0+i)*N + n0+tx];
  __syncthreads();
  #pragma unroll
  for (int i = ty; i < 32; i += 8) Wt[(size_t)(n0+i)*K + k0+tx] = f2b(tile[tx][i]);
}

__global__ __launch_bounds__(256) void bcat_kernel(const float* __restrict__ bq,
    const float* __restrict__ bk, const float* __restrict__ bv, float* __restrict__ bqkv)
{
  int i = blockIdx.x*256 + threadIdx.x;   // 0..3071
  if (i >= 2*QS) return;
  int l = i / QS, j = i - l*QS;
  const float* src = (j < 512) ? bq : (j < 1024 ? bk : bv);
  bqkv[i] = src[l*DM + (j & 511)];
}

// ---------------- bf16 MFMA GEMM: dbuf, K=64 per barrier (2 sub-tiles), XCD-swizzled --
// A: [M][K] bf16; Bt: [N][K] bf16; MODE 0: f32 out, 1: gelu->bf16 out, 2: +R f32 out
template<int BM, int BN, int MODE>
__global__ __launch_bounds__(256) void mfma_gemm(
    const ushort* __restrict__ A, const ushort* __restrict__ Bt,
    const float* __restrict__ bias, const float* __restrict__ R,
    float* __restrict__ Cf, ushort* __restrict__ Cb,
    int M, int N, int K)
{
  constexpr int MF = BM/32;          // A fragments per wave
  constexpr int NF = BN/32;          // B fragments per wave
  constexpr int AIT = BM*4/256;      // staging iters per K=32 sub-tile
  constexpr int BIT = BN*4/256;
  // [buffer][sub-tile][BM*32] — sub-tile layout byte-identical to the verified K=32 tile
  __shared__ __align__(16) ushort As[2][2][BM*32];
  __shared__ __align__(16) ushort Bs[2][2][BN*32];
  const int t = threadIdx.x, lane = t & 63, w = t >> 6, wr = w >> 1, wc = w & 1;

  // XCD-chunked bijective swizzle (all grids are multiples of 8)
  const int gx = gridDim.x;
  const int nwg = gx * gridDim.y;
  const int bid = blockIdx.y*gx + blockIdx.x;
  const int swz = (bid & 7)*(nwg >> 3) + (bid >> 3);
  const int row0 = (swz / gx)*BM, col0 = (swz % gx)*BN;

  // staging: linear LDS dest, inverse-swizzled global source (per K=32 sub-tile)
  const ushort* aSrc[AIT]; int aDst[AIT];
  #pragma unroll
  for (int j = 0; j < AIT; j++) {
    int ch = j*256 + t, r = ch >> 2, cc = ch & 3, cs = cc ^ ((r >> 1) & 3);
    aSrc[j] = A + (size_t)(row0 + r)*K + cs*8;
    aDst[j] = ch*16;
  }
  const ushort* bSrc[BIT]; int bDst[BIT];
  #pragma unroll
  for (int j = 0; j < BIT; j++) {
    int ch = j*256 + t, r = ch >> 2, cc = ch & 3, cs = cc ^ ((r >> 1) & 3);
    bSrc[j] = Bt + (size_t)(col0 + r)*K + cs*8;
    bDst[j] = ch*16;
  }
  // fragment read offsets (swizzled, within one sub-tile)
  int aOff[MF], bOff[NF];
  #pragma unroll
  for (int m = 0; m < MF; m++) {
    int r = wr*(BM/2) + m*16 + (lane & 15);
    aOff[m] = r*64 + (((lane >> 4)*16) ^ (((r >> 1) & 3) << 4));
  }
  #pragma unroll
  for (int n = 0; n < NF; n++) {
    int r = wc*(BN/2) + n*16 + (lane & 15);
    bOff[n] = r*64 + (((lane >> 4)*16) ^ (((r >> 1) & 3) << 4));
  }
  f32x4 zero = {0.f, 0.f, 0.f, 0.f};
  f32x4 acc[MF][NF];
  #pragma unroll
  for (int m = 0; m < MF; m++)
    #pragma unroll
    for (int n = 0; n < NF; n++) acc[m][n] = zero;

  // prologue: stage K=0..63 into buffer 0
  #pragma unroll
  for (int j = 0; j < AIT; j++) GLOAD16(aSrc[j],      (char*)As[0][0] + aDst[j]);
  #pragma unroll
  for (int j = 0; j < AIT; j++) GLOAD16(aSrc[j] + 32, (char*)As[0][1] + aDst[j]);
  #pragma unroll
  for (int j = 0; j < BIT; j++) GLOAD16(bSrc[j],      (char*)Bs[0][0] + bDst[j]);
  #pragma unroll
  for (int j = 0; j < BIT; j++) GLOAD16(bSrc[j] + 32, (char*)Bs[0][1] + bDst[j]);
  __syncthreads();

  const int nk = K >> 6;             // K/64
  for (int ki = 0; ki < nk; ki++) {
    const int cur = ki & 1;
    if (ki + 1 < nk) {               // issue next-K64 loads first (overlap with MFMA)
      const int kt = (ki + 1) << 6;
      #pragma unroll
      for (int j = 0; j < AIT; j++) GLOAD16(aSrc[j] + kt,      (char*)As[cur^1][0] + aDst[j]);
      #pragma unroll
      for (int j = 0; j < AIT; j++) GLOAD16(aSrc[j] + kt + 32, (char*)As[cur^1][1] + aDst[j]);
      #pragma unroll
      for (int j = 0; j < BIT; j++) GLOAD16(bSrc[j] + kt,      (char*)Bs[cur^1][0] + bDst[j]);
      #pragma unroll
      for (int j = 0; j < BIT; j++) GLOAD16(bSrc[j] + kt + 32, (char*)Bs[cur^1][1] + bDst[j]);
    }
    #pragma unroll
    for (int s = 0; s < 2; s++) {    // two K=32 sub-steps, same accumulation order as before
      bf16x8 af[MF], bfr[NF];
      #pragma unroll
      for (int m = 0; m < MF; m++) af[m] = *(const bf16x8*)((const char*)As[cur][s] + aOff[m]);
      #pragma unroll
      for (int n = 0; n < NF; n++) bfr[n] = *(const bf16x8*)((const char*)Bs[cur][s] + bOff[n]);
      #pragma unroll
      for (int m = 0; m < MF; m++)
        #pragma unroll
        for (int n = 0; n < NF; n++)
          acc[m][n] = __builtin_amdgcn_mfma_f32_16x16x32_bf16(af[m], bfr[n], acc[m][n], 0, 0, 0);
    }
    __syncthreads();                 // one drain per K=64 (was per K=32)
  }
  #pragma unroll
  for (int m = 0; m < MF; m++) {
    int rb = row0 + wr*(BM/2) + m*16 + ((lane >> 4) << 2);
    #pragma unroll
    for (int n = 0; n < NF; n++) {
      int c = col0 + wc*(BN/2) + n*16 + (lane & 15);
      float bv = bias[c];
      #pragma unroll
      for (int j = 0; j < 4; j++) {
        size_t idx = (size_t)(rb + j)*N + c;
        float v = acc[m][n][j] + bv;
        if (MODE == 1)      Cb[idx] = f2b(gelu_exact(v));
        else if (MODE == 2) Cf[idx] = v + R[idx];
        else                Cf[idx] = v;
      }
    }
  }
}

// ---------------- embed + positional encoding ----------------
__global__ __launch_bounds__(512) void embed_kernel(const float* __restrict__ src,
    const float* __restrict__ Wemb, const float* __restrict__ bemb,
    float* __restrict__ X, ushort* __restrict__ Xb)
{
  int row = blockIdx.x, l = row & (L_-1), t = threadIdx.x;
  __shared__ float s_src[32];
  if (t < 32) s_src[t] = src[row*32 + t];
  __syncthreads();
  float acc = bemb[t];
  #pragma unroll
  for (int k = 0; k < 32; k++) acc += s_src[k]*Wemb[k*DM + t];
  int i2 = t & ~1;
  float freq = expf((float)i2 * (-9.210340371976184f/512.0f));
  float ang = (float)l * freq;
  acc += (t & 1) ? cosf(ang) : sinf(ang);
  size_t idx = (size_t)row*DM + t;
  X[idx] = acc;
  Xb[idx] = f2b(acc);
}

// ---------------- QK_sample -> M score (j-parallel, short chains) ----------------
__global__ __launch_bounds__(64) void qksample_kernel(const float* __restrict__ QKV,
    const int* __restrict__ idx_s, float* __restrict__ Msc)
{
  int gid = blockIdx.x;              // (b*8+h)*1024 + i
  int i = gid & (L_-1), h = (gid >> 10) & 7, b = gid >> 13;
  int t = threadIdx.x;
  int j4 = t >> 2, e4 = t & 3;       // lane = j4*4 + e4
  const float* Qrow = QKV + ((size_t)(b*L_ + i))*QS + h*HD + e4*16;
  float4 q[4];
  #pragma unroll
  for (int r = 0; r < 4; r++) q[r] = *(const float4*)(Qrow + r*4);
  const float* Kbase = QKV + 512 + h*HD + (size_t)b*L_*QS + e4*16;
  const int* idq = idx_s + i*KS;
  float mx = -3.4e38f, sm = 0.f;
  #pragma unroll
  for (int p = 0; p < 3; p++) {
    int j = p*16 + j4;
    int jc = (j < KS) ? j : 0;       // inactive lanes redo j=0 (result discarded)
    int s = idq[jc];
    const float4* Kr = (const float4*)(Kbase + (size_t)s*QS);
    float4 k0 = Kr[0], k1 = Kr[1], k2 = Kr[2], k3 = Kr[3];
    float d = q[0].x*k0.x + q[0].y*k0.y + q[0].z*k0.z + q[0].w*k0.w;
    d += q[1].x*k1.x + q[1].y*k1.y + q[1].z*k1.z + q[1].w*k1.w;
    d += q[2].x*k2.x + q[2].y*k2.y + q[2].z*k2.z + q[2].w*k2.w;
    d += q[3].x*k3.x + q[3].y*k3.y + q[3].z*k3.z + q[3].w*k3.w;
    d += __shfl_xor(d, 1);
    d += __shfl_xor(d, 2);
    if (j < KS && e4 == 0) { mx = fmaxf(mx, d); sm += d; }
  }
  #pragma unroll
  for (int off = 4; off < 64; off <<= 1) {
    mx = fmaxf(mx, __shfl_xor(mx, off));
    sm += __shfl_xor(sm, off);
  }
  if (t == 0) Msc[gid] = mx - sm*(1.0f/KS);
}

// ---------------- register-resident top-35 (tie-break lower index) ----------------
__global__ __launch_bounds__(64) void topk_kernel(const float* __restrict__ Msc, int* __restrict__ idx_top)
{
  int bh = blockIdx.x, t = threadIdx.x;
  float v[16];
  #pragma unroll
  for (int r = 0; r < 16; r++) v[r] = Msc[(size_t)bh*L_ + r*64 + t];
  for (int sel = 0; sel < KS; sel++) {
    float bv = -3.4e38f; int br = 0;
    #pragma unroll
    for (int r = 0; r < 16; r++) {
      bool gt = v[r] > bv;
      bv = gt ? v[r] : bv;
      br = gt ? r : br;
    }
    int bi = br*64 + t;
    #pragma unroll
    for (int off = 32; off; off >>= 1) {
      float ov = __shfl_xor(bv, off); int oi = __shfl_xor(bi, off);
      if (ov > bv || (ov == bv && oi < bi)) { bv = ov; bi = oi; }
    }
    if (t == 0) idx_top[bh*KS + sel] = bi;
    if ((bi & 63) == t) v[bi >> 6] = -3.4e38f;
  }
}

// ---------------- V mean over L: segmented partials + merge (occupancy) ----------------
__global__ __launch_bounds__(64) void vmean_part_kernel(const float* __restrict__ QKV,
    float* __restrict__ VmeanP)
{
  int gid = blockIdx.x;              // bh*VSEG + seg  (512 blocks)
  int seg = gid & (VSEG-1), bh = gid >> 4;
  int h = bh & 7, b = bh >> 3;
  int e = threadIdx.x;
  const float* Vb = QKV + 1024 + h*HD + ((size_t)(b*L_ + seg*(L_/VSEG)))*QS;
  float s = 0.f;
  for (int l0 = 0; l0 < L_/VSEG; l0 += 8) {
    float vv[8];
    #pragma unroll
    for (int j = 0; j < 8; j++) vv[j] = Vb[(size_t)(l0+j)*QS + e];
    #pragma unroll
    for (int j = 0; j < 8; j++) s += vv[j];
  }
  VmeanP[gid*HD + e] = s;
}

__global__ __launch_bounds__(64) void vmean_merge_kernel(const float* __restrict__ VmeanP,
    float* __restrict__ Vmean)
{
  int bh = blockIdx.x, e = threadIdx.x;
  float s = 0.f;
  #pragma unroll
  for (int seg = 0; seg < VSEG; seg++) s += VmeanP[(bh*VSEG + seg)*HD + e];
  Vmean[bh*HD + e] = s * (1.f/L_);
}

// ---------------- fill context with broadcast V-mean (bf16) ----------------
__global__ __launch_bounds__(512) void ctxfill_kernel(const float* __restrict__ Vmean, ushort* __restrict__ CTXb)
{
  int row = blockIdx.x, b = row >> 10, t = threadIdx.x;
  CTXb[(size_t)row*DM + t] = f2b(Vmean[b*DM + t]);
}

// ---------------- chunked flash attention, phase A (query-split ×4, pipelined PV) ----
// grid: ((b*8+h)*8 + chunk)*4 + q  (1024 blocks), block 256
__global__ __launch_bounds__(256) void attn_part_kernel(const float* __restrict__ QKV,
    const int* __restrict__ idx_top,
    float* __restrict__ Pacc, float* __restrict__ Pm, float* __restrict__ Pl)
{
  int gid = blockIdx.x;
  int q = gid & 3, c = (gid >> 2) & 7, bh = gid >> 5;
  int h = bh & 7, b = bh >> 3;
  int chunk = bh*NCH + c;            // Pacc/Pm/Pl slot (same layout as before)
  int u0 = q*9;
  int NU = (q == 3) ? 8 : 9;
  int t = threadIdx.x;
  __shared__ float qs[9][68];          // scaled Q rows (padded pitch)
  __shared__ float sc[9][132];         // scores -> exp'd scores
  __shared__ float sm[9], sl[9];

  // load + scale this block's Q rows
  for (int idx = t; idx < NU*64; idx += 256) {
    int ul = idx >> 6, e = idx & 63;
    int qi = idx_top[bh*KS + u0 + ul];
    qs[ul][e] = QKV[((size_t)(b*L_ + qi))*QS + h*HD + e] * 0.125f;
  }
  __syncthreads();

  // scores: thread k = t&127 owns one key; K row in 16 float4 regs
  {
    int k = t & 127, par = t >> 7;
    const float4* Kr = (const float4*)(QKV + ((size_t)(b*L_ + c*CH + k))*QS + 512 + h*HD);
    float4 kreg[16];
    #pragma unroll
    for (int e4 = 0; e4 < 16; e4++) kreg[e4] = Kr[e4];
    for (int ul = par; ul < NU; ul += 2) {
      float d = 0.f;
      #pragma unroll
      for (int e4 = 0; e4 < 16; e4++) {
        float4 q4 = *(const float4*)&qs[ul][e4*4];   // wave-uniform broadcast
        float4 k4 = kreg[e4];
        d += q4.x*k4.x + q4.y*k4.y + q4.z*k4.z + q4.w*k4.w;
      }
      sc[ul][k] = d;
    }
  }
  __syncthreads();

  // softmax per ul: 4 threads/row
  {
    int ul = t >> 2, sub = t & 3;
    if (ul < NU) {
      float m = -3.4e38f;
      for (int i = sub; i < 128; i += 4) m = fmaxf(m, sc[ul][i]);
      m = fmaxf(m, __shfl_xor(m, 1));
      m = fmaxf(m, __shfl_xor(m, 2));
      float l = 0.f;
      for (int i = sub; i < 128; i += 4) {
        float ev = expf(sc[ul][i] - m);
        sc[ul][i] = ev;
        l += ev;
      }
      l += __shfl_xor(l, 1);
      l += __shfl_xor(l, 2);
      if (sub == 0) { sm[ul] = m; sl[ul] = l; }
    }
  }
  __syncthreads();

  // partial PV: thread = (ug, e); 8-deep manual load pipeline (ILP)
  {
    int e = t & 63, ug = t >> 6;
    const float* Vb = QKV + 1024 + h*HD + ((size_t)(b*L_ + c*CH))*QS;
    float acc[3] = {0.f, 0.f, 0.f};
    for (int kb0 = 0; kb0 < CH; kb0 += 8) {
      float vv[8];
      #pragma unroll
      for (int j = 0; j < 8; j++) vv[j] = Vb[(size_t)(kb0 + j)*QS + e];   // 8 loads in flight
      #pragma unroll
      for (int j = 0; j < 8; j++) {
        #pragma unroll
        for (int iu = 0; iu < 3; iu++) {
          int ul = ug + iu*4;
          if (ul < NU) acc[iu] += sc[ul][kb0 + j] * vv[j];   // sc read is wave-uniform broadcast
        }
      }
    }
    #pragma unroll
    for (int iu = 0; iu < 3; iu++) {
      int ul = ug + iu*4;
      if (ul < NU) Pacc[((size_t)chunk*35 + u0 + ul)*64 + e] = acc[iu];
    }
  }
  if (t < NU) { Pm[chunk*35 + u0 + t] = sm[t]; Pl[chunk*35 + u0 + t] = sl[t]; }
}

// ---------------- phase B: merge partials, scatter bf16 ctx ----------------
__global__ __launch_bounds__(256) void attn_merge_kernel(const float* __restrict__ Pacc,
    const float* __restrict__ Pm, const float* __restrict__ Pl,
    const int* __restrict__ idx_top, ushort* __restrict__ CTXb)
{
  int bh = blockIdx.x;
  int h = bh & 7, b = bh >> 3;
  int t = threadIdx.x;
  __shared__ float m8[NCH*35], l8[NCH*35];
  for (int i = t; i < NCH*35; i += 256) {
    int c = i / 35, u = i - c*35;
    m8[c*35 + u] = Pm[((size_t)bh*NCH + c)*35 + u];
    l8[c*35 + u] = Pl[((size_t)bh*NCH + c)*35 + u];
  }
  __syncthreads();
  int e = t & 63, ug = t >> 6;
  #pragma unroll
  for (int iu = 0; iu < 9; iu++) {
    int u = ug + iu*4;
    if (u >= 35) break;
    float M = -3.4e38f;
    #pragma unroll
    for (int c = 0; c < NCH; c++) M = fmaxf(M, m8[c*35 + u]);
    float Ltot = 0.f, o = 0.f;
    #pragma unroll
    for (int c = 0; c < NCH; c++) {
      float w = expf(m8[c*35 + u] - M);
      Ltot += w * l8[c*35 + u];
      o += w * Pacc[(((size_t)bh*NCH + c)*35 + u)*64 + e];
    }
    int qi = idx_top[bh*KS + u];
    CTXb[((size_t)(b*L_ + qi))*DM + h*HD + e] = f2b(o / Ltot);
  }
}

// ---------------- LayerNorm (optional add), f32 + bf16 out ----------------
__global__ __launch_bounds__(512) void ln_kernel(const float* __restrict__ Xa,
    const float* __restrict__ Xadd, const float* __restrict__ g, const float* __restrict__ beta,
    float* __restrict__ outf, ushort* __restrict__ outb)
{
  int row = blockIdx.x, t = threadIdx.x;
  __shared__ float red[16];
  size_t idx = (size_t)row*DM + t;
  float v = Xa[idx];
  if (Xadd) v += Xadd[idx];
  float s = v;
  #pragma unroll
  for (int off = 32; off; off >>= 1) s += __shfl_xor(s, off);
  if ((t & 63) == 0) red[t >> 6] = s;
  __syncthreads();
  float mean = 0.f;
  #pragma unroll
  for (int k = 0; k < 8; k++) mean += red[k];
  mean *= (1.f/DM);
  float d = v - mean, q = d*d;
  #pragma unroll
  for (int off = 32; off; off >>= 1) q += __shfl_xor(q, off);
  if ((t & 63) == 0) red[8 + (t >> 6)] = q;
  __syncthreads();
  float var = 0.f;
  #pragma unroll
  for (int k = 0; k < 8; k++) var += red[8 + k];
  var *= (1.f/DM);
  float r = d / sqrtf(var + 1e-5f) * g[t] + beta[t];
  outf[idx] = r;
  if (outb) outb[idx] = f2b(r);
}

// ---------------- partial mean pool + classifier ----------------
__global__ __launch_bounds__(512) void poolp_kernel(const float* __restrict__ X, float* __restrict__ pooledP)
{
  int p = blockIdx.x;
  int t = threadIdx.x;
  int b = p >> 3, seg = p & 7;
  float s = 0.f;
  const float* base = X + ((size_t)b*L_ + seg*128)*DM + t;
  for (int l = 0; l < 128; l++) s += base[(size_t)l*DM];
  pooledP[p*DM + t] = s;
}

__global__ __launch_bounds__(64) void cls_kernel(const float* __restrict__ pooledP,
    const float* __restrict__ Wc, const float* __restrict__ bc, float* __restrict__ out)
{
  int o = blockIdx.x;
  int b = o/10, c = o%10, t = threadIdx.x;
  float s = 0.f;
  for (int d = t; d < DM; d += 64) {
    float p = 0.f;
    #pragma unroll
    for (int seg = 0; seg < 8; seg++) p += pooledP[(b*8 + seg)*DM + d];
    s += p * (1.f/L_) * Wc[d*10 + c];
  }
  #pragma unroll
  for (int off = 32; off; off >>= 1) s += __shfl_xor(s, off);
  if (t == 0) out[o] = bc[c] + s;
}

extern "C" void kernel_launch(void* const* d_in, const int* in_sizes, int n_in,
                              void* d_out, int out_size, void* d_ws, size_t ws_size,
                              hipStream_t stream)
{
  const float* src   = (const float*)d_in[0];
  const int*   idxs  = (const int*)d_in[1];
  const float* Wemb  = (const float*)d_in[2];
  const float* bemb  = (const float*)d_in[3];
  const float* Wq    = (const float*)d_in[4];
  const float* bq    = (const float*)d_in[5];
  const float* Wk    = (const float*)d_in[6];
  const float* bk    = (const float*)d_in[7];
  const float* Wv    = (const float*)d_in[8];
  const float* bv    = (const float*)d_in[9];
  const float* Wo    = (const float*)d_in[10];
  const float* bo    = (const float*)d_in[11];
  const float* g1    = (const float*)d_in[12];
  const float* beta1 = (const float*)d_in[13];
  const float* W1    = (const float*)d_in[14];
  const float* bf1   = (const float*)d_in[15];
  const float* W2    = (const float*)d_in[16];
  const float* bf2   = (const float*)d_in[17];
  const float* g2    = (const float*)d_in[18];
  const float* beta2 = (const float*)d_in[19];
  const float* gf    = (const float*)d_in[20];
  const float* betaf = (const float*)d_in[21];
  const float* Wc    = (const float*)d_in[22];
  const float* bc    = (const float*)d_in[23];
  float* out = (float*)d_out;

  float* wsf = (float*)d_ws;
  float*  X     = wsf;                              // [0, 2097152)
  ushort* Xb    = (ushort*)(wsf + 2097152);         // [2097152, 3145728)
  ushort* CTXb  = (ushort*)(wsf + 3145728);         // [3145728, 4194304)
  float*  QKV   = wsf + 4194304;                    // [4194304, 10485760)  LIVE during attention
  ushort* H     = (ushort*)(wsf + 4194304);         // FFN hidden bf16 (QKV dead by FFN1)
  float*  Y     = wsf + 8388608;                    // [8388608, 10485760)  FFN2 out (QKV dead)
  // attention scratch: alias Xb (dead between QKV-GEMM read and ln1 rewrite)
  float*  Pacc  = wsf + 2097152;                    // 573,440 fl
  float*  VmeanP = wsf + 2670592;                   // 32,768 fl (ends 2703360 < 3145728)
  ushort* Wqkvt = (ushort*)(wsf + 10485760);        // 786,432 fl
  ushort* Wot   = (ushort*)(wsf + 11272192);        // 262,144 fl
  ushort* W1t   = (ushort*)(wsf + 11534336);        // 1,048,576 fl
  ushort* W2t   = (ushort*)(wsf + 12582912);        // 1,048,576 fl
  float*  bqkv  = wsf + 13631488;                   // 3,072
  float*  Msc   = wsf + 13634560;                   // 32,768 (dead after topk)
  float*  Pm    = wsf + 13634560;                   // alias Msc: 8,960
  float*  Pl    = wsf + 13634560 + 8960;            // alias Msc: 8,960
  float*  Vmean = wsf + 13667328;                   // 2,048
  float*  pooledP = wsf + 13669376;                 // 16,384
  int*    idx_top = (int*)(wsf + 13685760);         // 1,120

  // weight conversion, both layers batched via grid.z
  wconv_kernel<<<dim3(DM/32, DM/32, 2), 256, 0, stream>>>(Wq, Wqkvt +    0*DM, DM, DM, (size_t)DM*DM, (size_t)QS*DM);
  wconv_kernel<<<dim3(DM/32, DM/32, 2), 256, 0, stream>>>(Wk, Wqkvt +  512*DM, DM, DM, (size_t)DM*DM, (size_t)QS*DM);
  wconv_kernel<<<dim3(DM/32, DM/32, 2), 256, 0, stream>>>(Wv, Wqkvt + 1024*DM, DM, DM, (size_t)DM*DM, (size_t)QS*DM);
  wconv_kernel<<<dim3(DM/32, DM/32, 2), 256, 0, stream>>>(Wo, Wot, DM, DM, (size_t)DM*DM, (size_t)DM*DM);
  wconv_kernel<<<dim3(DFF/32, DM/32, 2), 256, 0, stream>>>(W1, W1t, DM, DFF, (size_t)DM*DFF, (size_t)DFF*DM);
  wconv_kernel<<<dim3(DM/32, DFF/32, 2), 256, 0, stream>>>(W2, W2t, DFF, DM, (size_t)DFF*DM, (size_t)DM*DFF);
  bcat_kernel<<<12, 256, 0, stream>>>(bq, bk, bv, bqkv);

  const int M = B_ * L_; // 4096
  embed_kernel<<<M, 512, 0, stream>>>(src, Wemb, bemb, X, Xb);

  for (int l = 0; l < 2; l++) {
    const size_t vo = (size_t)l*DM;
    // QKV: [4096,512] x [512,1536] -> 12x64 = 768 blocks
    mfma_gemm<64,128,0><<<dim3(QS/128, M/64), 256, 0, stream>>>(
        Xb, Wqkvt + (size_t)l*QS*DM, bqkv + (size_t)l*QS, nullptr, QKV, nullptr, M, QS, DM);
    qksample_kernel<<<B_*NH*L_, 64, 0, stream>>>(QKV, idxs + (size_t)l*L_*KS, Msc);
    topk_kernel<<<B_*NH, 64, 0, stream>>>(Msc, idx_top);
    vmean_part_kernel<<<B_*NH*VSEG, 64, 0, stream>>>(QKV, VmeanP);
    vmean_merge_kernel<<<B_*NH, 64, 0, stream>>>(VmeanP, Vmean);
    ctxfill_kernel<<<M, 512, 0, stream>>>(Vmean, CTXb);
    attn_part_kernel<<<B_*NH*NCH*4, 256, 0, stream>>>(QKV, idx_top, Pacc, Pm, Pl);
    attn_merge_kernel<<<B_*NH, 256, 0, stream>>>(Pacc, Pm, Pl, idx_top, CTXb);
    // Wo + residual: [4096,512] x [512,512] -> 8x64 = 512 blocks
    mfma_gemm<64,64,2><<<dim3(DM/64, M/64), 256, 0, stream>>>(
        CTXb, Wot + (size_t)l*DM*DM, bo + vo, X, X, nullptr, M, DM, DM);
    ln_kernel<<<M, 512, 0, stream>>>(X, nullptr, g1 + vo, beta1 + vo, X, Xb);
    // FFN1: [4096,512] x [512,2048] -> 16x64 = 1024 blocks
    mfma_gemm<64,128,1><<<dim3(DFF/128, M/64), 256, 0, stream>>>(
        Xb, W1t + (size_t)l*DFF*DM, bf1 + (size_t)l*DFF, nullptr, nullptr, H, M, DFF, DM);
    // FFN2: [4096,2048] x [2048,512] -> 8x64 = 512 blocks
    mfma_gemm<64,64,0><<<dim3(DM/64, M/64), 256, 0, stream>>>(
        H, W2t + (size_t)l*DM*DFF, bf2 + vo, nullptr, Y, nullptr, M, DM, DFF);
    ln_kernel<<<M, 512, 0, stream>>>(X, Y, g2 + vo, beta2 + vo, X, Xb);
  }
  ln_kernel<<<M, 512, 0, stream>>>(X, nullptr, gf, betaf, X, nullptr);
  poolp_kernel<<<B_*8, 512, 0, stream>>>(X, pooledP);
  cls_kernel<<<40, 64, 0, stream>>>(pooledP, Wc, bc, out);
}